// Round 12
// baseline (242.883 us; speedup 1.0000x reference)
//
#include <hip/hip_runtime.h>

typedef unsigned short u16;
typedef unsigned int   u32;
typedef short   bf16x8 __attribute__((ext_vector_type(8)));
typedef float   f32x4  __attribute__((ext_vector_type(4)));
typedef u16     u16x4  __attribute__((ext_vector_type(4)));

// ---------- bf16 helpers (RNE) ----------
__device__ __forceinline__ u16 f2b(float f) {
    u32 u = __builtin_bit_cast(u32, f);
    u32 r = u + 0x7FFFu + ((u >> 16) & 1u);
    return (u16)(r >> 16);
}
__device__ __forceinline__ float b2f(u16 h) {
    u32 u = ((u32)h) << 16;
    return __builtin_bit_cast(float, u);
}
__device__ __forceinline__ u16x4 f4_to_b4(float4 v) {
    u16x4 o; o.x = f2b(v.x); o.y = f2b(v.y); o.z = f2b(v.z); o.w = f2b(v.w);
    return o;
}

// native transcendentals: single-instruction v_exp_f32 / v_log_f32
__device__ __forceinline__ float fexp2(float x) {
    float r;
    asm("v_exp_f32 %0, %1" : "=v"(r) : "v"(x));
    return r;
}
__device__ __forceinline__ float flog2(float x) {
    float r;
    asm("v_log_f32 %0, %1" : "=v"(r) : "v"(x));
    return r;
}

// DPP add: p += p[lane permuted by CTRL]  (pure VALU, no DS pipe)
template <int CTRL>
__device__ __forceinline__ float dpp_add(float p) {
    int pi = __builtin_bit_cast(int, p);
    int q  = __builtin_amdgcn_update_dpp(pi, pi, CTRL, 0xF, 0xF, false);
    return p + __builtin_bit_cast(float, q);
}
#define DPP_XOR1 0xB1   // quad_perm [1,0,3,2]
#define DPP_XOR2 0x4E   // quad_perm [2,3,0,1]
#define DPP_HMIR 0x141  // row_half_mirror (lane^7)
#define DPP_MIR  0x140  // row_mirror      (lane^15)

// ---------- constants ----------
#define MROWS   2048   // B*L
#define NSEG    16
#define SEGT    64
#define L2E     1.44269504088896340736f
#define LN2     0.69314718055994530942f

#define GLDS(g, l) __builtin_amdgcn_global_load_lds(                      \
    (const __attribute__((address_space(1))) void*)(g),                   \
    (__attribute__((address_space(3))) void*)(l), 16, 0, 0)

// ---------- fp32 -> bf16 conversion (weights) ----------
__global__ __launch_bounds__(256) void cvt_kernel(const float* __restrict__ in,
                                                  u16* __restrict__ out, int n4) {
    int i = blockIdx.x * 256 + threadIdx.x;
    if (i < n4) {
        float4 v = ((const float4*)in)[i];
        ((u16x4*)out)[i] = f4_to_b4(v);
    }
}

// pad W_xproj (96 x 2048) -> bf16 (128 x 2048), rows 96..127 = 0
__global__ __launch_bounds__(256) void pad_xproj_kernel(const float* __restrict__ in,
                                                        u16* __restrict__ out) {
    int i = blockIdx.x * 256 + threadIdx.x;    // over 128*512
    int r = i >> 9, c4 = i & 511;
    float4 v = make_float4(0.f, 0.f, 0.f, 0.f);
    if (r < 96) v = ((const float4*)(in + (size_t)r * 2048))[c4];
    ((u16x4*)(out + (size_t)r * 2048))[c4] = f4_to_b4(v);
}

// ---------- LayerNorm (row = 1024 cols), fp32 in -> bf16 out ----------
__global__ __launch_bounds__(256) void ln_kernel(const float* __restrict__ x,
                                                 const float* __restrict__ w,
                                                 const float* __restrict__ b,
                                                 u16* __restrict__ out) {
    const int row = blockIdx.x;
    const int tid = threadIdx.x;
    const float4 v = ((const float4*)(x + (size_t)row * 1024))[tid];
    float s = v.x + v.y + v.z + v.w;
    float q = v.x * v.x + v.y * v.y + v.z * v.z + v.w * v.w;
#pragma unroll
    for (int off = 1; off < 64; off <<= 1) {
        s += __shfl_xor(s, off, 64);
        q += __shfl_xor(q, off, 64);
    }
    __shared__ float ss[4], qq[4];
    const int wave = tid >> 6;
    if ((tid & 63) == 0) { ss[wave] = s; qq[wave] = q; }
    __syncthreads();
    s = ss[0] + ss[1] + ss[2] + ss[3];
    q = qq[0] + qq[1] + qq[2] + qq[3];
    const float mean = s * (1.f / 1024.f);
    const float var  = q * (1.f / 1024.f) - mean * mean;
    const float rstd = rsqrtf(var + 1e-5f);
    const float4 wv = ((const float4*)w)[tid];
    const float4 bv = ((const float4*)b)[tid];
    float4 o;
    o.x = (v.x - mean) * rstd * wv.x + bv.x;
    o.y = (v.y - mean) * rstd * wv.y + bv.y;
    o.z = (v.z - mean) * rstd * wv.z + bv.z;
    o.w = (v.w - mean) * rstd * wv.w + bv.w;
    ((u16x4*)(out + (size_t)row * 1024))[tid] = f4_to_b4(o);
}

// ---------- depthwise causal conv + bias + silu (bf16 in) -> row-major upb + tiled utl ----------
__global__ __launch_bounds__(256) void conv_kernel(const u16* __restrict__ xzu,
                                                   const float* __restrict__ cw,
                                                   const float* __restrict__ cb,
                                                   u16* __restrict__ up,
                                                   u16* __restrict__ utl) {
    const int idx = blockIdx.x * 256 + threadIdx.x;   // over 2048 rows * 512 d4
    const int row = idx >> 9;
    const int d4  = idx & 511;
    const int d   = d4 * 4;
    const int bb  = row >> 10;
    const int t   = row & 1023;
    float w0[4], w1[4], w2[4], w3[4];
    *(float4*)w0 = ((const float4*)cw)[d + 0];
    *(float4*)w1 = ((const float4*)cw)[d + 1];
    *(float4*)w2 = ((const float4*)cw)[d + 2];
    *(float4*)w3 = ((const float4*)cw)[d + 3];
    float4 a = ((const float4*)cb)[d4];
#pragma unroll
    for (int j = 0; j < 4; ++j) {
        const int tt = t - 3 + j;
        if (tt >= 0) {
            const u16x4 uv = *(const u16x4*)(xzu + ((size_t)(bb * 1024 + tt)) * 2048 + d);
            a.x += b2f(uv.x) * w0[j];
            a.y += b2f(uv.y) * w1[j];
            a.z += b2f(uv.z) * w2[j];
            a.w += b2f(uv.w) * w3[j];
        }
    }
    float4 o;
    o.x = a.x / (1.f + __expf(-a.x));
    o.y = a.y / (1.f + __expf(-a.y));
    o.z = a.z / (1.f + __expf(-a.z));
    o.w = a.w / (1.f + __expf(-a.w));
    const u16x4 pk = f4_to_b4(o);
    ((u16x4*)up)[idx] = pk;
    *(u16x4*)(utl + (((size_t)(d >> 4)) * 2048 + row) * 16 + (d & 15)) = pk;
}

// ---------- triple-buffered GEMM 128x128 (XCD-swizzled), split-K partial out ----------
__global__ __launch_bounds__(256) void gemm_tb(const u16* __restrict__ A,
                                               const u16* __restrict__ Bw,
                                               float* __restrict__ Cptr,
                                               int M, int N, int K, int KS) {
    const int nbm = gridDim.x, nbn = gridDim.y;
    const int nwg = nbm * nbn;
    const int id  = blockIdx.x + nbm * blockIdx.y;
    const int sw  = (nwg >= 8) ? ((id & 7) * (nwg >> 3) + (id >> 3)) : id;
    const int bm  = sw % nbm, bn = sw / nbm;

    __shared__ u16 Asm[3][128 * 32];
    __shared__ u16 Bsm[3][128 * 32];
    const int tid  = threadIdx.x;
    const int kz   = blockIdx.z;
    const int lane = tid & 63;
    const int wave = tid >> 6;
    const int wm   = wave >> 1, wn = wave & 1;
    const u16* Ag = A  + (size_t)bm * 128 * K;
    const u16* Bg = Bw + (size_t)bn * 128 * K;
    const int r0 = tid >> 2;
    const int r1 = r0 + 64;
    const int sg = (tid & 3) * 8;
    const int k0 = kz * KS;
    const int nk = KS >> 5;
    const int fr = lane & 15, fk = (lane >> 4) * 8;

#define STG(bf, kk)                                                            \
    {                                                                          \
        const int kof = k0 + (kk) * 32;                                        \
        GLDS(Ag + (size_t)r0 * K + kof + sg, &Asm[bf][tid * 8]);               \
        GLDS(Ag + (size_t)r1 * K + kof + sg, &Asm[bf][(tid + 256) * 8]);       \
        GLDS(Bg + (size_t)r0 * K + kof + sg, &Bsm[bf][tid * 8]);               \
        GLDS(Bg + (size_t)r1 * K + kof + sg, &Bsm[bf][(tid + 256) * 8]);       \
    }

    f32x4 acc[4][4] = {};
    STG(0, 0); STG(1, 1); STG(2, 2);
    int buf = 0;
    for (int k = 0; k < nk; ++k) {
        if (k < nk - 2)       asm volatile("s_waitcnt vmcnt(8)" ::: "memory");
        else if (k == nk - 2) asm volatile("s_waitcnt vmcnt(4)" ::: "memory");
        else                  asm volatile("s_waitcnt vmcnt(0)" ::: "memory");
        __builtin_amdgcn_s_barrier();
        bf16x8 a[4], b[4];
#pragma unroll
        for (int m = 0; m < 4; ++m)
            a[m] = *(const bf16x8*)&Asm[buf][(wm * 64 + m * 16 + fr) * 32 + fk];
#pragma unroll
        for (int n = 0; n < 4; ++n)
            b[n] = *(const bf16x8*)&Bsm[buf][(wn * 64 + n * 16 + fr) * 32 + fk];
        asm volatile("s_waitcnt lgkmcnt(0)" ::: "memory");
        __builtin_amdgcn_s_barrier();
        if (k + 3 < nk) STG(buf, k + 3);
#pragma unroll
        for (int m = 0; m < 4; ++m)
#pragma unroll
            for (int n = 0; n < 4; ++n)
                acc[m][n] = __builtin_amdgcn_mfma_f32_16x16x32_bf16(a[m], b[n], acc[m][n], 0, 0, 0);
        buf = (buf == 2) ? 0 : buf + 1;
    }
#undef STG

    const int fq = lane >> 4;
#pragma unroll
    for (int m = 0; m < 4; ++m) {
#pragma unroll
        for (int n = 0; n < 4; ++n) {
            const int row0 = bm * 128 + wm * 64 + m * 16 + fq * 4;
            const int col  = bn * 128 + wn * 64 + n * 16 + fr;
#pragma unroll
            for (int j = 0; j < 4; ++j)
                Cptr[(size_t)kz * M * N + (size_t)(row0 + j) * N + col] = acc[m][n][j];
        }
    }
}

// ---------- triple-buffered GEMM 64x128 tile (4 blocks/CU for 2048xN grids) ----------
// EPI: 3 = relu(c+bias) bf16; 5 = xz split (u -> bf16 row-major / silu(z) -> TILED zst)
template <int EPI>
__global__ __launch_bounds__(256) void gemm_a64(const u16* __restrict__ A,
                                                const u16* __restrict__ Bw,
                                                void* __restrict__ Cptr,
                                                void* __restrict__ Cptr2,
                                                const float* __restrict__ bias,
                                                int M, int N, int K) {
    const int nbm = gridDim.x, nbn = gridDim.y;
    const int nwg = nbm * nbn;
    const int id  = blockIdx.x + nbm * blockIdx.y;
    const int sw  = (id & 7) * (nwg >> 3) + (id >> 3);
    const int bm  = sw % nbm, bn = sw / nbm;

    __shared__ u16 Asm[3][64 * 32];
    __shared__ u16 Bsm[3][128 * 32];
    const int tid  = threadIdx.x;
    const int lane = tid & 63;
    const int wave = tid >> 6;
    const int wm   = wave >> 1, wn = wave & 1;   // 2x2 waves over 64x128
    const u16* Ag = A  + (size_t)bm * 64 * K;
    const u16* Bg = Bw + (size_t)bn * 128 * K;
    const int r0 = tid >> 2;          // 0..63
    const int r1 = r0 + 64;
    const int sg = (tid & 3) * 8;
    const int nk = K >> 5;
    const int fr = lane & 15, fk = (lane >> 4) * 8;

#define STGA(bf, kk)                                                           \
    {                                                                          \
        const int kof = (kk) * 32;                                             \
        GLDS(Ag + (size_t)r0 * K + kof + sg, &Asm[bf][tid * 8]);               \
        GLDS(Bg + (size_t)r0 * K + kof + sg, &Bsm[bf][tid * 8]);               \
        GLDS(Bg + (size_t)r1 * K + kof + sg, &Bsm[bf][(tid + 256) * 8]);       \
    }

    f32x4 acc[2][4] = {};
    STGA(0, 0); STGA(1, 1); STGA(2, 2);
    int buf = 0;
    for (int k = 0; k < nk; ++k) {
        if (k < nk - 2)       asm volatile("s_waitcnt vmcnt(6)" ::: "memory");
        else if (k == nk - 2) asm volatile("s_waitcnt vmcnt(3)" ::: "memory");
        else                  asm volatile("s_waitcnt vmcnt(0)" ::: "memory");
        __builtin_amdgcn_s_barrier();
        bf16x8 a[2], b[4];
#pragma unroll
        for (int m = 0; m < 2; ++m)
            a[m] = *(const bf16x8*)&Asm[buf][(wm * 32 + m * 16 + fr) * 32 + fk];
#pragma unroll
        for (int n = 0; n < 4; ++n)
            b[n] = *(const bf16x8*)&Bsm[buf][(wn * 64 + n * 16 + fr) * 32 + fk];
        asm volatile("s_waitcnt lgkmcnt(0)" ::: "memory");
        __builtin_amdgcn_s_barrier();
        if (k + 3 < nk) STGA(buf, k + 3);
#pragma unroll
        for (int m = 0; m < 2; ++m)
#pragma unroll
            for (int n = 0; n < 4; ++n)
                acc[m][n] = __builtin_amdgcn_mfma_f32_16x16x32_bf16(a[m], b[n], acc[m][n], 0, 0, 0);
        buf = (buf == 2) ? 0 : buf + 1;
    }
#undef STGA

    const int fq = lane >> 4;
#pragma unroll
    for (int m = 0; m < 2; ++m) {
#pragma unroll
        for (int n = 0; n < 4; ++n) {
            const int row0 = bm * 64 + wm * 32 + m * 16 + fq * 4;
            const int col  = bn * 128 + wn * 64 + n * 16 + fr;
#pragma unroll
            for (int j = 0; j < 4; ++j) {
                float v = acc[m][n][j];
                if constexpr (EPI == 3) {
                    v += bias[col];
                    ((u16*)Cptr)[(size_t)(row0 + j) * N + col] = f2b(fmaxf(v, 0.f));
                } else {   // 5: xz split
                    if (col < 2048) {
                        ((u16*)Cptr)[(size_t)(row0 + j) * 2048 + col] = f2b(v);
                    } else {
                        const float sv = v / (1.f + __expf(-v));
                        const int zc = col - 2048;
                        ((u16*)Cptr2)[(((size_t)(zc >> 4)) * 2048 + row0 + j) * 16 + (zc & 15)]
                            = f2b(sv);
                    }
                }
            }
        }
    }
}

// combine split-K partials -> xdbr bf16 [2048,64] + bcp fp32 pair-packed:
// bcp[(t>>1)*64 + s*4 + (t&1)*2 + {0=B,1=C}]
__global__ __launch_bounds__(256) void xproj_combine(const float* __restrict__ part,
                                                     u16* __restrict__ xdbr,
                                                     float* __restrict__ bcp) {
    int i = blockIdx.x * 256 + threadIdx.x;     // over 2048*32
    int row = i >> 5, c4 = i & 31;
    if (c4 >= 24) return;
    float4 s = make_float4(0.f, 0.f, 0.f, 0.f);
#pragma unroll
    for (int p = 0; p < 8; ++p) {
        float4 v = ((const float4*)(part + (size_t)p * MROWS * 128 + (size_t)row * 128))[c4];
        s.x += v.x; s.y += v.y; s.z += v.z; s.w += v.w;
    }
    if (c4 < 16) {
        ((u16x4*)(xdbr + (size_t)row * 64))[c4] = f4_to_b4(s);
    } else {
        const int e0 = (c4 - 16) * 4;          // 0..31 over B(0..15)|C(16..31)
        float sv[4] = {s.x, s.y, s.z, s.w};
#pragma unroll
        for (int j = 0; j < 4; ++j) {
            const int e = e0 + j;
            const int st  = (e < 16) ? e : (e - 16);
            const int isc = (e < 16) ? 0 : 1;
            bcp[(size_t)(row >> 1) * 64 + st * 4 + (row & 1) * 2 + isc] = sv[j];
        }
    }
}

// ---------- selective scan: time-segmented, dt fused via MFMA ----------
__device__ __forceinline__ void compute_dtu_tile(const u16* __restrict__ xdbr,
                                                 const u16* __restrict__ Wdtb,
                                                 const float* __restrict__ b_dt,
                                                 const u16* __restrict__ utile,
                                                 float* __restrict__ du_s,
                                                 size_t t0, int d0, int w, int l) {
    const int fr = l & 15, fk = (l >> 4) * 8;
    const bf16x8 a0 = *(const bf16x8*)(xdbr + (t0 + w * 16 + fr) * 64 + fk);
    const bf16x8 a1 = *(const bf16x8*)(xdbr + (t0 + w * 16 + fr) * 64 + 32 + fk);
    const bf16x8 b0 = *(const bf16x8*)(Wdtb + (size_t)(d0 + fr) * 64 + fk);
    const bf16x8 b1 = *(const bf16x8*)(Wdtb + (size_t)(d0 + fr) * 64 + 32 + fk);
    const float bdt = b_dt[d0 + fr];
    f32x4 acc = {};
    acc = __builtin_amdgcn_mfma_f32_16x16x32_bf16(a0, b0, acc, 0, 0, 0);
    acc = __builtin_amdgcn_mfma_f32_16x16x32_bf16(a1, b1, acc, 0, 0, 0);
#pragma unroll
    for (int j = 0; j < 4; ++j) {
        const int row = w * 16 + (l >> 4) * 4 + j;
        float v = acc[j] + bdt;
        const float sp = flog2(1.f + fexp2(v * L2E)) * LN2;
        v = (v > 20.f) ? v : sp;
        const float uval = b2f(utile[(t0 + row) * 16 + fr]);
        float2 dv; dv.x = v; dv.y = v * uval;
        *(float2*)&du_s[(row >> 1) * 66 + fr * 4 + (row & 1) * 2] = dv;  // b64 write
    }
}

// stage bcp pair rows: 32 rows x 64 floats = 8KB, lane-linear per wave
__device__ __forceinline__ void stage_bc(const float* __restrict__ bcp,
                                         float* __restrict__ bc_s,
                                         size_t p0, int w, int l) {
    const int pr = (w << 3) + (l >> 4);
    const int pc = (l & 15) << 2;
    GLDS(bcp + (p0 + pr) * 64 + pc,     &bc_s[(w << 9)]);
    GLDS(bcp + (p0 + pr + 4) * 64 + pc, &bc_s[(w << 9) + 256]);
}

// grid (128, 2, 16): d-chunk, b, seg.  block 256.
__global__ __launch_bounds__(256) void scan_pass1(const u16* __restrict__ xdbr,
                                                  const u16* __restrict__ Wdtb,
                                                  const float* __restrict__ b_dt,
                                                  const u16* __restrict__ utl,
                                                  const float* __restrict__ bcp,
                                                  const float* __restrict__ A_log,
                                                  float* __restrict__ Qarr,
                                                  float* __restrict__ Sarr) {
    __shared__ __align__(16) float du_s[32 * 66];
    __shared__ __align__(16) float bc_s[32 * 64];

    const int tid = threadIdx.x;
    const int l   = tid & 63;
    const int w   = tid >> 6;
    const int s   = l & 15;
    const int g   = (w << 2) | (l >> 4);
    const int d0  = blockIdx.x << 4;
    const int b   = blockIdx.y;
    const int seg = blockIdx.z;
    const int d   = d0 + g;
    const size_t t0 = (size_t)b * 1024 + (size_t)seg * SEGT;
    const u16* utile = utl + (size_t)(d0 >> 4) * 2048 * 16;

    stage_bc(bcp, bc_s, t0 >> 1, w, l);
    compute_dtu_tile(xdbr, Wdtb, b_dt, utile, du_s, t0, d0, w, l);

    const float As2 = -__expf(A_log[d * 16 + s]) * L2E;
    asm volatile("s_waitcnt vmcnt(0) lgkmcnt(0)" ::: "memory");
    __builtin_amdgcn_s_barrier();

    float Q = 0.f, S = 0.f;
#pragma unroll 8
    for (int t2 = 0; t2 < 32; ++t2) {
        const float4 du4 = *(const float4*)&du_s[t2 * 66 + g * 4];
        const float4 BC2 = *(const float4*)&bc_s[t2 * 64 + s * 4];
        S += du4.x;
        Q = fexp2(du4.x * As2) * Q + du4.y * BC2.x;
        S += du4.z;
        Q = fexp2(du4.z * As2) * Q + du4.w * BC2.z;
    }
    Qarr[(((size_t)seg * 2 + b) * 2048 + d) * 16 + s] = Q;
    if (s == 0) Sarr[((size_t)seg * 2 + b) * 2048 + d] = S;
}

// prefix scan over segments: H0[i][b][d][s] = h entering segment i
__global__ __launch_bounds__(256) void scan_prefix(const float* __restrict__ Qarr,
                                                   const float* __restrict__ Sarr,
                                                   const float* __restrict__ A_log,
                                                   float* __restrict__ H0) {
    const int tid = threadIdx.x;
    const int d   = (blockIdx.x << 4) + (tid >> 4);
    const int s   = tid & 15;
    const int b   = blockIdx.y;
    const float As2 = -__expf(A_log[d * 16 + s]) * L2E;
    float h = 0.f;
#pragma unroll
    for (int i = 0; i < NSEG; ++i) {
        const size_t base = ((size_t)i * 2 + b) * 2048 + d;
        H0[base * 16 + s] = h;
        h = fexp2(As2 * Sarr[base]) * h + Qarr[base * 16 + s];
    }
}

__global__ __launch_bounds__(256) void scan_pass2(const u16* __restrict__ xdbr,
                                                  const u16* __restrict__ Wdtb,
                                                  const float* __restrict__ b_dt,
                                                  const u16* __restrict__ utl,
                                                  const float* __restrict__ bcp,
                                                  const u16* __restrict__ zst,
                                                  const float* __restrict__ A_log,
                                                  const float* __restrict__ Dp,
                                                  const float* __restrict__ H0,
                                                  u16* __restrict__ ymul) {
    __shared__ __align__(16) float du_s[32 * 66];   // overlaid by p_s after inner loop
    __shared__ __align__(16) float bc_s[32 * 64];
    __shared__ __align__(16) u16   u_s[1024];       // [64][16] bf16 u tile
    __shared__ __align__(16) u16   z_s[1024];       // [64][16] bf16 silu(z) tile

    const int tid = threadIdx.x;
    const int l   = tid & 63;
    const int w   = tid >> 6;
    const int s   = l & 15;
    const int g   = (w << 2) | (l >> 4);
    const int d0  = blockIdx.x << 4;
    const int b   = blockIdx.y;
    const int seg = blockIdx.z;
    const int d   = d0 + g;
    const size_t t0 = (size_t)b * 1024 + (size_t)seg * SEGT;
    const u16* utile = utl + (size_t)(d0 >> 4) * 2048 * 16;
    const u16* ztile = zst + (size_t)(d0 >> 4) * 2048 * 16;

    stage_bc(bcp, bc_s, t0 >> 1, w, l);
    if (w < 2)
        GLDS(utile + t0 * 16 + ((w & 1) * 64 + l) * 8, &u_s[(w & 1) << 9]);
    else
        GLDS(ztile + t0 * 16 + ((w & 1) * 64 + l) * 8, &z_s[(w & 1) << 9]);

    compute_dtu_tile(xdbr, Wdtb, b_dt, utile, du_s, t0, d0, w, l);

    const float As2 = -__expf(A_log[d * 16 + s]) * L2E;
    float h = H0[(((size_t)seg * 2 + b) * 2048 + d) * 16 + s];

    asm volatile("s_waitcnt vmcnt(0) lgkmcnt(0)" ::: "memory");
    __builtin_amdgcn_s_barrier();

    float pk[4];
#pragma unroll
    for (int c = 0; c < 4; ++c) {
        pk[c] = 0.f;
#pragma unroll
        for (int q = 0; q < 8; ++q) {
            const int t2 = c * 8 + q;
            const float4 du4 = *(const float4*)&du_s[t2 * 66 + g * 4];
            const float4 BC2 = *(const float4*)&bc_s[t2 * 64 + s * 4];
            // even t
            h = fexp2(du4.x * As2) * h + du4.y * BC2.x;
            float p = h * BC2.y;
            p = dpp_add<DPP_XOR1>(p);
            p = dpp_add<DPP_XOR2>(p);
            p = dpp_add<DPP_HMIR>(p);
            p = dpp_add<DPP_MIR>(p);
            {
                const unsigned long long km = 0x0001000100010001ULL << (2 * q);
                asm("v_cndmask_b32 %0, %0, %1, %2" : "+v"(pk[c]) : "v"(p), "s"(km));
            }
            // odd t
            h = fexp2(du4.z * As2) * h + du4.w * BC2.z;
            p = h * BC2.w;
            p = dpp_add<DPP_XOR1>(p);
            p = dpp_add<DPP_XOR2>(p);
            p = dpp_add<DPP_HMIR>(p);
            p = dpp_add<DPP_MIR>(p);
            {
                const unsigned long long km = 0x0001000100010001ULL << (2 * q + 1);
                asm("v_cndmask_b32 %0, %0, %1, %2" : "+v"(pk[c]) : "v"(p), "s"(km));
            }
        }
    }

    __builtin_amdgcn_s_barrier();    // all waves done reading du_s (reuse as p_s)
    float* p_s = du_s;
#pragma unroll
    for (int c = 0; c < 4; ++c) {
        const int row = c * 16 + s;
        p_s[row * 16 + (g ^ (row & 12))] = pk[c];
    }

    asm volatile("s_waitcnt lgkmcnt(0)" ::: "memory");
    __builtin_amdgcn_s_barrier();

    {
        const int tt = tid >> 2, cc = (tid & 3) << 2;
        const float4 pv = *(const float4*)&p_s[tt * 16 + (cc ^ (tt & 12))];
        const u16x4  uv = *(const u16x4*)&u_s[tt * 16 + cc];
        const u16x4  zs = *(const u16x4*)&z_s[tt * 16 + cc];
        const float4 Dv = *(const float4*)(Dp + d0 + cc);
        float4 o;
        o.x = (pv.x + b2f(uv.x) * Dv.x) * b2f(zs.x);
        o.y = (pv.y + b2f(uv.y) * Dv.y) * b2f(zs.y);
        o.z = (pv.z + b2f(uv.z) * Dv.z) * b2f(zs.z);
        o.w = (pv.w + b2f(uv.w) * Dv.w) * b2f(zs.w);
        *(u16x4*)(ymul + (t0 + tt) * 2048 + d0 + cc) = f4_to_b4(o);
    }
}

// out = x2 + b2 + sum of 4 partials   [2048,1024] fp32
__global__ __launch_bounds__(256) void ffn2_combine(const float* __restrict__ part,
                                                    const float* __restrict__ x2,
                                                    const float* __restrict__ b2,
                                                    float* __restrict__ out) {
    int i = blockIdx.x * 256 + threadIdx.x;    // over 2048*256
    float4 s = ((const float4*)x2)[i];
    float4 bv = ((const float4*)b2)[i & 255];
    s.x += bv.x; s.y += bv.y; s.z += bv.z; s.w += bv.w;
#pragma unroll
    for (int p = 0; p < 4; ++p) {
        float4 v = ((const float4*)(part + (size_t)p * MROWS * 1024))[i];
        s.x += v.x; s.y += v.y; s.z += v.z; s.w += v.w;
    }
    ((float4*)out)[i] = s;
}

// x2 = x + part0 + part1; h2 = LN2(x2) bf16.   one block per row.
__global__ __launch_bounds__(256) void outproj_combine_ln2(const float* __restrict__ x,
                                                           const float* __restrict__ part,
                                                           const float* __restrict__ w,
                                                           const float* __restrict__ b,
                                                           float* __restrict__ x2,
                                                           u16* __restrict__ h2) {
    const int row = blockIdx.x;
    const int tid = threadIdx.x;
    float4 v = ((const float4*)(x + (size_t)row * 1024))[tid];
    float4 p0 = ((const float4*)(part + (size_t)row * 1024))[tid];
    float4 p1 = ((const float4*)(part + (size_t)MROWS * 1024 + (size_t)row * 1024))[tid];
    v.x += p0.x + p1.x; v.y += p0.y + p1.y; v.z += p0.z + p1.z; v.w += p0.w + p1.w;
    ((float4*)(x2 + (size_t)row * 1024))[tid] = v;
    float s = v.x + v.y + v.z + v.w;
    float q = v.x * v.x + v.y * v.y + v.z * v.z + v.w * v.w;
#pragma unroll
    for (int off = 1; off < 64; off <<= 1) {
        s += __shfl_xor(s, off, 64);
        q += __shfl_xor(q, off, 64);
    }
    __shared__ float ss[4], qq[4];
    const int wave = tid >> 6;
    if ((tid & 63) == 0) { ss[wave] = s; qq[wave] = q; }
    __syncthreads();
    s = ss[0] + ss[1] + ss[2] + ss[3];
    q = qq[0] + qq[1] + qq[2] + qq[3];
    const float mean = s * (1.f / 1024.f);
    const float var  = q * (1.f / 1024.f) - mean * mean;
    const float rstd = rsqrtf(var + 1e-5f);
    const float4 wv = ((const float4*)w)[tid];
    const float4 bv = ((const float4*)b)[tid];
    float4 o;
    o.x = (v.x - mean) * rstd * wv.x + bv.x;
    o.y = (v.y - mean) * rstd * wv.y + bv.y;
    o.z = (v.z - mean) * rstd * wv.z + bv.z;
    o.w = (v.w - mean) * rstd * wv.w + bv.w;
    ((u16x4*)(h2 + (size_t)row * 1024))[tid] = f4_to_b4(o);
}

// ---------- host launcher ----------
extern "C" void kernel_launch(void* const* d_in, const int* in_sizes, int n_in,
                              void* d_out, int out_size, void* d_ws, size_t ws_size,
                              hipStream_t stream) {
    const float* x      = (const float*)d_in[0];
    const float* ln1_w  = (const float*)d_in[1];
    const float* ln1_b  = (const float*)d_in[2];
    const float* W_in   = (const float*)d_in[3];
    const float* conv_w = (const float*)d_in[4];
    const float* conv_b = (const float*)d_in[5];
    const float* W_xproj= (const float*)d_in[6];
    const float* W_dt   = (const float*)d_in[7];
    const float* b_dt   = (const float*)d_in[8];
    const float* A_log  = (const float*)d_in[9];
    const float* Dvec   = (const float*)d_in[10];
    const float* W_out  = (const float*)d_in[11];
    const float* ln2_w  = (const float*)d_in[12];
    const float* ln2_b  = (const float*)d_in[13];
    const float* W1     = (const float*)d_in[14];
    const float* b1     = (const float*)d_in[15];
    const float* W2     = (const float*)d_in[16];
    const float* b2     = (const float*)d_in[17];
    float* out = (float*)d_out;
    char*  ws  = (char*)d_ws;
    const size_t MB = 1024ull * 1024ull;

    u16*   h1b   = (u16*)(ws + 0);              // 4 MB (reused as h2b)
    u16*   xzu   = (u16*)(ws + 4 * MB);         // 8 MB  [2048,2048] bf16 (u pre-conv)
    u16*   zst   = (u16*)(ws + 12 * MB);        // 8 MB  tiled silu(z) [128][2048][16]
    u16*   upb   = (u16*)(ws + 20 * MB);        // 8 MB  row-major u (xproj GEMM)
    u16*   utl   = (u16*)(ws + 28 * MB);        // 8 MB  tiled u [128][2048][16]
    float* parts = (float*)(ws + 36 * MB);      // 8 MB  [8][2048][128] fp32
    float* bcp   = (float*)(ws + 44 * MB);      // 256 KB [1024 pairs][64]
    u16*   xdbr  = (u16*)(ws + 44 * MB + 256 * 1024);  // 256 KB
    u16*   Wdtb  = (u16*)(ws + 44 * MB + 512 * 1024);  // 256 KB
    u16*   ymul  = (u16*)(ws + 45 * MB);        // 8 MB
    float* Qarr  = (float*)(ws + 53 * MB);      // 4 MB  [16][2][2048][16]
    float* Sarr  = (float*)(ws + 57 * MB);      // 256 KB
    float* H0    = (float*)(ws + 58 * MB);      // 4 MB  [16][2][2048][16]
    float* x2    = (float*)(ws + 62 * MB);      // 8 MB
    u16*   Winb  = (u16*)(ws + 70 * MB);        // 8 MB
    u16*   Woutb = (u16*)(ws + 78 * MB);        // 4 MB
    u16*   W1b   = (u16*)(ws + 82 * MB);        // 8 MB
    u16*   W2b   = (u16*)(ws + 90 * MB);        // 8 MB
    u16*   Wxpb  = (u16*)(ws + 98 * MB);        // 512 KB
    u16*   h2b   = h1b;
    float* opart = (float*)(ws + 4 * MB);       // 16 MB (xzu+zst dead after pass2)
    u16*   f1    = (u16*)(ws + 4 * MB);         // 16 MB (opart dead after combine_ln2)
    float* fpart = (float*)(ws + 20 * MB);      // 32 MB (upb..parts dead by FFN2)

    // weight conversions (independent)
    cvt_kernel<<<4096, 256, 0, stream>>>(W_in,  Winb,  4096 * 1024 / 4);
    cvt_kernel<<<2048, 256, 0, stream>>>(W_out, Woutb, 1024 * 2048 / 4);
    cvt_kernel<<<4096, 256, 0, stream>>>(W1,    W1b,   4096 * 1024 / 4);
    cvt_kernel<<<4096, 256, 0, stream>>>(W2,    W2b,   1024 * 4096 / 4);
    cvt_kernel<<<128,  256, 0, stream>>>(W_dt,  Wdtb,  2048 * 64 / 4);
    pad_xproj_kernel<<<256, 256, 0, stream>>>(W_xproj, Wxpb);

    // LN1 -> h1 (bf16)
    ln_kernel<<<2048, 256, 0, stream>>>(x, ln1_w, ln1_b, h1b);
    // xz = h1 @ W_in^T : u-half -> bf16 xzu, z-half -> silu -> TILED zst bf16
    // 64x128 tiles: grid (32,32) = 1024 blocks = 4 blocks/CU
    gemm_a64<5><<<dim3(32, 32), 256, 0, stream>>>(h1b, Winb, xzu, zst, nullptr,
                                                  MROWS, 4096, 1024);
    // depthwise conv + silu -> u (row-major + tiled)
    conv_kernel<<<4096, 256, 0, stream>>>(xzu, conv_w, conv_b, upb, utl);
    // xproj split-K (8 x K=256) -> partials -> combine (pair-packed bcp)
    gemm_tb<<<dim3(16, 1, 8), 256, 0, stream>>>(upb, Wxpb, parts, MROWS, 128, 2048, 256);
    xproj_combine<<<256, 256, 0, stream>>>(parts, xdbr, bcp);
    // selective scan: per-segment states -> prefix -> in-segment scan
    scan_pass1<<<dim3(128, 2, NSEG), 256, 0, stream>>>(xdbr, Wdtb, b_dt, utl, bcp, A_log,
                                                       Qarr, Sarr);
    scan_prefix<<<dim3(128, 2), 256, 0, stream>>>(Qarr, Sarr, A_log, H0);
    scan_pass2<<<dim3(128, 2, NSEG), 256, 0, stream>>>(xdbr, Wdtb, b_dt, utl, bcp, zst,
                                                       A_log, Dvec, H0, ymul);
    // out-proj split-K (2 x K=1024) -> partials; combine + residual + LN2 fused
    gemm_tb<<<dim3(16, 8, 2), 256, 0, stream>>>(ymul, Woutb, opart, MROWS, 1024, 2048, 1024);
    outproj_combine_ln2<<<2048, 256, 0, stream>>>(x, opart, ln2_w, ln2_b, x2, h2b);
    // f1 = relu(h2 @ W1^T + b1)  bf16 [2048,4096]  (64x128 tiles)
    gemm_a64<3><<<dim3(32, 32), 256, 0, stream>>>(h2b, W1b, f1, nullptr, b1,
                                                  MROWS, 4096, 1024);
    // FFN2 split-K (4 x K=1024) -> partials; combine + bias + residual
    gemm_tb<<<dim3(16, 8, 4), 256, 0, stream>>>(f1, W2b, fpart, MROWS, 1024, 4096, 1024);
    ffn2_combine<<<2048, 256, 0, stream>>>(fpart, x2, b2, out);
}

// Round 13
// 226.208 us; speedup vs baseline: 1.0737x; 1.0737x over previous
//
#include <hip/hip_runtime.h>

typedef unsigned short u16;
typedef unsigned int   u32;
typedef short   bf16x8 __attribute__((ext_vector_type(8)));
typedef float   f32x4  __attribute__((ext_vector_type(4)));
typedef u16     u16x4  __attribute__((ext_vector_type(4)));

// ---------- bf16 helpers (RNE) ----------
__device__ __forceinline__ u16 f2b(float f) {
    u32 u = __builtin_bit_cast(u32, f);
    u32 r = u + 0x7FFFu + ((u >> 16) & 1u);
    return (u16)(r >> 16);
}
__device__ __forceinline__ float b2f(u16 h) {
    u32 u = ((u32)h) << 16;
    return __builtin_bit_cast(float, u);
}
__device__ __forceinline__ u16x4 f4_to_b4(float4 v) {
    u16x4 o; o.x = f2b(v.x); o.y = f2b(v.y); o.z = f2b(v.z); o.w = f2b(v.w);
    return o;
}

// native transcendentals: single-instruction v_exp_f32 / v_log_f32
__device__ __forceinline__ float fexp2(float x) {
    float r;
    asm("v_exp_f32 %0, %1" : "=v"(r) : "v"(x));
    return r;
}
__device__ __forceinline__ float flog2(float x) {
    float r;
    asm("v_log_f32 %0, %1" : "=v"(r) : "v"(x));
    return r;
}

// DPP add: p += p[lane permuted by CTRL]  (pure VALU, no DS pipe)
template <int CTRL>
__device__ __forceinline__ float dpp_add(float p) {
    int pi = __builtin_bit_cast(int, p);
    int q  = __builtin_amdgcn_update_dpp(pi, pi, CTRL, 0xF, 0xF, false);
    return p + __builtin_bit_cast(float, q);
}
#define DPP_XOR1 0xB1   // quad_perm [1,0,3,2]
#define DPP_XOR2 0x4E   // quad_perm [2,3,0,1]
#define DPP_HMIR 0x141  // row_half_mirror (lane^7)
#define DPP_MIR  0x140  // row_mirror      (lane^15)

// ---------- constants ----------
#define MROWS   2048   // B*L
#define NSEG    16
#define SEGT    64
#define L2E     1.44269504088896340736f
#define LN2     0.69314718055994530942f

#define GLDS(g, l) __builtin_amdgcn_global_load_lds(                      \
    (const __attribute__((address_space(1))) void*)(g),                   \
    (__attribute__((address_space(3))) void*)(l), 16, 0, 0)

// ---------- merged fp32 -> bf16 weight conversion ----------
// segments (float4 units, all block-aligned): W_in 1048576 | W_out 524288 |
// W1 1048576 | W2 1048576 | W_dt 32768  => total 3702784 = 14464 * 256
__global__ __launch_bounds__(256) void cvt_all(const float* __restrict__ W_in,
                                               const float* __restrict__ W_out,
                                               const float* __restrict__ W1,
                                               const float* __restrict__ W2,
                                               const float* __restrict__ W_dt,
                                               u16* __restrict__ Winb,
                                               u16* __restrict__ Woutb,
                                               u16* __restrict__ W1b,
                                               u16* __restrict__ W2b,
                                               u16* __restrict__ Wdtb) {
    const int i = blockIdx.x * 256 + threadIdx.x;
    const float* src; u16* dst; int off;
    if (i < 1048576)      { src = W_in;  dst = Winb;  off = i; }
    else if (i < 1572864) { src = W_out; dst = Woutb; off = i - 1048576; }
    else if (i < 2621440) { src = W1;    dst = W1b;   off = i - 1572864; }
    else if (i < 3670016) { src = W2;    dst = W2b;   off = i - 2621440; }
    else                  { src = W_dt;  dst = Wdtb;  off = i - 3670016; }
    float4 v = ((const float4*)src)[off];
    ((u16x4*)dst)[off] = f4_to_b4(v);
}

// pad W_xproj (96 x 2048) -> bf16 (128 x 2048), rows 96..127 = 0
__global__ __launch_bounds__(256) void pad_xproj_kernel(const float* __restrict__ in,
                                                        u16* __restrict__ out) {
    int i = blockIdx.x * 256 + threadIdx.x;    // over 128*512
    int r = i >> 9, c4 = i & 511;
    float4 v = make_float4(0.f, 0.f, 0.f, 0.f);
    if (r < 96) v = ((const float4*)(in + (size_t)r * 2048))[c4];
    ((u16x4*)(out + (size_t)r * 2048))[c4] = f4_to_b4(v);
}

// ---------- LayerNorm (row = 1024 cols), fp32 in -> bf16 out ----------
__global__ __launch_bounds__(256) void ln_kernel(const float* __restrict__ x,
                                                 const float* __restrict__ w,
                                                 const float* __restrict__ b,
                                                 u16* __restrict__ out) {
    const int row = blockIdx.x;
    const int tid = threadIdx.x;
    const float4 v = ((const float4*)(x + (size_t)row * 1024))[tid];
    float s = v.x + v.y + v.z + v.w;
    float q = v.x * v.x + v.y * v.y + v.z * v.z + v.w * v.w;
#pragma unroll
    for (int off = 1; off < 64; off <<= 1) {
        s += __shfl_xor(s, off, 64);
        q += __shfl_xor(q, off, 64);
    }
    __shared__ float ss[4], qq[4];
    const int wave = tid >> 6;
    if ((tid & 63) == 0) { ss[wave] = s; qq[wave] = q; }
    __syncthreads();
    s = ss[0] + ss[1] + ss[2] + ss[3];
    q = qq[0] + qq[1] + qq[2] + qq[3];
    const float mean = s * (1.f / 1024.f);
    const float var  = q * (1.f / 1024.f) - mean * mean;
    const float rstd = rsqrtf(var + 1e-5f);
    const float4 wv = ((const float4*)w)[tid];
    const float4 bv = ((const float4*)b)[tid];
    float4 o;
    o.x = (v.x - mean) * rstd * wv.x + bv.x;
    o.y = (v.y - mean) * rstd * wv.y + bv.y;
    o.z = (v.z - mean) * rstd * wv.z + bv.z;
    o.w = (v.w - mean) * rstd * wv.w + bv.w;
    ((u16x4*)(out + (size_t)row * 1024))[tid] = f4_to_b4(o);
}

// ---------- depthwise causal conv + bias + silu (bf16 in) -> tiled utl only ----------
__global__ __launch_bounds__(256) void conv_kernel(const u16* __restrict__ xzu,
                                                   const float* __restrict__ cw,
                                                   const float* __restrict__ cb,
                                                   u16* __restrict__ utl) {
    const int idx = blockIdx.x * 256 + threadIdx.x;   // over 2048 rows * 512 d4
    const int row = idx >> 9;
    const int d4  = idx & 511;
    const int d   = d4 * 4;
    const int bb  = row >> 10;
    const int t   = row & 1023;
    float w0[4], w1[4], w2[4], w3[4];
    *(float4*)w0 = ((const float4*)cw)[d + 0];
    *(float4*)w1 = ((const float4*)cw)[d + 1];
    *(float4*)w2 = ((const float4*)cw)[d + 2];
    *(float4*)w3 = ((const float4*)cw)[d + 3];
    float4 a = ((const float4*)cb)[d4];
#pragma unroll
    for (int j = 0; j < 4; ++j) {
        const int tt = t - 3 + j;
        if (tt >= 0) {
            const u16x4 uv = *(const u16x4*)(xzu + ((size_t)(bb * 1024 + tt)) * 2048 + d);
            a.x += b2f(uv.x) * w0[j];
            a.y += b2f(uv.y) * w1[j];
            a.z += b2f(uv.z) * w2[j];
            a.w += b2f(uv.w) * w3[j];
        }
    }
    float4 o;
    o.x = a.x / (1.f + __expf(-a.x));
    o.y = a.y / (1.f + __expf(-a.y));
    o.z = a.z / (1.f + __expf(-a.z));
    o.w = a.w / (1.f + __expf(-a.w));
    *(u16x4*)(utl + (((size_t)(d >> 4)) * 2048 + row) * 16 + (d & 15)) = f4_to_b4(o);
}

// ---------- unified triple-buffered GEMM 128x128 (XCD-swizzled) ----------
// EPI: 3 = relu(c+bias) bf16; 5 = xz split (u -> bf16 row-major / silu(z) -> TILED zst);
//      10 = split-K partial fp32
template <int EPI>
__global__ __launch_bounds__(256) void gemm_tb(const u16* __restrict__ A,
                                               const u16* __restrict__ Bw,
                                               void* __restrict__ Cptr,
                                               void* __restrict__ Cptr2,
                                               const float* __restrict__ bias,
                                               int M, int N, int K, int KS) {
    const int nbm = gridDim.x, nbn = gridDim.y;
    const int nwg = nbm * nbn;
    const int id  = blockIdx.x + nbm * blockIdx.y;
    const int sw  = (nwg >= 8) ? ((id & 7) * (nwg >> 3) + (id >> 3)) : id;
    const int bm  = sw % nbm, bn = sw / nbm;

    __shared__ u16 Asm[3][128 * 32];
    __shared__ u16 Bsm[3][128 * 32];
    const int tid  = threadIdx.x;
    const int kz   = blockIdx.z;
    const int lane = tid & 63;
    const int wave = tid >> 6;
    const int wm   = wave >> 1, wn = wave & 1;
    const u16* Ag = A  + (size_t)bm * 128 * K;
    const u16* Bg = Bw + (size_t)bn * 128 * K;
    const int r0 = tid >> 2;
    const int r1 = r0 + 64;
    const int sg = (tid & 3) * 8;
    const int k0 = kz * KS;
    const int nk = KS >> 5;
    const int fr = lane & 15, fk = (lane >> 4) * 8;

#define STG(bf, kk)                                                            \
    {                                                                          \
        const int kof = k0 + (kk) * 32;                                        \
        GLDS(Ag + (size_t)r0 * K + kof + sg, &Asm[bf][tid * 8]);               \
        GLDS(Ag + (size_t)r1 * K + kof + sg, &Asm[bf][(tid + 256) * 8]);       \
        GLDS(Bg + (size_t)r0 * K + kof + sg, &Bsm[bf][tid * 8]);               \
        GLDS(Bg + (size_t)r1 * K + kof + sg, &Bsm[bf][(tid + 256) * 8]);       \
    }

    f32x4 acc[4][4] = {};
    STG(0, 0); STG(1, 1); STG(2, 2);
    int buf = 0;
    for (int k = 0; k < nk; ++k) {
        if (k < nk - 2)       asm volatile("s_waitcnt vmcnt(8)" ::: "memory");
        else if (k == nk - 2) asm volatile("s_waitcnt vmcnt(4)" ::: "memory");
        else                  asm volatile("s_waitcnt vmcnt(0)" ::: "memory");
        __builtin_amdgcn_s_barrier();
        bf16x8 a[4], b[4];
#pragma unroll
        for (int m = 0; m < 4; ++m)
            a[m] = *(const bf16x8*)&Asm[buf][(wm * 64 + m * 16 + fr) * 32 + fk];
#pragma unroll
        for (int n = 0; n < 4; ++n)
            b[n] = *(const bf16x8*)&Bsm[buf][(wn * 64 + n * 16 + fr) * 32 + fk];
        asm volatile("s_waitcnt lgkmcnt(0)" ::: "memory");
        __builtin_amdgcn_s_barrier();
        if (k + 3 < nk) STG(buf, k + 3);
#pragma unroll
        for (int m = 0; m < 4; ++m)
#pragma unroll
            for (int n = 0; n < 4; ++n)
                acc[m][n] = __builtin_amdgcn_mfma_f32_16x16x32_bf16(a[m], b[n], acc[m][n], 0, 0, 0);
        buf = (buf == 2) ? 0 : buf + 1;
    }
#undef STG

    const int fq = lane >> 4;
#pragma unroll
    for (int m = 0; m < 4; ++m) {
#pragma unroll
        for (int n = 0; n < 4; ++n) {
            const int row0 = bm * 128 + wm * 64 + m * 16 + fq * 4;
            const int col  = bn * 128 + wn * 64 + n * 16 + fr;
#pragma unroll
            for (int j = 0; j < 4; ++j) {
                float v = acc[m][n][j];
                if constexpr (EPI == 3) {
                    v += bias[col];
                    ((u16*)Cptr)[(size_t)(row0 + j) * N + col] = f2b(fmaxf(v, 0.f));
                } else if constexpr (EPI == 5) {
                    if (col < 2048) {
                        ((u16*)Cptr)[(size_t)(row0 + j) * 2048 + col] = f2b(v);
                    } else {
                        const float sv = v / (1.f + __expf(-v));
                        const int zc = col - 2048;
                        ((u16*)Cptr2)[(((size_t)(zc >> 4)) * 2048 + row0 + j) * 16 + (zc & 15)]
                            = f2b(sv);
                    }
                } else {   // 10: split-K partial
                    ((float*)Cptr)[(size_t)kz * M * N + (size_t)(row0 + j) * N + col] = v;
                }
            }
        }
    }
}

// ---------- xproj GEMM: A read from TILED utl [128 chunks][2048 rows][16] ----------
// grid (16, 1, 8): bm, -, kz (K-slice 256).  Partials out.
__global__ __launch_bounds__(256) void gemm_xp(const u16* __restrict__ utl,
                                               const u16* __restrict__ Bw,
                                               float* __restrict__ part) {
    const int nwg = 16;
    const int id  = blockIdx.x;
    const int sw  = (id & 7) * (nwg >> 3) + (id >> 3);
    const int bm  = sw;
    __shared__ u16 Asm[3][128 * 32];
    __shared__ u16 Bsm[3][128 * 32];
    const int tid  = threadIdx.x;
    const int kz   = blockIdx.z;
    const int lane = tid & 63;
    const int wave = tid >> 6;
    const int wm   = wave >> 1, wn = wave & 1;
    const u16* Bg = Bw;
    const int r0 = tid >> 2;             // 0..63
    const int pc = tid & 3;              // K-piece 0..3 (8 u16 each)
    const int sg = pc * 8;
    const int k0 = kz * 256;
    const int fr = lane & 15, fk = (lane >> 4) * 8;

#define STGX(bf, kk)                                                                     \
    {                                                                                    \
        const int kof = k0 + (kk) * 32;                                                  \
        const int kc  = kof >> 4;                                                        \
        GLDS(utl + ((size_t)(kc + (pc >> 1)) * 2048 + bm * 128 + r0) * 16 + (pc & 1) * 8,\
             &Asm[bf][tid * 8]);                                                         \
        GLDS(utl + ((size_t)(kc + (pc >> 1)) * 2048 + bm * 128 + r0 + 64) * 16 + (pc & 1) * 8,\
             &Asm[bf][(tid + 256) * 8]);                                                 \
        GLDS(Bg + (size_t)r0 * 2048 + kof + sg, &Bsm[bf][tid * 8]);                      \
        GLDS(Bg + (size_t)(r0 + 64) * 2048 + kof + sg, &Bsm[bf][(tid + 256) * 8]);       \
    }

    f32x4 acc[4][4] = {};
    STGX(0, 0); STGX(1, 1); STGX(2, 2);
    int buf = 0;
    const int nk = 8;
    for (int k = 0; k < nk; ++k) {
        if (k < nk - 2)       asm volatile("s_waitcnt vmcnt(8)" ::: "memory");
        else if (k == nk - 2) asm volatile("s_waitcnt vmcnt(4)" ::: "memory");
        else                  asm volatile("s_waitcnt vmcnt(0)" ::: "memory");
        __builtin_amdgcn_s_barrier();
        bf16x8 a[4], b[4];
#pragma unroll
        for (int m = 0; m < 4; ++m)
            a[m] = *(const bf16x8*)&Asm[buf][(wm * 64 + m * 16 + fr) * 32 + fk];
#pragma unroll
        for (int n = 0; n < 4; ++n)
            b[n] = *(const bf16x8*)&Bsm[buf][(wn * 64 + n * 16 + fr) * 32 + fk];
        asm volatile("s_waitcnt lgkmcnt(0)" ::: "memory");
        __builtin_amdgcn_s_barrier();
        if (k + 3 < nk) STGX(buf, k + 3);
#pragma unroll
        for (int m = 0; m < 4; ++m)
#pragma unroll
            for (int n = 0; n < 4; ++n)
                acc[m][n] = __builtin_amdgcn_mfma_f32_16x16x32_bf16(a[m], b[n], acc[m][n], 0, 0, 0);
        buf = (buf == 2) ? 0 : buf + 1;
    }
#undef STGX

    const int fq = lane >> 4;
    float* Cp = part + (size_t)kz * MROWS * 128;
#pragma unroll
    for (int m = 0; m < 4; ++m) {
#pragma unroll
        for (int n = 0; n < 4; ++n) {
            const int row0 = bm * 128 + wm * 64 + m * 16 + fq * 4;
            const int col  = wn * 64 + n * 16 + fr;
#pragma unroll
            for (int j = 0; j < 4; ++j)
                Cp[(size_t)(row0 + j) * 128 + col] = acc[m][n][j];
        }
    }
}

// combine split-K partials -> xdbr bf16 [2048,64] + bcp fp32 pair-packed:
// bcp[(t>>1)*64 + s*4 + (t&1)*2 + {0=B,1=C}]
__global__ __launch_bounds__(256) void xproj_combine(const float* __restrict__ part,
                                                     u16* __restrict__ xdbr,
                                                     float* __restrict__ bcp) {
    int i = blockIdx.x * 256 + threadIdx.x;     // over 2048*32
    int row = i >> 5, c4 = i & 31;
    if (c4 >= 24) return;
    float4 s = make_float4(0.f, 0.f, 0.f, 0.f);
#pragma unroll
    for (int p = 0; p < 8; ++p) {
        float4 v = ((const float4*)(part + (size_t)p * MROWS * 128 + (size_t)row * 128))[c4];
        s.x += v.x; s.y += v.y; s.z += v.z; s.w += v.w;
    }
    if (c4 < 16) {
        ((u16x4*)(xdbr + (size_t)row * 64))[c4] = f4_to_b4(s);
    } else {
        const int e0 = (c4 - 16) * 4;          // 0..31 over B(0..15)|C(16..31)
        float sv[4] = {s.x, s.y, s.z, s.w};
#pragma unroll
        for (int j = 0; j < 4; ++j) {
            const int e = e0 + j;
            const int st  = (e < 16) ? e : (e - 16);
            const int isc = (e < 16) ? 0 : 1;
            bcp[(size_t)(row >> 1) * 64 + st * 4 + (row & 1) * 2 + isc] = sv[j];
        }
    }
}

// ---------- selective scan: time-segmented, dt fused via MFMA ----------
__device__ __forceinline__ void compute_dtu_tile(const u16* __restrict__ xdbr,
                                                 const u16* __restrict__ Wdtb,
                                                 const float* __restrict__ b_dt,
                                                 const u16* __restrict__ utile,
                                                 float* __restrict__ du_s,
                                                 size_t t0, int d0, int w, int l) {
    const int fr = l & 15, fk = (l >> 4) * 8;
    const bf16x8 a0 = *(const bf16x8*)(xdbr + (t0 + w * 16 + fr) * 64 + fk);
    const bf16x8 a1 = *(const bf16x8*)(xdbr + (t0 + w * 16 + fr) * 64 + 32 + fk);
    const bf16x8 b0 = *(const bf16x8*)(Wdtb + (size_t)(d0 + fr) * 64 + fk);
    const bf16x8 b1 = *(const bf16x8*)(Wdtb + (size_t)(d0 + fr) * 64 + 32 + fk);
    const float bdt = b_dt[d0 + fr];
    f32x4 acc = {};
    acc = __builtin_amdgcn_mfma_f32_16x16x32_bf16(a0, b0, acc, 0, 0, 0);
    acc = __builtin_amdgcn_mfma_f32_16x16x32_bf16(a1, b1, acc, 0, 0, 0);
#pragma unroll
    for (int j = 0; j < 4; ++j) {
        const int row = w * 16 + (l >> 4) * 4 + j;
        float v = acc[j] + bdt;
        const float sp = flog2(1.f + fexp2(v * L2E)) * LN2;
        v = (v > 20.f) ? v : sp;
        const float uval = b2f(utile[(t0 + row) * 16 + fr]);
        float2 dv; dv.x = v; dv.y = v * uval;
        *(float2*)&du_s[(row >> 1) * 66 + fr * 4 + (row & 1) * 2] = dv;  // b64 write
    }
}

// stage bcp pair rows: 32 rows x 64 floats = 8KB, lane-linear per wave
__device__ __forceinline__ void stage_bc(const float* __restrict__ bcp,
                                         float* __restrict__ bc_s,
                                         size_t p0, int w, int l) {
    const int pr = (w << 3) + (l >> 4);
    const int pc = (l & 15) << 2;
    GLDS(bcp + (p0 + pr) * 64 + pc,     &bc_s[(w << 9)]);
    GLDS(bcp + (p0 + pr + 4) * 64 + pc, &bc_s[(w << 9) + 256]);
}

// grid (128, 2, 16): d-chunk, b, seg.  block 256.
__global__ __launch_bounds__(256) void scan_pass1(const u16* __restrict__ xdbr,
                                                  const u16* __restrict__ Wdtb,
                                                  const float* __restrict__ b_dt,
                                                  const u16* __restrict__ utl,
                                                  const float* __restrict__ bcp,
                                                  const float* __restrict__ A_log,
                                                  float* __restrict__ Qarr,
                                                  float* __restrict__ Sarr) {
    __shared__ __align__(16) float du_s[32 * 66];
    __shared__ __align__(16) float bc_s[32 * 64];

    const int tid = threadIdx.x;
    const int l   = tid & 63;
    const int w   = tid >> 6;
    const int s   = l & 15;
    const int g   = (w << 2) | (l >> 4);
    const int d0  = blockIdx.x << 4;
    const int b   = blockIdx.y;
    const int seg = blockIdx.z;
    const int d   = d0 + g;
    const size_t t0 = (size_t)b * 1024 + (size_t)seg * SEGT;
    const u16* utile = utl + (size_t)(d0 >> 4) * 2048 * 16;

    stage_bc(bcp, bc_s, t0 >> 1, w, l);
    compute_dtu_tile(xdbr, Wdtb, b_dt, utile, du_s, t0, d0, w, l);

    const float As2 = -__expf(A_log[d * 16 + s]) * L2E;
    asm volatile("s_waitcnt vmcnt(0) lgkmcnt(0)" ::: "memory");
    __builtin_amdgcn_s_barrier();

    float Q = 0.f, S = 0.f;
#pragma unroll 8
    for (int t2 = 0; t2 < 32; ++t2) {
        const float4 du4 = *(const float4*)&du_s[t2 * 66 + g * 4];
        const float4 BC2 = *(const float4*)&bc_s[t2 * 64 + s * 4];
        S += du4.x;
        Q = fexp2(du4.x * As2) * Q + du4.y * BC2.x;
        S += du4.z;
        Q = fexp2(du4.z * As2) * Q + du4.w * BC2.z;
    }
    Qarr[(((size_t)seg * 2 + b) * 2048 + d) * 16 + s] = Q;
    if (s == 0) Sarr[((size_t)seg * 2 + b) * 2048 + d] = S;
}

// prefix scan over segments: H0[i][b][d][s] = h entering segment i
__global__ __launch_bounds__(256) void scan_prefix(const float* __restrict__ Qarr,
                                                   const float* __restrict__ Sarr,
                                                   const float* __restrict__ A_log,
                                                   float* __restrict__ H0) {
    const int tid = threadIdx.x;
    const int d   = (blockIdx.x << 4) + (tid >> 4);
    const int s   = tid & 15;
    const int b   = blockIdx.y;
    const float As2 = -__expf(A_log[d * 16 + s]) * L2E;
    float h = 0.f;
#pragma unroll
    for (int i = 0; i < NSEG; ++i) {
        const size_t base = ((size_t)i * 2 + b) * 2048 + d;
        H0[base * 16 + s] = h;
        h = fexp2(As2 * Sarr[base]) * h + Qarr[base * 16 + s];
    }
}

__global__ __launch_bounds__(256) void scan_pass2(const u16* __restrict__ xdbr,
                                                  const u16* __restrict__ Wdtb,
                                                  const float* __restrict__ b_dt,
                                                  const u16* __restrict__ utl,
                                                  const float* __restrict__ bcp,
                                                  const u16* __restrict__ zst,
                                                  const float* __restrict__ A_log,
                                                  const float* __restrict__ Dp,
                                                  const float* __restrict__ H0,
                                                  u16* __restrict__ ymul) {
    __shared__ __align__(16) float du_s[32 * 66];   // overlaid by p_s after inner loop
    __shared__ __align__(16) float bc_s[32 * 64];
    __shared__ __align__(16) u16   u_s[1024];       // [64][16] bf16 u tile
    __shared__ __align__(16) u16   z_s[1024];       // [64][16] bf16 silu(z) tile

    const int tid = threadIdx.x;
    const int l   = tid & 63;
    const int w   = tid >> 6;
    const int s   = l & 15;
    const int g   = (w << 2) | (l >> 4);
    const int d0  = blockIdx.x << 4;
    const int b   = blockIdx.y;
    const int seg = blockIdx.z;
    const int d   = d0 + g;
    const size_t t0 = (size_t)b * 1024 + (size_t)seg * SEGT;
    const u16* utile = utl + (size_t)(d0 >> 4) * 2048 * 16;
    const u16* ztile = zst + (size_t)(d0 >> 4) * 2048 * 16;

    stage_bc(bcp, bc_s, t0 >> 1, w, l);
    if (w < 2)
        GLDS(utile + t0 * 16 + ((w & 1) * 64 + l) * 8, &u_s[(w & 1) << 9]);
    else
        GLDS(ztile + t0 * 16 + ((w & 1) * 64 + l) * 8, &z_s[(w & 1) << 9]);

    compute_dtu_tile(xdbr, Wdtb, b_dt, utile, du_s, t0, d0, w, l);

    const float As2 = -__expf(A_log[d * 16 + s]) * L2E;
    float h = H0[(((size_t)seg * 2 + b) * 2048 + d) * 16 + s];

    asm volatile("s_waitcnt vmcnt(0) lgkmcnt(0)" ::: "memory");
    __builtin_amdgcn_s_barrier();

    float pk[4];
#pragma unroll
    for (int c = 0; c < 4; ++c) {
        pk[c] = 0.f;
#pragma unroll
        for (int q = 0; q < 8; ++q) {
            const int t2 = c * 8 + q;
            const float4 du4 = *(const float4*)&du_s[t2 * 66 + g * 4];
            const float4 BC2 = *(const float4*)&bc_s[t2 * 64 + s * 4];
            // even t
            h = fexp2(du4.x * As2) * h + du4.y * BC2.x;
            float p = h * BC2.y;
            p = dpp_add<DPP_XOR1>(p);
            p = dpp_add<DPP_XOR2>(p);
            p = dpp_add<DPP_HMIR>(p);
            p = dpp_add<DPP_MIR>(p);
            {
                const unsigned long long km = 0x0001000100010001ULL << (2 * q);
                asm("v_cndmask_b32 %0, %0, %1, %2" : "+v"(pk[c]) : "v"(p), "s"(km));
            }
            // odd t
            h = fexp2(du4.z * As2) * h + du4.w * BC2.z;
            p = h * BC2.w;
            p = dpp_add<DPP_XOR1>(p);
            p = dpp_add<DPP_XOR2>(p);
            p = dpp_add<DPP_HMIR>(p);
            p = dpp_add<DPP_MIR>(p);
            {
                const unsigned long long km = 0x0001000100010001ULL << (2 * q + 1);
                asm("v_cndmask_b32 %0, %0, %1, %2" : "+v"(pk[c]) : "v"(p), "s"(km));
            }
        }
    }

    __builtin_amdgcn_s_barrier();    // all waves done reading du_s (reuse as p_s)
    float* p_s = du_s;
#pragma unroll
    for (int c = 0; c < 4; ++c) {
        const int row = c * 16 + s;
        p_s[row * 16 + (g ^ (row & 12))] = pk[c];
    }

    asm volatile("s_waitcnt lgkmcnt(0)" ::: "memory");
    __builtin_amdgcn_s_barrier();

    {
        const int tt = tid >> 2, cc = (tid & 3) << 2;
        const float4 pv = *(const float4*)&p_s[tt * 16 + (cc ^ (tt & 12))];
        const u16x4  uv = *(const u16x4*)&u_s[tt * 16 + cc];
        const u16x4  zs = *(const u16x4*)&z_s[tt * 16 + cc];
        const float4 Dv = *(const float4*)(Dp + d0 + cc);
        float4 o;
        o.x = (pv.x + b2f(uv.x) * Dv.x) * b2f(zs.x);
        o.y = (pv.y + b2f(uv.y) * Dv.y) * b2f(zs.y);
        o.z = (pv.z + b2f(uv.z) * Dv.z) * b2f(zs.z);
        o.w = (pv.w + b2f(uv.w) * Dv.w) * b2f(zs.w);
        *(u16x4*)(ymul + (t0 + tt) * 2048 + d0 + cc) = f4_to_b4(o);
    }
}

// out = x2 + b2 + sum of 4 partials   [2048,1024] fp32
__global__ __launch_bounds__(256) void ffn2_combine(const float* __restrict__ part,
                                                    const float* __restrict__ x2,
                                                    const float* __restrict__ b2,
                                                    float* __restrict__ out) {
    int i = blockIdx.x * 256 + threadIdx.x;    // over 2048*256
    float4 s = ((const float4*)x2)[i];
    float4 bv = ((const float4*)b2)[i & 255];
    s.x += bv.x; s.y += bv.y; s.z += bv.z; s.w += bv.w;
#pragma unroll
    for (int p = 0; p < 4; ++p) {
        float4 v = ((const float4*)(part + (size_t)p * MROWS * 1024))[i];
        s.x += v.x; s.y += v.y; s.z += v.z; s.w += v.w;
    }
    ((float4*)out)[i] = s;
}

// x2 = x + part0 + part1; h2 = LN2(x2) bf16.   one block per row.
__global__ __launch_bounds__(256) void outproj_combine_ln2(const float* __restrict__ x,
                                                           const float* __restrict__ part,
                                                           const float* __restrict__ w,
                                                           const float* __restrict__ b,
                                                           float* __restrict__ x2,
                                                           u16* __restrict__ h2) {
    const int row = blockIdx.x;
    const int tid = threadIdx.x;
    float4 v = ((const float4*)(x + (size_t)row * 1024))[tid];
    float4 p0 = ((const float4*)(part + (size_t)row * 1024))[tid];
    float4 p1 = ((const float4*)(part + (size_t)MROWS * 1024 + (size_t)row * 1024))[tid];
    v.x += p0.x + p1.x; v.y += p0.y + p1.y; v.z += p0.z + p1.z; v.w += p0.w + p1.w;
    ((float4*)(x2 + (size_t)row * 1024))[tid] = v;
    float s = v.x + v.y + v.z + v.w;
    float q = v.x * v.x + v.y * v.y + v.z * v.z + v.w * v.w;
#pragma unroll
    for (int off = 1; off < 64; off <<= 1) {
        s += __shfl_xor(s, off, 64);
        q += __shfl_xor(q, off, 64);
    }
    __shared__ float ss[4], qq[4];
    const int wave = tid >> 6;
    if ((tid & 63) == 0) { ss[wave] = s; qq[wave] = q; }
    __syncthreads();
    s = ss[0] + ss[1] + ss[2] + ss[3];
    q = qq[0] + qq[1] + qq[2] + qq[3];
    const float mean = s * (1.f / 1024.f);
    const float var  = q * (1.f / 1024.f) - mean * mean;
    const float rstd = rsqrtf(var + 1e-5f);
    const float4 wv = ((const float4*)w)[tid];
    const float4 bv = ((const float4*)b)[tid];
    float4 o;
    o.x = (v.x - mean) * rstd * wv.x + bv.x;
    o.y = (v.y - mean) * rstd * wv.y + bv.y;
    o.z = (v.z - mean) * rstd * wv.z + bv.z;
    o.w = (v.w - mean) * rstd * wv.w + bv.w;
    ((u16x4*)(h2 + (size_t)row * 1024))[tid] = f4_to_b4(o);
}

// ---------- host launcher ----------
extern "C" void kernel_launch(void* const* d_in, const int* in_sizes, int n_in,
                              void* d_out, int out_size, void* d_ws, size_t ws_size,
                              hipStream_t stream) {
    const float* x      = (const float*)d_in[0];
    const float* ln1_w  = (const float*)d_in[1];
    const float* ln1_b  = (const float*)d_in[2];
    const float* W_in   = (const float*)d_in[3];
    const float* conv_w = (const float*)d_in[4];
    const float* conv_b = (const float*)d_in[5];
    const float* W_xproj= (const float*)d_in[6];
    const float* W_dt   = (const float*)d_in[7];
    const float* b_dt   = (const float*)d_in[8];
    const float* A_log  = (const float*)d_in[9];
    const float* Dvec   = (const float*)d_in[10];
    const float* W_out  = (const float*)d_in[11];
    const float* ln2_w  = (const float*)d_in[12];
    const float* ln2_b  = (const float*)d_in[13];
    const float* W1     = (const float*)d_in[14];
    const float* b1     = (const float*)d_in[15];
    const float* W2     = (const float*)d_in[16];
    const float* b2     = (const float*)d_in[17];
    float* out = (float*)d_out;
    char*  ws  = (char*)d_ws;
    const size_t MB = 1024ull * 1024ull;

    u16*   h1b   = (u16*)(ws + 0);              // 4 MB (reused as h2b)
    u16*   xzu   = (u16*)(ws + 4 * MB);         // 8 MB  [2048,2048] bf16 (u pre-conv)
    u16*   zst   = (u16*)(ws + 12 * MB);        // 8 MB  tiled silu(z) [128][2048][16]
    u16*   utl   = (u16*)(ws + 20 * MB);        // 8 MB  tiled u [128][2048][16]
    float* parts = (float*)(ws + 28 * MB);      // 8 MB  [8][2048][128] fp32
    float* bcp   = (float*)(ws + 36 * MB);      // 256 KB [1024 pairs][64]
    u16*   xdbr  = (u16*)(ws + 36 * MB + 256 * 1024);  // 256 KB
    u16*   Wdtb  = (u16*)(ws + 36 * MB + 512 * 1024);  // 256 KB
    u16*   ymul  = (u16*)(ws + 37 * MB);        // 8 MB
    float* Qarr  = (float*)(ws + 45 * MB);      // 4 MB  [16][2][2048][16]
    float* Sarr  = (float*)(ws + 49 * MB);      // 256 KB
    float* H0    = (float*)(ws + 50 * MB);      // 4 MB  [16][2][2048][16]
    float* x2    = (float*)(ws + 54 * MB);      // 8 MB
    u16*   Winb  = (u16*)(ws + 62 * MB);        // 8 MB
    u16*   Woutb = (u16*)(ws + 70 * MB);        // 4 MB
    u16*   W1b   = (u16*)(ws + 74 * MB);        // 8 MB
    u16*   W2b   = (u16*)(ws + 82 * MB);        // 8 MB
    u16*   Wxpb  = (u16*)(ws + 90 * MB);        // 512 KB
    u16*   h2b   = h1b;
    float* opart = (float*)(ws + 4 * MB);       // 16 MB (xzu+zst dead after pass2)
    u16*   f1    = (u16*)(ws + 4 * MB);         // 16 MB (opart dead after combine_ln2)
    float* fpart = (float*)(ws + 20 * MB);      // 32 MB (utl..H0 dead by FFN2)

    // weight conversions: 1 merged kernel + pad
    cvt_all<<<14464, 256, 0, stream>>>(W_in, W_out, W1, W2, W_dt,
                                       Winb, Woutb, W1b, W2b, Wdtb);
    pad_xproj_kernel<<<256, 256, 0, stream>>>(W_xproj, Wxpb);

    // LN1 -> h1 (bf16)
    ln_kernel<<<2048, 256, 0, stream>>>(x, ln1_w, ln1_b, h1b);
    // xz = h1 @ W_in^T : u-half -> bf16 xzu row-major, z-half -> silu -> TILED zst
    gemm_tb<5><<<dim3(16, 32, 1), 256, 0, stream>>>(h1b, Winb, xzu, zst, nullptr,
                                                    MROWS, 4096, 1024, 1024);
    // depthwise conv + silu -> tiled utl only
    conv_kernel<<<4096, 256, 0, stream>>>(xzu, conv_w, conv_b, utl);
    // xproj split-K (8 x K=256), A from tiled utl -> partials -> combine
    gemm_xp<<<dim3(16, 1, 8), 256, 0, stream>>>(utl, Wxpb, parts);
    xproj_combine<<<256, 256, 0, stream>>>(parts, xdbr, bcp);
    // selective scan: per-segment states -> prefix -> in-segment scan
    scan_pass1<<<dim3(128, 2, NSEG), 256, 0, stream>>>(xdbr, Wdtb, b_dt, utl, bcp, A_log,
                                                       Qarr, Sarr);
    scan_prefix<<<dim3(128, 2), 256, 0, stream>>>(Qarr, Sarr, A_log, H0);
    scan_pass2<<<dim3(128, 2, NSEG), 256, 0, stream>>>(xdbr, Wdtb, b_dt, utl, bcp, zst,
                                                       A_log, Dvec, H0, ymul);
    // out-proj split-K (2 x K=1024) -> partials; combine + residual + LN2 fused
    gemm_tb<10><<<dim3(16, 8, 2), 256, 0, stream>>>(ymul, Woutb, opart, nullptr, nullptr,
                                                    MROWS, 1024, 2048, 1024);
    outproj_combine_ln2<<<2048, 256, 0, stream>>>(x, opart, ln2_w, ln2_b, x2, h2b);
    // f1 = relu(h2 @ W1^T + b1)  bf16 [2048,4096]  (128^2 tiles)
    gemm_tb<3><<<dim3(16, 32, 1), 256, 0, stream>>>(h2b, W1b, f1, nullptr, b1,
                                                    MROWS, 4096, 1024, 1024);
    // FFN2 split-K (4 x K=1024) -> partials; combine + bias + residual
    gemm_tb<10><<<dim3(16, 8, 4), 256, 0, stream>>>(f1, W2b, fpart, nullptr, nullptr,
                                                    MROWS, 1024, 4096, 1024);
    ffn2_combine<<<2048, 256, 0, stream>>>(fpart, x2, b2, out);
}

// Round 14
// 224.808 us; speedup vs baseline: 1.0804x; 1.0062x over previous
//
#include <hip/hip_runtime.h>

typedef unsigned short u16;
typedef unsigned int   u32;
typedef short   bf16x8 __attribute__((ext_vector_type(8)));
typedef float   f32x4  __attribute__((ext_vector_type(4)));
typedef u16     u16x4  __attribute__((ext_vector_type(4)));

// ---------- bf16 helpers (RNE) ----------
__device__ __forceinline__ u16 f2b(float f) {
    u32 u = __builtin_bit_cast(u32, f);
    u32 r = u + 0x7FFFu + ((u >> 16) & 1u);
    return (u16)(r >> 16);
}
__device__ __forceinline__ float b2f(u16 h) {
    u32 u = ((u32)h) << 16;
    return __builtin_bit_cast(float, u);
}
__device__ __forceinline__ u16x4 f4_to_b4(float4 v) {
    u16x4 o; o.x = f2b(v.x); o.y = f2b(v.y); o.z = f2b(v.z); o.w = f2b(v.w);
    return o;
}

// native transcendentals: single-instruction v_exp_f32 / v_log_f32
__device__ __forceinline__ float fexp2(float x) {
    float r;
    asm("v_exp_f32 %0, %1" : "=v"(r) : "v"(x));
    return r;
}
__device__ __forceinline__ float flog2(float x) {
    float r;
    asm("v_log_f32 %0, %1" : "=v"(r) : "v"(x));
    return r;
}

// DPP add: p += p[lane permuted by CTRL]  (pure VALU, no DS pipe)
template <int CTRL>
__device__ __forceinline__ float dpp_add(float p) {
    int pi = __builtin_bit_cast(int, p);
    int q  = __builtin_amdgcn_update_dpp(pi, pi, CTRL, 0xF, 0xF, false);
    return p + __builtin_bit_cast(float, q);
}
#define DPP_XOR1 0xB1   // quad_perm [1,0,3,2]
#define DPP_XOR2 0x4E   // quad_perm [2,3,0,1]
#define DPP_HMIR 0x141  // row_half_mirror (lane^7)
#define DPP_MIR  0x140  // row_mirror      (lane^15)

// ---------- constants ----------
#define MROWS   2048   // B*L
#define NSEG    16
#define SEGT    64
#define L2E     1.44269504088896340736f
#define LN2     0.69314718055994530942f

#define GLDS(g, l) __builtin_amdgcn_global_load_lds(                      \
    (const __attribute__((address_space(1))) void*)(g),                   \
    (__attribute__((address_space(3))) void*)(l), 16, 0, 0)

// ---------- merged fp32 -> bf16 weight conversion ----------
__global__ __launch_bounds__(256) void cvt_all(const float* __restrict__ W_in,
                                               const float* __restrict__ W_out,
                                               const float* __restrict__ W1,
                                               const float* __restrict__ W2,
                                               const float* __restrict__ W_dt,
                                               u16* __restrict__ Winb,
                                               u16* __restrict__ Woutb,
                                               u16* __restrict__ W1b,
                                               u16* __restrict__ W2b,
                                               u16* __restrict__ Wdtb) {
    const int i = blockIdx.x * 256 + threadIdx.x;
    const float* src; u16* dst; int off;
    if (i < 1048576)      { src = W_in;  dst = Winb;  off = i; }
    else if (i < 1572864) { src = W_out; dst = Woutb; off = i - 1048576; }
    else if (i < 2621440) { src = W1;    dst = W1b;   off = i - 1572864; }
    else if (i < 3670016) { src = W2;    dst = W2b;   off = i - 2621440; }
    else                  { src = W_dt;  dst = Wdtb;  off = i - 3670016; }
    float4 v = ((const float4*)src)[off];
    ((u16x4*)dst)[off] = f4_to_b4(v);
}

// pad W_xproj (96 x 2048) -> bf16 (128 x 2048), rows 96..127 = 0
__global__ __launch_bounds__(256) void pad_xproj_kernel(const float* __restrict__ in,
                                                        u16* __restrict__ out) {
    int i = blockIdx.x * 256 + threadIdx.x;    // over 128*512
    int r = i >> 9, c4 = i & 511;
    float4 v = make_float4(0.f, 0.f, 0.f, 0.f);
    if (r < 96) v = ((const float4*)(in + (size_t)r * 2048))[c4];
    ((u16x4*)(out + (size_t)r * 2048))[c4] = f4_to_b4(v);
}

// ---------- LayerNorm (row = 1024 cols), fp32 in -> bf16 out ----------
__global__ __launch_bounds__(256) void ln_kernel(const float* __restrict__ x,
                                                 const float* __restrict__ w,
                                                 const float* __restrict__ b,
                                                 u16* __restrict__ out) {
    const int row = blockIdx.x;
    const int tid = threadIdx.x;
    const float4 v = ((const float4*)(x + (size_t)row * 1024))[tid];
    float s = v.x + v.y + v.z + v.w;
    float q = v.x * v.x + v.y * v.y + v.z * v.z + v.w * v.w;
#pragma unroll
    for (int off = 1; off < 64; off <<= 1) {
        s += __shfl_xor(s, off, 64);
        q += __shfl_xor(q, off, 64);
    }
    __shared__ float ss[4], qq[4];
    const int wave = tid >> 6;
    if ((tid & 63) == 0) { ss[wave] = s; qq[wave] = q; }
    __syncthreads();
    s = ss[0] + ss[1] + ss[2] + ss[3];
    q = qq[0] + qq[1] + qq[2] + qq[3];
    const float mean = s * (1.f / 1024.f);
    const float var  = q * (1.f / 1024.f) - mean * mean;
    const float rstd = rsqrtf(var + 1e-5f);
    const float4 wv = ((const float4*)w)[tid];
    const float4 bv = ((const float4*)b)[tid];
    float4 o;
    o.x = (v.x - mean) * rstd * wv.x + bv.x;
    o.y = (v.y - mean) * rstd * wv.y + bv.y;
    o.z = (v.z - mean) * rstd * wv.z + bv.z;
    o.w = (v.w - mean) * rstd * wv.w + bv.w;
    ((u16x4*)(out + (size_t)row * 1024))[tid] = f4_to_b4(o);
}

// ---------- depthwise causal conv + bias + silu (bf16 in) -> tiled utl only ----------
__global__ __launch_bounds__(256) void conv_kernel(const u16* __restrict__ xzu,
                                                   const float* __restrict__ cw,
                                                   const float* __restrict__ cb,
                                                   u16* __restrict__ utl) {
    const int idx = blockIdx.x * 256 + threadIdx.x;   // over 2048 rows * 512 d4
    const int row = idx >> 9;
    const int d4  = idx & 511;
    const int d   = d4 * 4;
    const int bb  = row >> 10;
    const int t   = row & 1023;
    float w0[4], w1[4], w2[4], w3[4];
    *(float4*)w0 = ((const float4*)cw)[d + 0];
    *(float4*)w1 = ((const float4*)cw)[d + 1];
    *(float4*)w2 = ((const float4*)cw)[d + 2];
    *(float4*)w3 = ((const float4*)cw)[d + 3];
    float4 a = ((const float4*)cb)[d4];
#pragma unroll
    for (int j = 0; j < 4; ++j) {
        const int tt = t - 3 + j;
        if (tt >= 0) {
            const u16x4 uv = *(const u16x4*)(xzu + ((size_t)(bb * 1024 + tt)) * 2048 + d);
            a.x += b2f(uv.x) * w0[j];
            a.y += b2f(uv.y) * w1[j];
            a.z += b2f(uv.z) * w2[j];
            a.w += b2f(uv.w) * w3[j];
        }
    }
    float4 o;
    o.x = a.x / (1.f + __expf(-a.x));
    o.y = a.y / (1.f + __expf(-a.y));
    o.z = a.z / (1.f + __expf(-a.z));
    o.w = a.w / (1.f + __expf(-a.w));
    *(u16x4*)(utl + (((size_t)(d >> 4)) * 2048 + row) * 16 + (d & 15)) = f4_to_b4(o);
}

// ---------- triple-buffered GEMM 128x128, 8 waves (512 thr), XCD-swizzled ----------
// waves: wm = wave>>1 (0..3) over rows (32 each), wn = wave&1 over cols (64 each).
// EPI: 3 = relu(c+bias) bf16; 5 = xz split (u -> bf16 row-major / silu(z) -> TILED zst);
//      10 = split-K partial fp32
template <int EPI>
__global__ __launch_bounds__(512) void gemm_tb(const u16* __restrict__ A,
                                               const u16* __restrict__ Bw,
                                               void* __restrict__ Cptr,
                                               void* __restrict__ Cptr2,
                                               const float* __restrict__ bias,
                                               int M, int N, int K, int KS) {
    const int nbm = gridDim.x, nbn = gridDim.y;
    const int nwg = nbm * nbn;
    const int id  = blockIdx.x + nbm * blockIdx.y;
    const int sw  = (nwg >= 8) ? ((id & 7) * (nwg >> 3) + (id >> 3)) : id;
    const int bm  = sw % nbm, bn = sw / nbm;

    __shared__ u16 Asm[3][128 * 32];
    __shared__ u16 Bsm[3][128 * 32];
    const int tid  = threadIdx.x;
    const int kz   = blockIdx.z;
    const int lane = tid & 63;
    const int wave = tid >> 6;
    const int wm   = wave >> 1, wn = wave & 1;
    const u16* Ag = A  + (size_t)bm * 128 * K;
    const u16* Bg = Bw + (size_t)bn * 128 * K;
    const int r0 = tid >> 2;            // 0..127
    const int sg = (tid & 3) * 8;
    const int k0 = kz * KS;
    const int nk = KS >> 5;
    const int fr = lane & 15, fk = (lane >> 4) * 8;

#define STG(bf, kk)                                                            \
    {                                                                          \
        const int kof = k0 + (kk) * 32;                                        \
        GLDS(Ag + (size_t)r0 * K + kof + sg, &Asm[bf][tid * 8]);               \
        GLDS(Bg + (size_t)r0 * K + kof + sg, &Bsm[bf][tid * 8]);               \
    }

    f32x4 acc[2][4] = {};
    STG(0, 0); STG(1, 1); STG(2, 2);
    int buf = 0;
    for (int k = 0; k < nk; ++k) {
        // per-wave: 2 loads/stage, 3 stages in flight = 6 outstanding
        if (k < nk - 2)       asm volatile("s_waitcnt vmcnt(4)" ::: "memory");
        else if (k == nk - 2) asm volatile("s_waitcnt vmcnt(2)" ::: "memory");
        else                  asm volatile("s_waitcnt vmcnt(0)" ::: "memory");
        __builtin_amdgcn_s_barrier();
        bf16x8 a[2], b[4];
#pragma unroll
        for (int m = 0; m < 2; ++m)
            a[m] = *(const bf16x8*)&Asm[buf][(wm * 32 + m * 16 + fr) * 32 + fk];
#pragma unroll
        for (int n = 0; n < 4; ++n)
            b[n] = *(const bf16x8*)&Bsm[buf][(wn * 64 + n * 16 + fr) * 32 + fk];
        asm volatile("s_waitcnt lgkmcnt(0)" ::: "memory");
        __builtin_amdgcn_s_barrier();
        if (k + 3 < nk) STG(buf, k + 3);
#pragma unroll
        for (int m = 0; m < 2; ++m)
#pragma unroll
            for (int n = 0; n < 4; ++n)
                acc[m][n] = __builtin_amdgcn_mfma_f32_16x16x32_bf16(a[m], b[n], acc[m][n], 0, 0, 0);
        buf = (buf == 2) ? 0 : buf + 1;
    }
#undef STG

    const int fq = lane >> 4;
#pragma unroll
    for (int m = 0; m < 2; ++m) {
#pragma unroll
        for (int n = 0; n < 4; ++n) {
            const int row0 = bm * 128 + wm * 32 + m * 16 + fq * 4;
            const int col  = bn * 128 + wn * 64 + n * 16 + fr;
#pragma unroll
            for (int j = 0; j < 4; ++j) {
                float v = acc[m][n][j];
                if constexpr (EPI == 3) {
                    v += bias[col];
                    ((u16*)Cptr)[(size_t)(row0 + j) * N + col] = f2b(fmaxf(v, 0.f));
                } else if constexpr (EPI == 5) {
                    if (col < 2048) {
                        ((u16*)Cptr)[(size_t)(row0 + j) * 2048 + col] = f2b(v);
                    } else {
                        const float sv = v / (1.f + __expf(-v));
                        const int zc = col - 2048;
                        ((u16*)Cptr2)[(((size_t)(zc >> 4)) * 2048 + row0 + j) * 16 + (zc & 15)]
                            = f2b(sv);
                    }
                } else {   // 10: split-K partial
                    ((float*)Cptr)[(size_t)kz * M * N + (size_t)(row0 + j) * N + col] = v;
                }
            }
        }
    }
}

// ---------- xproj GEMM: A read from TILED utl [128 chunks][2048 rows][16] ----------
// grid (16, 1, 8): bm, -, kz (K-slice 256).  Partials out.  256 threads.
__global__ __launch_bounds__(256) void gemm_xp(const u16* __restrict__ utl,
                                               const u16* __restrict__ Bw,
                                               float* __restrict__ part) {
    const int nwg = 16;
    const int id  = blockIdx.x;
    const int sw  = (id & 7) * (nwg >> 3) + (id >> 3);
    const int bm  = sw;
    __shared__ u16 Asm[3][128 * 32];
    __shared__ u16 Bsm[3][128 * 32];
    const int tid  = threadIdx.x;
    const int kz   = blockIdx.z;
    const int lane = tid & 63;
    const int wave = tid >> 6;
    const int wm   = wave >> 1, wn = wave & 1;
    const u16* Bg = Bw;
    const int r0 = tid >> 2;             // 0..63
    const int pc = tid & 3;              // K-piece 0..3 (8 u16 each)
    const int sg = pc * 8;
    const int k0 = kz * 256;
    const int fr = lane & 15, fk = (lane >> 4) * 8;

#define STGX(bf, kk)                                                                     \
    {                                                                                    \
        const int kof = k0 + (kk) * 32;                                                  \
        const int kc  = kof >> 4;                                                        \
        GLDS(utl + ((size_t)(kc + (pc >> 1)) * 2048 + bm * 128 + r0) * 16 + (pc & 1) * 8,\
             &Asm[bf][tid * 8]);                                                         \
        GLDS(utl + ((size_t)(kc + (pc >> 1)) * 2048 + bm * 128 + r0 + 64) * 16 + (pc & 1) * 8,\
             &Asm[bf][(tid + 256) * 8]);                                                 \
        GLDS(Bg + (size_t)r0 * 2048 + kof + sg, &Bsm[bf][tid * 8]);                      \
        GLDS(Bg + (size_t)(r0 + 64) * 2048 + kof + sg, &Bsm[bf][(tid + 256) * 8]);       \
    }

    f32x4 acc[4][4] = {};
    STGX(0, 0); STGX(1, 1); STGX(2, 2);
    int buf = 0;
    const int nk = 8;
    for (int k = 0; k < nk; ++k) {
        if (k < nk - 2)       asm volatile("s_waitcnt vmcnt(8)" ::: "memory");
        else if (k == nk - 2) asm volatile("s_waitcnt vmcnt(4)" ::: "memory");
        else                  asm volatile("s_waitcnt vmcnt(0)" ::: "memory");
        __builtin_amdgcn_s_barrier();
        bf16x8 a[4], b[4];
#pragma unroll
        for (int m = 0; m < 4; ++m)
            a[m] = *(const bf16x8*)&Asm[buf][(wm * 64 + m * 16 + fr) * 32 + fk];
#pragma unroll
        for (int n = 0; n < 4; ++n)
            b[n] = *(const bf16x8*)&Bsm[buf][(wn * 64 + n * 16 + fr) * 32 + fk];
        asm volatile("s_waitcnt lgkmcnt(0)" ::: "memory");
        __builtin_amdgcn_s_barrier();
        if (k + 3 < nk) STGX(buf, k + 3);
#pragma unroll
        for (int m = 0; m < 4; ++m)
#pragma unroll
            for (int n = 0; n < 4; ++n)
                acc[m][n] = __builtin_amdgcn_mfma_f32_16x16x32_bf16(a[m], b[n], acc[m][n], 0, 0, 0);
        buf = (buf == 2) ? 0 : buf + 1;
    }
#undef STGX

    const int fq = lane >> 4;
    float* Cp = part + (size_t)kz * MROWS * 128;
#pragma unroll
    for (int m = 0; m < 4; ++m) {
#pragma unroll
        for (int n = 0; n < 4; ++n) {
            const int row0 = bm * 128 + wm * 64 + m * 16 + fq * 4;
            const int col  = wn * 64 + n * 16 + fr;
#pragma unroll
            for (int j = 0; j < 4; ++j)
                Cp[(size_t)(row0 + j) * 128 + col] = acc[m][n][j];
        }
    }
}

// combine split-K partials -> xdbr bf16 [2048,64] + bcp fp32 pair-packed:
// bcp[(t>>1)*64 + s*4 + (t&1)*2 + {0=B,1=C}]
__global__ __launch_bounds__(256) void xproj_combine(const float* __restrict__ part,
                                                     u16* __restrict__ xdbr,
                                                     float* __restrict__ bcp) {
    int i = blockIdx.x * 256 + threadIdx.x;     // over 2048*32
    int row = i >> 5, c4 = i & 31;
    if (c4 >= 24) return;
    float4 s = make_float4(0.f, 0.f, 0.f, 0.f);
#pragma unroll
    for (int p = 0; p < 8; ++p) {
        float4 v = ((const float4*)(part + (size_t)p * MROWS * 128 + (size_t)row * 128))[c4];
        s.x += v.x; s.y += v.y; s.z += v.z; s.w += v.w;
    }
    if (c4 < 16) {
        ((u16x4*)(xdbr + (size_t)row * 64))[c4] = f4_to_b4(s);
    } else {
        const int e0 = (c4 - 16) * 4;          // 0..31 over B(0..15)|C(16..31)
        float sv[4] = {s.x, s.y, s.z, s.w};
#pragma unroll
        for (int j = 0; j < 4; ++j) {
            const int e = e0 + j;
            const int st  = (e < 16) ? e : (e - 16);
            const int isc = (e < 16) ? 0 : 1;
            bcp[(size_t)(row >> 1) * 64 + st * 4 + (row & 1) * 2 + isc] = sv[j];
        }
    }
}

// ---------- selective scan: time-segmented, dt fused via MFMA ----------
__device__ __forceinline__ void compute_dtu_tile(const u16* __restrict__ xdbr,
                                                 const u16* __restrict__ Wdtb,
                                                 const float* __restrict__ b_dt,
                                                 const u16* __restrict__ utile,
                                                 float* __restrict__ du_s,
                                                 size_t t0, int d0, int w, int l) {
    const int fr = l & 15, fk = (l >> 4) * 8;
    const bf16x8 a0 = *(const bf16x8*)(xdbr + (t0 + w * 16 + fr) * 64 + fk);
    const bf16x8 a1 = *(const bf16x8*)(xdbr + (t0 + w * 16 + fr) * 64 + 32 + fk);
    const bf16x8 b0 = *(const bf16x8*)(Wdtb + (size_t)(d0 + fr) * 64 + fk);
    const bf16x8 b1 = *(const bf16x8*)(Wdtb + (size_t)(d0 + fr) * 64 + 32 + fk);
    const float bdt = b_dt[d0 + fr];
    f32x4 acc = {};
    acc = __builtin_amdgcn_mfma_f32_16x16x32_bf16(a0, b0, acc, 0, 0, 0);
    acc = __builtin_amdgcn_mfma_f32_16x16x32_bf16(a1, b1, acc, 0, 0, 0);
#pragma unroll
    for (int j = 0; j < 4; ++j) {
        const int row = w * 16 + (l >> 4) * 4 + j;
        float v = acc[j] + bdt;
        const float sp = flog2(1.f + fexp2(v * L2E)) * LN2;
        v = (v > 20.f) ? v : sp;
        const float uval = b2f(utile[(t0 + row) * 16 + fr]);
        float2 dv; dv.x = v; dv.y = v * uval;
        *(float2*)&du_s[(row >> 1) * 66 + fr * 4 + (row & 1) * 2] = dv;  // b64 write
    }
}

// stage bcp pair rows: 32 rows x 64 floats = 8KB, lane-linear per wave
__device__ __forceinline__ void stage_bc(const float* __restrict__ bcp,
                                         float* __restrict__ bc_s,
                                         size_t p0, int w, int l) {
    const int pr = (w << 3) + (l >> 4);
    const int pc = (l & 15) << 2;
    GLDS(bcp + (p0 + pr) * 64 + pc,     &bc_s[(w << 9)]);
    GLDS(bcp + (p0 + pr + 4) * 64 + pc, &bc_s[(w << 9) + 256]);
}

// grid (128, 2, 16): d-chunk, b, seg.  block 256.
__global__ __launch_bounds__(256) void scan_pass1(const u16* __restrict__ xdbr,
                                                  const u16* __restrict__ Wdtb,
                                                  const float* __restrict__ b_dt,
                                                  const u16* __restrict__ utl,
                                                  const float* __restrict__ bcp,
                                                  const float* __restrict__ A_log,
                                                  float* __restrict__ Qarr,
                                                  float* __restrict__ Sarr) {
    __shared__ __align__(16) float du_s[32 * 66];
    __shared__ __align__(16) float bc_s[32 * 64];

    const int tid = threadIdx.x;
    const int l   = tid & 63;
    const int w   = tid >> 6;
    const int s   = l & 15;
    const int g   = (w << 2) | (l >> 4);
    const int d0  = blockIdx.x << 4;
    const int b   = blockIdx.y;
    const int seg = blockIdx.z;
    const int d   = d0 + g;
    const size_t t0 = (size_t)b * 1024 + (size_t)seg * SEGT;
    const u16* utile = utl + (size_t)(d0 >> 4) * 2048 * 16;

    stage_bc(bcp, bc_s, t0 >> 1, w, l);
    compute_dtu_tile(xdbr, Wdtb, b_dt, utile, du_s, t0, d0, w, l);

    const float As2 = -__expf(A_log[d * 16 + s]) * L2E;
    asm volatile("s_waitcnt vmcnt(0) lgkmcnt(0)" ::: "memory");
    __builtin_amdgcn_s_barrier();

    float Q = 0.f, S = 0.f;
#pragma unroll 8
    for (int t2 = 0; t2 < 32; ++t2) {
        const float4 du4 = *(const float4*)&du_s[t2 * 66 + g * 4];
        const float4 BC2 = *(const float4*)&bc_s[t2 * 64 + s * 4];
        S += du4.x;
        Q = fexp2(du4.x * As2) * Q + du4.y * BC2.x;
        S += du4.z;
        Q = fexp2(du4.z * As2) * Q + du4.w * BC2.z;
    }
    Qarr[(((size_t)seg * 2 + b) * 2048 + d) * 16 + s] = Q;
    if (s == 0) Sarr[((size_t)seg * 2 + b) * 2048 + d] = S;
}

// prefix scan over segments: H0[i][b][d][s] = h entering segment i
__global__ __launch_bounds__(256) void scan_prefix(const float* __restrict__ Qarr,
                                                   const float* __restrict__ Sarr,
                                                   const float* __restrict__ A_log,
                                                   float* __restrict__ H0) {
    const int tid = threadIdx.x;
    const int d   = (blockIdx.x << 4) + (tid >> 4);
    const int s   = tid & 15;
    const int b   = blockIdx.y;
    const float As2 = -__expf(A_log[d * 16 + s]) * L2E;
    float h = 0.f;
#pragma unroll
    for (int i = 0; i < NSEG; ++i) {
        const size_t base = ((size_t)i * 2 + b) * 2048 + d;
        H0[base * 16 + s] = h;
        h = fexp2(As2 * Sarr[base]) * h + Qarr[base * 16 + s];
    }
}

__global__ __launch_bounds__(256) void scan_pass2(const u16* __restrict__ xdbr,
                                                  const u16* __restrict__ Wdtb,
                                                  const float* __restrict__ b_dt,
                                                  const u16* __restrict__ utl,
                                                  const float* __restrict__ bcp,
                                                  const u16* __restrict__ zst,
                                                  const float* __restrict__ A_log,
                                                  const float* __restrict__ Dp,
                                                  const float* __restrict__ H0,
                                                  u16* __restrict__ ymul) {
    __shared__ __align__(16) float du_s[32 * 66];   // overlaid by p_s after inner loop
    __shared__ __align__(16) float bc_s[32 * 64];
    __shared__ __align__(16) u16   u_s[1024];       // [64][16] bf16 u tile
    __shared__ __align__(16) u16   z_s[1024];       // [64][16] bf16 silu(z) tile

    const int tid = threadIdx.x;
    const int l   = tid & 63;
    const int w   = tid >> 6;
    const int s   = l & 15;
    const int g   = (w << 2) | (l >> 4);
    const int d0  = blockIdx.x << 4;
    const int b   = blockIdx.y;
    const int seg = blockIdx.z;
    const int d   = d0 + g;
    const size_t t0 = (size_t)b * 1024 + (size_t)seg * SEGT;
    const u16* utile = utl + (size_t)(d0 >> 4) * 2048 * 16;
    const u16* ztile = zst + (size_t)(d0 >> 4) * 2048 * 16;

    stage_bc(bcp, bc_s, t0 >> 1, w, l);
    if (w < 2)
        GLDS(utile + t0 * 16 + ((w & 1) * 64 + l) * 8, &u_s[(w & 1) << 9]);
    else
        GLDS(ztile + t0 * 16 + ((w & 1) * 64 + l) * 8, &z_s[(w & 1) << 9]);

    compute_dtu_tile(xdbr, Wdtb, b_dt, utile, du_s, t0, d0, w, l);

    const float As2 = -__expf(A_log[d * 16 + s]) * L2E;
    float h = H0[(((size_t)seg * 2 + b) * 2048 + d) * 16 + s];

    asm volatile("s_waitcnt vmcnt(0) lgkmcnt(0)" ::: "memory");
    __builtin_amdgcn_s_barrier();

    float pk[4];
#pragma unroll
    for (int c = 0; c < 4; ++c) {
        pk[c] = 0.f;
#pragma unroll
        for (int q = 0; q < 8; ++q) {
            const int t2 = c * 8 + q;
            const float4 du4 = *(const float4*)&du_s[t2 * 66 + g * 4];
            const float4 BC2 = *(const float4*)&bc_s[t2 * 64 + s * 4];
            // even t
            h = fexp2(du4.x * As2) * h + du4.y * BC2.x;
            float p = h * BC2.y;
            p = dpp_add<DPP_XOR1>(p);
            p = dpp_add<DPP_XOR2>(p);
            p = dpp_add<DPP_HMIR>(p);
            p = dpp_add<DPP_MIR>(p);
            {
                const unsigned long long km = 0x0001000100010001ULL << (2 * q);
                asm("v_cndmask_b32 %0, %0, %1, %2" : "+v"(pk[c]) : "v"(p), "s"(km));
            }
            // odd t
            h = fexp2(du4.z * As2) * h + du4.w * BC2.z;
            p = h * BC2.w;
            p = dpp_add<DPP_XOR1>(p);
            p = dpp_add<DPP_XOR2>(p);
            p = dpp_add<DPP_HMIR>(p);
            p = dpp_add<DPP_MIR>(p);
            {
                const unsigned long long km = 0x0001000100010001ULL << (2 * q + 1);
                asm("v_cndmask_b32 %0, %0, %1, %2" : "+v"(pk[c]) : "v"(p), "s"(km));
            }
        }
    }

    __builtin_amdgcn_s_barrier();    // all waves done reading du_s (reuse as p_s)
    float* p_s = du_s;
#pragma unroll
    for (int c = 0; c < 4; ++c) {
        const int row = c * 16 + s;
        p_s[row * 16 + (g ^ (row & 12))] = pk[c];
    }

    asm volatile("s_waitcnt lgkmcnt(0)" ::: "memory");
    __builtin_amdgcn_s_barrier();

    {
        const int tt = tid >> 2, cc = (tid & 3) << 2;
        const float4 pv = *(const float4*)&p_s[tt * 16 + (cc ^ (tt & 12))];
        const u16x4  uv = *(const u16x4*)&u_s[tt * 16 + cc];
        const u16x4  zs = *(const u16x4*)&z_s[tt * 16 + cc];
        const float4 Dv = *(const float4*)(Dp + d0 + cc);
        float4 o;
        o.x = (pv.x + b2f(uv.x) * Dv.x) * b2f(zs.x);
        o.y = (pv.y + b2f(uv.y) * Dv.y) * b2f(zs.y);
        o.z = (pv.z + b2f(uv.z) * Dv.z) * b2f(zs.z);
        o.w = (pv.w + b2f(uv.w) * Dv.w) * b2f(zs.w);
        *(u16x4*)(ymul + (t0 + tt) * 2048 + d0 + cc) = f4_to_b4(o);
    }
}

// out = x2 + b2 + sum of 4 partials   [2048,1024] fp32
__global__ __launch_bounds__(256) void ffn2_combine(const float* __restrict__ part,
                                                    const float* __restrict__ x2,
                                                    const float* __restrict__ b2,
                                                    float* __restrict__ out) {
    int i = blockIdx.x * 256 + threadIdx.x;    // over 2048*256
    float4 s = ((const float4*)x2)[i];
    float4 bv = ((const float4*)b2)[i & 255];
    s.x += bv.x; s.y += bv.y; s.z += bv.z; s.w += bv.w;
#pragma unroll
    for (int p = 0; p < 4; ++p) {
        float4 v = ((const float4*)(part + (size_t)p * MROWS * 1024))[i];
        s.x += v.x; s.y += v.y; s.z += v.z; s.w += v.w;
    }
    ((float4*)out)[i] = s;
}

// x2 = x + part0 + part1; h2 = LN2(x2) bf16.   one block per row.
__global__ __launch_bounds__(256) void outproj_combine_ln2(const float* __restrict__ x,
                                                           const float* __restrict__ part,
                                                           const float* __restrict__ w,
                                                           const float* __restrict__ b,
                                                           float* __restrict__ x2,
                                                           u16* __restrict__ h2) {
    const int row = blockIdx.x;
    const int tid = threadIdx.x;
    float4 v = ((const float4*)(x + (size_t)row * 1024))[tid];
    float4 p0 = ((const float4*)(part + (size_t)row * 1024))[tid];
    float4 p1 = ((const float4*)(part + (size_t)MROWS * 1024 + (size_t)row * 1024))[tid];
    v.x += p0.x + p1.x; v.y += p0.y + p1.y; v.z += p0.z + p1.z; v.w += p0.w + p1.w;
    ((float4*)(x2 + (size_t)row * 1024))[tid] = v;
    float s = v.x + v.y + v.z + v.w;
    float q = v.x * v.x + v.y * v.y + v.z * v.z + v.w * v.w;
#pragma unroll
    for (int off = 1; off < 64; off <<= 1) {
        s += __shfl_xor(s, off, 64);
        q += __shfl_xor(q, off, 64);
    }
    __shared__ float ss[4], qq[4];
    const int wave = tid >> 6;
    if ((tid & 63) == 0) { ss[wave] = s; qq[wave] = q; }
    __syncthreads();
    s = ss[0] + ss[1] + ss[2] + ss[3];
    q = qq[0] + qq[1] + qq[2] + qq[3];
    const float mean = s * (1.f / 1024.f);
    const float var  = q * (1.f / 1024.f) - mean * mean;
    const float rstd = rsqrtf(var + 1e-5f);
    const float4 wv = ((const float4*)w)[tid];
    const float4 bv = ((const float4*)b)[tid];
    float4 o;
    o.x = (v.x - mean) * rstd * wv.x + bv.x;
    o.y = (v.y - mean) * rstd * wv.y + bv.y;
    o.z = (v.z - mean) * rstd * wv.z + bv.z;
    o.w = (v.w - mean) * rstd * wv.w + bv.w;
    ((u16x4*)(h2 + (size_t)row * 1024))[tid] = f4_to_b4(o);
}

// ---------- host launcher ----------
extern "C" void kernel_launch(void* const* d_in, const int* in_sizes, int n_in,
                              void* d_out, int out_size, void* d_ws, size_t ws_size,
                              hipStream_t stream) {
    const float* x      = (const float*)d_in[0];
    const float* ln1_w  = (const float*)d_in[1];
    const float* ln1_b  = (const float*)d_in[2];
    const float* W_in   = (const float*)d_in[3];
    const float* conv_w = (const float*)d_in[4];
    const float* conv_b = (const float*)d_in[5];
    const float* W_xproj= (const float*)d_in[6];
    const float* W_dt   = (const float*)d_in[7];
    const float* b_dt   = (const float*)d_in[8];
    const float* A_log  = (const float*)d_in[9];
    const float* Dvec   = (const float*)d_in[10];
    const float* W_out  = (const float*)d_in[11];
    const float* ln2_w  = (const float*)d_in[12];
    const float* ln2_b  = (const float*)d_in[13];
    const float* W1     = (const float*)d_in[14];
    const float* b1     = (const float*)d_in[15];
    const float* W2     = (const float*)d_in[16];
    const float* b2     = (const float*)d_in[17];
    float* out = (float*)d_out;
    char*  ws  = (char*)d_ws;
    const size_t MB = 1024ull * 1024ull;

    u16*   h1b   = (u16*)(ws + 0);              // 4 MB (reused as h2b)
    u16*   xzu   = (u16*)(ws + 4 * MB);         // 8 MB  [2048,2048] bf16 (u pre-conv)
    u16*   zst   = (u16*)(ws + 12 * MB);        // 8 MB  tiled silu(z) [128][2048][16]
    u16*   utl   = (u16*)(ws + 20 * MB);        // 8 MB  tiled u [128][2048][16]
    float* parts = (float*)(ws + 28 * MB);      // 8 MB  [8][2048][128] fp32
    float* bcp   = (float*)(ws + 36 * MB);      // 256 KB [1024 pairs][64]
    u16*   xdbr  = (u16*)(ws + 36 * MB + 256 * 1024);  // 256 KB
    u16*   Wdtb  = (u16*)(ws + 36 * MB + 512 * 1024);  // 256 KB
    u16*   ymul  = (u16*)(ws + 37 * MB);        // 8 MB
    float* Qarr  = (float*)(ws + 45 * MB);      // 4 MB  [16][2][2048][16]
    float* Sarr  = (float*)(ws + 49 * MB);      // 256 KB
    float* H0    = (float*)(ws + 50 * MB);      // 4 MB  [16][2][2048][16]
    float* x2    = (float*)(ws + 54 * MB);      // 8 MB
    u16*   Winb  = (u16*)(ws + 62 * MB);        // 8 MB
    u16*   Woutb = (u16*)(ws + 70 * MB);        // 4 MB
    u16*   W1b   = (u16*)(ws + 74 * MB);        // 8 MB
    u16*   W2b   = (u16*)(ws + 82 * MB);        // 8 MB
    u16*   Wxpb  = (u16*)(ws + 90 * MB);        // 512 KB
    u16*   h2b   = h1b;
    float* opart = (float*)(ws + 4 * MB);       // 16 MB (xzu+zst dead after pass2)
    u16*   f1    = (u16*)(ws + 4 * MB);         // 16 MB (opart dead after combine_ln2)
    float* fpart = (float*)(ws + 20 * MB);      // 32 MB (utl..H0 dead by FFN2)

    // weight conversions: 1 merged kernel + pad
    cvt_all<<<14464, 256, 0, stream>>>(W_in, W_out, W1, W2, W_dt,
                                       Winb, Woutb, W1b, W2b, Wdtb);
    pad_xproj_kernel<<<256, 256, 0, stream>>>(W_xproj, Wxpb);

    // LN1 -> h1 (bf16)
    ln_kernel<<<2048, 256, 0, stream>>>(x, ln1_w, ln1_b, h1b);
    // xz = h1 @ W_in^T : u-half -> bf16 xzu row-major, z-half -> silu -> TILED zst
    gemm_tb<5><<<dim3(16, 32, 1), 512, 0, stream>>>(h1b, Winb, xzu, zst, nullptr,
                                                    MROWS, 4096, 1024, 1024);
    // depthwise conv + silu -> tiled utl only
    conv_kernel<<<4096, 256, 0, stream>>>(xzu, conv_w, conv_b, utl);
    // xproj split-K (8 x K=256), A from tiled utl -> partials -> combine
    gemm_xp<<<dim3(16, 1, 8), 256, 0, stream>>>(utl, Wxpb, parts);
    xproj_combine<<<256, 256, 0, stream>>>(parts, xdbr, bcp);
    // selective scan: per-segment states -> prefix -> in-segment scan
    scan_pass1<<<dim3(128, 2, NSEG), 256, 0, stream>>>(xdbr, Wdtb, b_dt, utl, bcp, A_log,
                                                       Qarr, Sarr);
    scan_prefix<<<dim3(128, 2), 256, 0, stream>>>(Qarr, Sarr, A_log, H0);
    scan_pass2<<<dim3(128, 2, NSEG), 256, 0, stream>>>(xdbr, Wdtb, b_dt, utl, bcp, zst,
                                                       A_log, Dvec, H0, ymul);
    // out-proj split-K (2 x K=1024) -> partials; combine + residual + LN2 fused
    gemm_tb<10><<<dim3(16, 8, 2), 512, 0, stream>>>(ymul, Woutb, opart, nullptr, nullptr,
                                                    MROWS, 1024, 2048, 1024);
    outproj_combine_ln2<<<2048, 256, 0, stream>>>(x, opart, ln2_w, ln2_b, x2, h2b);
    // f1 = relu(h2 @ W1^T + b1)  bf16 [2048,4096]  (128^2 tiles, 8 waves)
    gemm_tb<3><<<dim3(16, 32, 1), 512, 0, stream>>>(h2b, W1b, f1, nullptr, b1,
                                                    MROWS, 4096, 1024, 1024);
    // FFN2 split-K (4 x K=1024) -> partials; combine + bias + residual
    gemm_tb<10><<<dim3(16, 8, 4), 512, 0, stream>>>(f1, W2b, fpart, nullptr, nullptr,
                                                    MROWS, 1024, 4096, 1024);
    ffn2_combine<<<2048, 256, 0, stream>>>(fpart, x2, b2, out);
}

// Round 15
// 216.976 us; speedup vs baseline: 1.1194x; 1.0361x over previous
//
#include <hip/hip_runtime.h>

typedef unsigned short u16;
typedef unsigned int   u32;
typedef short   bf16x8 __attribute__((ext_vector_type(8)));
typedef float   f32x4  __attribute__((ext_vector_type(4)));
typedef u16     u16x4  __attribute__((ext_vector_type(4)));

// ---------- bf16 helpers (RNE) ----------
__device__ __forceinline__ u16 f2b(float f) {
    u32 u = __builtin_bit_cast(u32, f);
    u32 r = u + 0x7FFFu + ((u >> 16) & 1u);
    return (u16)(r >> 16);
}
__device__ __forceinline__ float b2f(u16 h) {
    u32 u = ((u32)h) << 16;
    return __builtin_bit_cast(float, u);
}
__device__ __forceinline__ u16x4 f4_to_b4(float4 v) {
    u16x4 o; o.x = f2b(v.x); o.y = f2b(v.y); o.z = f2b(v.z); o.w = f2b(v.w);
    return o;
}

// native transcendentals: single-instruction v_exp_f32 / v_log_f32
__device__ __forceinline__ float fexp2(float x) {
    float r;
    asm("v_exp_f32 %0, %1" : "=v"(r) : "v"(x));
    return r;
}
__device__ __forceinline__ float flog2(float x) {
    float r;
    asm("v_log_f32 %0, %1" : "=v"(r) : "v"(x));
    return r;
}

// DPP add: p += p[lane permuted by CTRL]  (pure VALU, no DS pipe)
template <int CTRL>
__device__ __forceinline__ float dpp_add(float p) {
    int pi = __builtin_bit_cast(int, p);
    int q  = __builtin_amdgcn_update_dpp(pi, pi, CTRL, 0xF, 0xF, false);
    return p + __builtin_bit_cast(float, q);
}
#define DPP_XOR1 0xB1   // quad_perm [1,0,3,2]
#define DPP_XOR2 0x4E   // quad_perm [2,3,0,1]
#define DPP_HMIR 0x141  // row_half_mirror (lane^7)
#define DPP_MIR  0x140  // row_mirror      (lane^15)

// ---------- constants ----------
#define MROWS   2048   // B*L
#define NSEG    16
#define SEGT    64
#define L2E     1.44269504088896340736f
#define LN2     0.69314718055994530942f

#define GLDS(g, l) __builtin_amdgcn_global_load_lds(                      \
    (const __attribute__((address_space(1))) void*)(g),                   \
    (__attribute__((address_space(3))) void*)(l), 16, 0, 0)

// ---------- merged fp32 -> bf16 weight conversion ----------
__global__ __launch_bounds__(256) void cvt_all(const float* __restrict__ W_in,
                                               const float* __restrict__ W_out,
                                               const float* __restrict__ W1,
                                               const float* __restrict__ W2,
                                               const float* __restrict__ W_dt,
                                               u16* __restrict__ Winb,
                                               u16* __restrict__ Woutb,
                                               u16* __restrict__ W1b,
                                               u16* __restrict__ W2b,
                                               u16* __restrict__ Wdtb) {
    const int i = blockIdx.x * 256 + threadIdx.x;
    const float* src; u16* dst; int off;
    if (i < 1048576)      { src = W_in;  dst = Winb;  off = i; }
    else if (i < 1572864) { src = W_out; dst = Woutb; off = i - 1048576; }
    else if (i < 2621440) { src = W1;    dst = W1b;   off = i - 1572864; }
    else if (i < 3670016) { src = W2;    dst = W2b;   off = i - 2621440; }
    else                  { src = W_dt;  dst = Wdtb;  off = i - 3670016; }
    float4 v = ((const float4*)src)[off];
    ((u16x4*)dst)[off] = f4_to_b4(v);
}

// pad W_xproj (96 x 2048) -> bf16 (128 x 2048), rows 96..127 = 0
__global__ __launch_bounds__(256) void pad_xproj_kernel(const float* __restrict__ in,
                                                        u16* __restrict__ out) {
    int i = blockIdx.x * 256 + threadIdx.x;    // over 128*512
    int r = i >> 9, c4 = i & 511;
    float4 v = make_float4(0.f, 0.f, 0.f, 0.f);
    if (r < 96) v = ((const float4*)(in + (size_t)r * 2048))[c4];
    ((u16x4*)(out + (size_t)r * 2048))[c4] = f4_to_b4(v);
}

// ---------- LayerNorm (row = 1024 cols), fp32 in -> bf16 out ----------
__global__ __launch_bounds__(256) void ln_kernel(const float* __restrict__ x,
                                                 const float* __restrict__ w,
                                                 const float* __restrict__ b,
                                                 u16* __restrict__ out) {
    const int row = blockIdx.x;
    const int tid = threadIdx.x;
    const float4 v = ((const float4*)(x + (size_t)row * 1024))[tid];
    float s = v.x + v.y + v.z + v.w;
    float q = v.x * v.x + v.y * v.y + v.z * v.z + v.w * v.w;
#pragma unroll
    for (int off = 1; off < 64; off <<= 1) {
        s += __shfl_xor(s, off, 64);
        q += __shfl_xor(q, off, 64);
    }
    __shared__ float ss[4], qq[4];
    const int wave = tid >> 6;
    if ((tid & 63) == 0) { ss[wave] = s; qq[wave] = q; }
    __syncthreads();
    s = ss[0] + ss[1] + ss[2] + ss[3];
    q = qq[0] + qq[1] + qq[2] + qq[3];
    const float mean = s * (1.f / 1024.f);
    const float var  = q * (1.f / 1024.f) - mean * mean;
    const float rstd = rsqrtf(var + 1e-5f);
    const float4 wv = ((const float4*)w)[tid];
    const float4 bv = ((const float4*)b)[tid];
    float4 o;
    o.x = (v.x - mean) * rstd * wv.x + bv.x;
    o.y = (v.y - mean) * rstd * wv.y + bv.y;
    o.z = (v.z - mean) * rstd * wv.z + bv.z;
    o.w = (v.w - mean) * rstd * wv.w + bv.w;
    ((u16x4*)(out + (size_t)row * 1024))[tid] = f4_to_b4(o);
}

// ---------- depthwise causal conv + bias + silu (bf16 in) -> tiled utl only ----------
__global__ __launch_bounds__(256) void conv_kernel(const u16* __restrict__ xzu,
                                                   const float* __restrict__ cw,
                                                   const float* __restrict__ cb,
                                                   u16* __restrict__ utl) {
    const int idx = blockIdx.x * 256 + threadIdx.x;   // over 2048 rows * 512 d4
    const int row = idx >> 9;
    const int d4  = idx & 511;
    const int d   = d4 * 4;
    const int bb  = row >> 10;
    const int t   = row & 1023;
    float w0[4], w1[4], w2[4], w3[4];
    *(float4*)w0 = ((const float4*)cw)[d + 0];
    *(float4*)w1 = ((const float4*)cw)[d + 1];
    *(float4*)w2 = ((const float4*)cw)[d + 2];
    *(float4*)w3 = ((const float4*)cw)[d + 3];
    float4 a = ((const float4*)cb)[d4];
#pragma unroll
    for (int j = 0; j < 4; ++j) {
        const int tt = t - 3 + j;
        if (tt >= 0) {
            const u16x4 uv = *(const u16x4*)(xzu + ((size_t)(bb * 1024 + tt)) * 2048 + d);
            a.x += b2f(uv.x) * w0[j];
            a.y += b2f(uv.y) * w1[j];
            a.z += b2f(uv.z) * w2[j];
            a.w += b2f(uv.w) * w3[j];
        }
    }
    float4 o;
    o.x = a.x / (1.f + __expf(-a.x));
    o.y = a.y / (1.f + __expf(-a.y));
    o.z = a.z / (1.f + __expf(-a.z));
    o.w = a.w / (1.f + __expf(-a.w));
    *(u16x4*)(utl + (((size_t)(d >> 4)) * 2048 + row) * 16 + (d & 15)) = f4_to_b4(o);
}

// ---------- 4-buffer single-barrier GEMM 128x128, 8 waves, XCD-swizzled ----------
// step k: wait own stage-k loads (vmcnt) -> barrier -> ds_read buf -> refill
// buffer (buf+3)&3 (safely consumed before last barrier) -> MFMA. ONE barrier/step.
// EPI: 3 = relu(c+bias) bf16; 5 = xz split; 10 = split-K partial fp32
template <int EPI>
__global__ __launch_bounds__(512) void gemm_tb(const u16* __restrict__ A,
                                               const u16* __restrict__ Bw,
                                               void* __restrict__ Cptr,
                                               void* __restrict__ Cptr2,
                                               const float* __restrict__ bias,
                                               int M, int N, int K, int KS) {
    const int nbm = gridDim.x, nbn = gridDim.y;
    const int nwg = nbm * nbn;
    const int id  = blockIdx.x + nbm * blockIdx.y;
    const int sw  = (nwg >= 8) ? ((id & 7) * (nwg >> 3) + (id >> 3)) : id;
    const int bm  = sw % nbm, bn = sw / nbm;

    __shared__ u16 Asm[4][128 * 32];
    __shared__ u16 Bsm[4][128 * 32];
    const int tid  = threadIdx.x;
    const int kz   = blockIdx.z;
    const int lane = tid & 63;
    const int wave = tid >> 6;
    const int wm   = wave >> 1, wn = wave & 1;
    const u16* Ag = A  + (size_t)bm * 128 * K;
    const u16* Bg = Bw + (size_t)bn * 128 * K;
    const int r0 = tid >> 2;            // 0..127
    const int sg = (tid & 3) * 8;
    const int k0 = kz * KS;
    const int nk = KS >> 5;
    const int fr = lane & 15, fk = (lane >> 4) * 8;

#define STG(bf, kk)                                                            \
    {                                                                          \
        const int kof = k0 + (kk) * 32;                                        \
        GLDS(Ag + (size_t)r0 * K + kof + sg, &Asm[bf][tid * 8]);               \
        GLDS(Bg + (size_t)r0 * K + kof + sg, &Bsm[bf][tid * 8]);               \
    }

    f32x4 acc[2][4] = {};
    STG(0, 0); STG(1, 1); STG(2, 2);
    int buf = 0;
    for (int k = 0; k < nk; ++k) {
        // per-wave: 2 loads/stage, 3 stages in flight
        if (k < nk - 2)       asm volatile("s_waitcnt vmcnt(4)" ::: "memory");
        else if (k == nk - 2) asm volatile("s_waitcnt vmcnt(2)" ::: "memory");
        else                  asm volatile("s_waitcnt vmcnt(0)" ::: "memory");
        __builtin_amdgcn_s_barrier();
        bf16x8 a[2], b[4];
#pragma unroll
        for (int m = 0; m < 2; ++m)
            a[m] = *(const bf16x8*)&Asm[buf][(wm * 32 + m * 16 + fr) * 32 + fk];
#pragma unroll
        for (int n = 0; n < 4; ++n)
            b[n] = *(const bf16x8*)&Bsm[buf][(wn * 64 + n * 16 + fr) * 32 + fk];
        if (k + 3 < nk) STG((buf + 3) & 3, k + 3);   // refill ring slot read 1 step ago
#pragma unroll
        for (int m = 0; m < 2; ++m)
#pragma unroll
            for (int n = 0; n < 4; ++n)
                acc[m][n] = __builtin_amdgcn_mfma_f32_16x16x32_bf16(a[m], b[n], acc[m][n], 0, 0, 0);
        buf = (buf + 1) & 3;
    }
#undef STG

    const int fq = lane >> 4;
#pragma unroll
    for (int m = 0; m < 2; ++m) {
#pragma unroll
        for (int n = 0; n < 4; ++n) {
            const int row0 = bm * 128 + wm * 32 + m * 16 + fq * 4;
            const int col  = bn * 128 + wn * 64 + n * 16 + fr;
#pragma unroll
            for (int j = 0; j < 4; ++j) {
                float v = acc[m][n][j];
                if constexpr (EPI == 3) {
                    v += bias[col];
                    ((u16*)Cptr)[(size_t)(row0 + j) * N + col] = f2b(fmaxf(v, 0.f));
                } else if constexpr (EPI == 5) {
                    if (col < 2048) {
                        ((u16*)Cptr)[(size_t)(row0 + j) * 2048 + col] = f2b(v);
                    } else {
                        const float sv = v / (1.f + __expf(-v));
                        const int zc = col - 2048;
                        ((u16*)Cptr2)[(((size_t)(zc >> 4)) * 2048 + row0 + j) * 16 + (zc & 15)]
                            = f2b(sv);
                    }
                } else {   // 10: split-K partial
                    ((float*)Cptr)[(size_t)kz * M * N + (size_t)(row0 + j) * N + col] = v;
                }
            }
        }
    }
}

// ---------- xproj GEMM: A from TILED utl; 4-buffer single-barrier; 256 thr ----------
__global__ __launch_bounds__(256) void gemm_xp(const u16* __restrict__ utl,
                                               const u16* __restrict__ Bw,
                                               float* __restrict__ part) {
    const int nwg = 16;
    const int id  = blockIdx.x;
    const int sw  = (id & 7) * (nwg >> 3) + (id >> 3);
    const int bm  = sw;
    __shared__ u16 Asm[4][128 * 32];
    __shared__ u16 Bsm[4][128 * 32];
    const int tid  = threadIdx.x;
    const int kz   = blockIdx.z;
    const int lane = tid & 63;
    const int wave = tid >> 6;
    const int wm   = wave >> 1, wn = wave & 1;
    const u16* Bg = Bw;
    const int r0 = tid >> 2;             // 0..63
    const int pc = tid & 3;              // K-piece 0..3 (8 u16 each)
    const int sg = pc * 8;
    const int k0 = kz * 256;
    const int fr = lane & 15, fk = (lane >> 4) * 8;

#define STGX(bf, kk)                                                                     \
    {                                                                                    \
        const int kof = k0 + (kk) * 32;                                                  \
        const int kc  = kof >> 4;                                                        \
        GLDS(utl + ((size_t)(kc + (pc >> 1)) * 2048 + bm * 128 + r0) * 16 + (pc & 1) * 8,\
             &Asm[bf][tid * 8]);                                                         \
        GLDS(utl + ((size_t)(kc + (pc >> 1)) * 2048 + bm * 128 + r0 + 64) * 16 + (pc & 1) * 8,\
             &Asm[bf][(tid + 256) * 8]);                                                 \
        GLDS(Bg + (size_t)r0 * 2048 + kof + sg, &Bsm[bf][tid * 8]);                      \
        GLDS(Bg + (size_t)(r0 + 64) * 2048 + kof + sg, &Bsm[bf][(tid + 256) * 8]);       \
    }

    f32x4 acc[4][4] = {};
    STGX(0, 0); STGX(1, 1); STGX(2, 2);
    int buf = 0;
    const int nk = 8;
    for (int k = 0; k < nk; ++k) {
        if (k < nk - 2)       asm volatile("s_waitcnt vmcnt(8)" ::: "memory");
        else if (k == nk - 2) asm volatile("s_waitcnt vmcnt(4)" ::: "memory");
        else                  asm volatile("s_waitcnt vmcnt(0)" ::: "memory");
        __builtin_amdgcn_s_barrier();
        bf16x8 a[4], b[4];
#pragma unroll
        for (int m = 0; m < 4; ++m)
            a[m] = *(const bf16x8*)&Asm[buf][(wm * 64 + m * 16 + fr) * 32 + fk];
#pragma unroll
        for (int n = 0; n < 4; ++n)
            b[n] = *(const bf16x8*)&Bsm[buf][(wn * 64 + n * 16 + fr) * 32 + fk];
        if (k + 3 < nk) STGX((buf + 3) & 3, k + 3);
#pragma unroll
        for (int m = 0; m < 4; ++m)
#pragma unroll
            for (int n = 0; n < 4; ++n)
                acc[m][n] = __builtin_amdgcn_mfma_f32_16x16x32_bf16(a[m], b[n], acc[m][n], 0, 0, 0);
        buf = (buf + 1) & 3;
    }
#undef STGX

    const int fq = lane >> 4;
    float* Cp = part + (size_t)kz * MROWS * 128;
#pragma unroll
    for (int m = 0; m < 4; ++m) {
#pragma unroll
        for (int n = 0; n < 4; ++n) {
            const int row0 = bm * 128 + wm * 64 + m * 16 + fq * 4;
            const int col  = wn * 64 + n * 16 + fr;
#pragma unroll
            for (int j = 0; j < 4; ++j)
                Cp[(size_t)(row0 + j) * 128 + col] = acc[m][n][j];
        }
    }
}

// combine split-K partials -> xdbr bf16 [2048,64] + bcp fp32 pair-packed:
// bcp[(t>>1)*64 + s*4 + (t&1)*2 + {0=B,1=C}]
__global__ __launch_bounds__(256) void xproj_combine(const float* __restrict__ part,
                                                     u16* __restrict__ xdbr,
                                                     float* __restrict__ bcp) {
    int i = blockIdx.x * 256 + threadIdx.x;     // over 2048*32
    int row = i >> 5, c4 = i & 31;
    if (c4 >= 24) return;
    float4 s = make_float4(0.f, 0.f, 0.f, 0.f);
#pragma unroll
    for (int p = 0; p < 8; ++p) {
        float4 v = ((const float4*)(part + (size_t)p * MROWS * 128 + (size_t)row * 128))[c4];
        s.x += v.x; s.y += v.y; s.z += v.z; s.w += v.w;
    }
    if (c4 < 16) {
        ((u16x4*)(xdbr + (size_t)row * 64))[c4] = f4_to_b4(s);
    } else {
        const int e0 = (c4 - 16) * 4;          // 0..31 over B(0..15)|C(16..31)
        float sv[4] = {s.x, s.y, s.z, s.w};
#pragma unroll
        for (int j = 0; j < 4; ++j) {
            const int e = e0 + j;
            const int st  = (e < 16) ? e : (e - 16);
            const int isc = (e < 16) ? 0 : 1;
            bcp[(size_t)(row >> 1) * 64 + st * 4 + (row & 1) * 2 + isc] = sv[j];
        }
    }
}

// ---------- selective scan: time-segmented, dt fused via MFMA ----------
__device__ __forceinline__ void compute_dtu_tile(const u16* __restrict__ xdbr,
                                                 const u16* __restrict__ Wdtb,
                                                 const float* __restrict__ b_dt,
                                                 const u16* __restrict__ utile,
                                                 float* __restrict__ du_s,
                                                 size_t t0, int d0, int w, int l) {
    const int fr = l & 15, fk = (l >> 4) * 8;
    const bf16x8 a0 = *(const bf16x8*)(xdbr + (t0 + w * 16 + fr) * 64 + fk);
    const bf16x8 a1 = *(const bf16x8*)(xdbr + (t0 + w * 16 + fr) * 64 + 32 + fk);
    const bf16x8 b0 = *(const bf16x8*)(Wdtb + (size_t)(d0 + fr) * 64 + fk);
    const bf16x8 b1 = *(const bf16x8*)(Wdtb + (size_t)(d0 + fr) * 64 + 32 + fk);
    const float bdt = b_dt[d0 + fr];
    f32x4 acc = {};
    acc = __builtin_amdgcn_mfma_f32_16x16x32_bf16(a0, b0, acc, 0, 0, 0);
    acc = __builtin_amdgcn_mfma_f32_16x16x32_bf16(a1, b1, acc, 0, 0, 0);
#pragma unroll
    for (int j = 0; j < 4; ++j) {
        const int row = w * 16 + (l >> 4) * 4 + j;
        float v = acc[j] + bdt;
        const float sp = flog2(1.f + fexp2(v * L2E)) * LN2;
        v = (v > 20.f) ? v : sp;
        const float uval = b2f(utile[(t0 + row) * 16 + fr]);
        float2 dv; dv.x = v; dv.y = v * uval;
        *(float2*)&du_s[(row >> 1) * 66 + fr * 4 + (row & 1) * 2] = dv;  // b64 write
    }
}

// stage bcp pair rows: 32 rows x 64 floats = 8KB, lane-linear per wave
__device__ __forceinline__ void stage_bc(const float* __restrict__ bcp,
                                         float* __restrict__ bc_s,
                                         size_t p0, int w, int l) {
    const int pr = (w << 3) + (l >> 4);
    const int pc = (l & 15) << 2;
    GLDS(bcp + (p0 + pr) * 64 + pc,     &bc_s[(w << 9)]);
    GLDS(bcp + (p0 + pr + 4) * 64 + pc, &bc_s[(w << 9) + 256]);
}

// grid (128, 2, 16): d-chunk, b, seg.  block 256.
__global__ __launch_bounds__(256) void scan_pass1(const u16* __restrict__ xdbr,
                                                  const u16* __restrict__ Wdtb,
                                                  const float* __restrict__ b_dt,
                                                  const u16* __restrict__ utl,
                                                  const float* __restrict__ bcp,
                                                  const float* __restrict__ A_log,
                                                  float* __restrict__ Qarr,
                                                  float* __restrict__ Sarr) {
    __shared__ __align__(16) float du_s[32 * 66];
    __shared__ __align__(16) float bc_s[32 * 64];

    const int tid = threadIdx.x;
    const int l   = tid & 63;
    const int w   = tid >> 6;
    const int s   = l & 15;
    const int g   = (w << 2) | (l >> 4);
    const int d0  = blockIdx.x << 4;
    const int b   = blockIdx.y;
    const int seg = blockIdx.z;
    const int d   = d0 + g;
    const size_t t0 = (size_t)b * 1024 + (size_t)seg * SEGT;
    const u16* utile = utl + (size_t)(d0 >> 4) * 2048 * 16;

    stage_bc(bcp, bc_s, t0 >> 1, w, l);
    compute_dtu_tile(xdbr, Wdtb, b_dt, utile, du_s, t0, d0, w, l);

    const float As2 = -__expf(A_log[d * 16 + s]) * L2E;
    asm volatile("s_waitcnt vmcnt(0) lgkmcnt(0)" ::: "memory");
    __builtin_amdgcn_s_barrier();

    float Q = 0.f, S = 0.f;
#pragma unroll 8
    for (int t2 = 0; t2 < 32; ++t2) {
        const float4 du4 = *(const float4*)&du_s[t2 * 66 + g * 4];
        const float4 BC2 = *(const float4*)&bc_s[t2 * 64 + s * 4];
        S += du4.x;
        Q = fexp2(du4.x * As2) * Q + du4.y * BC2.x;
        S += du4.z;
        Q = fexp2(du4.z * As2) * Q + du4.w * BC2.z;
    }
    Qarr[(((size_t)seg * 2 + b) * 2048 + d) * 16 + s] = Q;
    if (s == 0) Sarr[((size_t)seg * 2 + b) * 2048 + d] = S;
}

// prefix scan over segments: H0[i][b][d][s] = h entering segment i
__global__ __launch_bounds__(256) void scan_prefix(const float* __restrict__ Qarr,
                                                   const float* __restrict__ Sarr,
                                                   const float* __restrict__ A_log,
                                                   float* __restrict__ H0) {
    const int tid = threadIdx.x;
    const int d   = (blockIdx.x << 4) + (tid >> 4);
    const int s   = tid & 15;
    const int b   = blockIdx.y;
    const float As2 = -__expf(A_log[d * 16 + s]) * L2E;
    float h = 0.f;
#pragma unroll
    for (int i = 0; i < NSEG; ++i) {
        const size_t base = ((size_t)i * 2 + b) * 2048 + d;
        H0[base * 16 + s] = h;
        h = fexp2(As2 * Sarr[base]) * h + Qarr[base * 16 + s];
    }
}

__global__ __launch_bounds__(256) void scan_pass2(const u16* __restrict__ xdbr,
                                                  const u16* __restrict__ Wdtb,
                                                  const float* __restrict__ b_dt,
                                                  const u16* __restrict__ utl,
                                                  const float* __restrict__ bcp,
                                                  const u16* __restrict__ zst,
                                                  const float* __restrict__ A_log,
                                                  const float* __restrict__ Dp,
                                                  const float* __restrict__ H0,
                                                  u16* __restrict__ ymul) {
    __shared__ __align__(16) float du_s[32 * 66];   // overlaid by p_s after inner loop
    __shared__ __align__(16) float bc_s[32 * 64];

    const int tid = threadIdx.x;
    const int l   = tid & 63;
    const int w   = tid >> 6;
    const int s   = l & 15;
    const int g   = (w << 2) | (l >> 4);
    const int d0  = blockIdx.x << 4;
    const int b   = blockIdx.y;
    const int seg = blockIdx.z;
    const int d   = d0 + g;
    const size_t t0 = (size_t)b * 1024 + (size_t)seg * SEGT;
    const u16* utile = utl + (size_t)(d0 >> 4) * 2048 * 16;
    const u16* ztile = zst + (size_t)(d0 >> 4) * 2048 * 16;

    stage_bc(bcp, bc_s, t0 >> 1, w, l);
    compute_dtu_tile(xdbr, Wdtb, b_dt, utile, du_s, t0, d0, w, l);

    const float As2 = -__expf(A_log[d * 16 + s]) * L2E;
    float h = H0[(((size_t)seg * 2 + b) * 2048 + d) * 16 + s];

    asm volatile("s_waitcnt vmcnt(0) lgkmcnt(0)" ::: "memory");
    __builtin_amdgcn_s_barrier();

    float pk[4];
#pragma unroll
    for (int c = 0; c < 4; ++c) {
        pk[c] = 0.f;
#pragma unroll
        for (int q = 0; q < 8; ++q) {
            const int t2 = c * 8 + q;
            const float4 du4 = *(const float4*)&du_s[t2 * 66 + g * 4];
            const float4 BC2 = *(const float4*)&bc_s[t2 * 64 + s * 4];
            // even t
            h = fexp2(du4.x * As2) * h + du4.y * BC2.x;
            float p = h * BC2.y;
            p = dpp_add<DPP_XOR1>(p);
            p = dpp_add<DPP_XOR2>(p);
            p = dpp_add<DPP_HMIR>(p);
            p = dpp_add<DPP_MIR>(p);
            {
                const unsigned long long km = 0x0001000100010001ULL << (2 * q);
                asm("v_cndmask_b32 %0, %0, %1, %2" : "+v"(pk[c]) : "v"(p), "s"(km));
            }
            // odd t
            h = fexp2(du4.z * As2) * h + du4.w * BC2.z;
            p = h * BC2.w;
            p = dpp_add<DPP_XOR1>(p);
            p = dpp_add<DPP_XOR2>(p);
            p = dpp_add<DPP_HMIR>(p);
            p = dpp_add<DPP_MIR>(p);
            {
                const unsigned long long km = 0x0001000100010001ULL << (2 * q + 1);
                asm("v_cndmask_b32 %0, %0, %1, %2" : "+v"(pk[c]) : "v"(p), "s"(km));
            }
        }
    }

    __builtin_amdgcn_s_barrier();    // all waves done reading du_s (reuse as p_s)
    float* p_s = du_s;
#pragma unroll
    for (int c = 0; c < 4; ++c) {
        const int row = c * 16 + s;
        p_s[row * 16 + (g ^ (row & 12))] = pk[c];
    }

    asm volatile("s_waitcnt lgkmcnt(0)" ::: "memory");
    __builtin_amdgcn_s_barrier();

    // epilogue: u/z read directly from tiled global (coalesced, cache-warm)
    {
        const int tt = tid >> 2, cc = (tid & 3) << 2;
        const float4 pv = *(const float4*)&p_s[tt * 16 + (cc ^ (tt & 12))];
        const u16x4  uv = *(const u16x4*)(utile + (t0 + tt) * 16 + cc);
        const u16x4  zs = *(const u16x4*)(ztile + (t0 + tt) * 16 + cc);
        const float4 Dv = *(const float4*)(Dp + d0 + cc);
        float4 o;
        o.x = (pv.x + b2f(uv.x) * Dv.x) * b2f(zs.x);
        o.y = (pv.y + b2f(uv.y) * Dv.y) * b2f(zs.y);
        o.z = (pv.z + b2f(uv.z) * Dv.z) * b2f(zs.z);
        o.w = (pv.w + b2f(uv.w) * Dv.w) * b2f(zs.w);
        *(u16x4*)(ymul + (t0 + tt) * 2048 + d0 + cc) = f4_to_b4(o);
    }
}

// out = x2 + b2 + sum of 4 partials   [2048,1024] fp32
__global__ __launch_bounds__(256) void ffn2_combine(const float* __restrict__ part,
                                                    const float* __restrict__ x2,
                                                    const float* __restrict__ b2,
                                                    float* __restrict__ out) {
    int i = blockIdx.x * 256 + threadIdx.x;    // over 2048*256
    float4 s = ((const float4*)x2)[i];
    float4 bv = ((const float4*)b2)[i & 255];
    s.x += bv.x; s.y += bv.y; s.z += bv.z; s.w += bv.w;
#pragma unroll
    for (int p = 0; p < 4; ++p) {
        float4 v = ((const float4*)(part + (size_t)p * MROWS * 1024))[i];
        s.x += v.x; s.y += v.y; s.z += v.z; s.w += v.w;
    }
    ((float4*)out)[i] = s;
}

// x2 = x + part0 + part1; h2 = LN2(x2) bf16.   one block per row.
__global__ __launch_bounds__(256) void outproj_combine_ln2(const float* __restrict__ x,
                                                           const float* __restrict__ part,
                                                           const float* __restrict__ w,
                                                           const float* __restrict__ b,
                                                           float* __restrict__ x2,
                                                           u16* __restrict__ h2) {
    const int row = blockIdx.x;
    const int tid = threadIdx.x;
    float4 v = ((const float4*)(x + (size_t)row * 1024))[tid];
    float4 p0 = ((const float4*)(part + (size_t)row * 1024))[tid];
    float4 p1 = ((const float4*)(part + (size_t)MROWS * 1024 + (size_t)row * 1024))[tid];
    v.x += p0.x + p1.x; v.y += p0.y + p1.y; v.z += p0.z + p1.z; v.w += p0.w + p1.w;
    ((float4*)(x2 + (size_t)row * 1024))[tid] = v;
    float s = v.x + v.y + v.z + v.w;
    float q = v.x * v.x + v.y * v.y + v.z * v.z + v.w * v.w;
#pragma unroll
    for (int off = 1; off < 64; off <<= 1) {
        s += __shfl_xor(s, off, 64);
        q += __shfl_xor(q, off, 64);
    }
    __shared__ float ss[4], qq[4];
    const int wave = tid >> 6;
    if ((tid & 63) == 0) { ss[wave] = s; qq[wave] = q; }
    __syncthreads();
    s = ss[0] + ss[1] + ss[2] + ss[3];
    q = qq[0] + qq[1] + qq[2] + qq[3];
    const float mean = s * (1.f / 1024.f);
    const float var  = q * (1.f / 1024.f) - mean * mean;
    const float rstd = rsqrtf(var + 1e-5f);
    const float4 wv = ((const float4*)w)[tid];
    const float4 bv = ((const float4*)b)[tid];
    float4 o;
    o.x = (v.x - mean) * rstd * wv.x + bv.x;
    o.y = (v.y - mean) * rstd * wv.y + bv.y;
    o.z = (v.z - mean) * rstd * wv.z + bv.z;
    o.w = (v.w - mean) * rstd * wv.w + bv.w;
    ((u16x4*)(h2 + (size_t)row * 1024))[tid] = f4_to_b4(o);
}

// ---------- host launcher ----------
extern "C" void kernel_launch(void* const* d_in, const int* in_sizes, int n_in,
                              void* d_out, int out_size, void* d_ws, size_t ws_size,
                              hipStream_t stream) {
    const float* x      = (const float*)d_in[0];
    const float* ln1_w  = (const float*)d_in[1];
    const float* ln1_b  = (const float*)d_in[2];
    const float* W_in   = (const float*)d_in[3];
    const float* conv_w = (const float*)d_in[4];
    const float* conv_b = (const float*)d_in[5];
    const float* W_xproj= (const float*)d_in[6];
    const float* W_dt   = (const float*)d_in[7];
    const float* b_dt   = (const float*)d_in[8];
    const float* A_log  = (const float*)d_in[9];
    const float* Dvec   = (const float*)d_in[10];
    const float* W_out  = (const float*)d_in[11];
    const float* ln2_w  = (const float*)d_in[12];
    const float* ln2_b  = (const float*)d_in[13];
    const float* W1     = (const float*)d_in[14];
    const float* b1     = (const float*)d_in[15];
    const float* W2     = (const float*)d_in[16];
    const float* b2     = (const float*)d_in[17];
    float* out = (float*)d_out;
    char*  ws  = (char*)d_ws;
    const size_t MB = 1024ull * 1024ull;

    u16*   h1b   = (u16*)(ws + 0);              // 4 MB (reused as h2b)
    u16*   xzu   = (u16*)(ws + 4 * MB);         // 8 MB  [2048,2048] bf16 (u pre-conv)
    u16*   zst   = (u16*)(ws + 12 * MB);        // 8 MB  tiled silu(z) [128][2048][16]
    u16*   utl   = (u16*)(ws + 20 * MB);        // 8 MB  tiled u [128][2048][16]
    float* parts = (float*)(ws + 28 * MB);      // 8 MB  [8][2048][128] fp32
    float* bcp   = (float*)(ws + 36 * MB);      // 256 KB [1024 pairs][64]
    u16*   xdbr  = (u16*)(ws + 36 * MB + 256 * 1024);  // 256 KB
    u16*   Wdtb  = (u16*)(ws + 36 * MB + 512 * 1024);  // 256 KB
    u16*   ymul  = (u16*)(ws + 37 * MB);        // 8 MB
    float* Qarr  = (float*)(ws + 45 * MB);      // 4 MB  [16][2][2048][16]
    float* Sarr  = (float*)(ws + 49 * MB);      // 256 KB
    float* H0    = (float*)(ws + 50 * MB);      // 4 MB  [16][2][2048][16]
    float* x2    = (float*)(ws + 54 * MB);      // 8 MB
    u16*   Winb  = (u16*)(ws + 62 * MB);        // 8 MB
    u16*   Woutb = (u16*)(ws + 70 * MB);        // 4 MB
    u16*   W1b   = (u16*)(ws + 74 * MB);        // 8 MB
    u16*   W2b   = (u16*)(ws + 82 * MB);        // 8 MB
    u16*   Wxpb  = (u16*)(ws + 90 * MB);        // 512 KB
    u16*   h2b   = h1b;
    float* opart = (float*)(ws + 4 * MB);       // 16 MB (xzu+zst dead after pass2)
    u16*   f1    = (u16*)(ws + 4 * MB);         // 16 MB (opart dead after combine_ln2)
    float* fpart = (float*)(ws + 20 * MB);      // 32 MB (utl..H0 dead by FFN2)

    // weight conversions: 1 merged kernel + pad
    cvt_all<<<14464, 256, 0, stream>>>(W_in, W_out, W1, W2, W_dt,
                                       Winb, Woutb, W1b, W2b, Wdtb);
    pad_xproj_kernel<<<256, 256, 0, stream>>>(W_xproj, Wxpb);

    // LN1 -> h1 (bf16)
    ln_kernel<<<2048, 256, 0, stream>>>(x, ln1_w, ln1_b, h1b);
    // xz = h1 @ W_in^T : u-half -> bf16 xzu row-major, z-half -> silu -> TILED zst
    gemm_tb<5><<<dim3(16, 32, 1), 512, 0, stream>>>(h1b, Winb, xzu, zst, nullptr,
                                                    MROWS, 4096, 1024, 1024);
    // depthwise conv + silu -> tiled utl only
    conv_kernel<<<4096, 256, 0, stream>>>(xzu, conv_w, conv_b, utl);
    // xproj split-K (8 x K=256), A from tiled utl -> partials -> combine
    gemm_xp<<<dim3(16, 1, 8), 256, 0, stream>>>(utl, Wxpb, parts);
    xproj_combine<<<256, 256, 0, stream>>>(parts, xdbr, bcp);
    // selective scan: per-segment states -> prefix -> in-segment scan
    scan_pass1<<<dim3(128, 2, NSEG), 256, 0, stream>>>(xdbr, Wdtb, b_dt, utl, bcp, A_log,
                                                       Qarr, Sarr);
    scan_prefix<<<dim3(128, 2), 256, 0, stream>>>(Qarr, Sarr, A_log, H0);
    scan_pass2<<<dim3(128, 2, NSEG), 256, 0, stream>>>(xdbr, Wdtb, b_dt, utl, bcp, zst,
                                                       A_log, Dvec, H0, ymul);
    // out-proj split-K (2 x K=1024) -> partials; combine + residual + LN2 fused
    gemm_tb<10><<<dim3(16, 8, 2), 512, 0, stream>>>(ymul, Woutb, opart, nullptr, nullptr,
                                                    MROWS, 1024, 2048, 1024);
    outproj_combine_ln2<<<2048, 256, 0, stream>>>(x, opart, ln2_w, ln2_b, x2, h2b);
    // f1 = relu(h2 @ W1^T + b1)  bf16 [2048,4096]
    gemm_tb<3><<<dim3(16, 32, 1), 512, 0, stream>>>(h2b, W1b, f1, nullptr, b1,
                                                    MROWS, 4096, 1024, 1024);
    // FFN2 split-K (4 x K=1024) -> partials; combine + bias + residual
    gemm_tb<10><<<dim3(16, 8, 4), 512, 0, stream>>>(f1, W2b, fpart, nullptr, nullptr,
                                                    MROWS, 1024, 4096, 1024);
    ffn2_combine<<<2048, 256, 0, stream>>>(fpart, x2, b2, out);
}

// Round 16
// 216.183 us; speedup vs baseline: 1.1235x; 1.0037x over previous
//
#include <hip/hip_runtime.h>

typedef unsigned short u16;
typedef unsigned int   u32;
typedef short   bf16x8 __attribute__((ext_vector_type(8)));
typedef float   f32x4  __attribute__((ext_vector_type(4)));
typedef u16     u16x4  __attribute__((ext_vector_type(4)));

// ---------- bf16 helpers (RNE) ----------
__device__ __forceinline__ u16 f2b(float f) {
    u32 u = __builtin_bit_cast(u32, f);
    u32 r = u + 0x7FFFu + ((u >> 16) & 1u);
    return (u16)(r >> 16);
}
__device__ __forceinline__ float b2f(u16 h) {
    u32 u = ((u32)h) << 16;
    return __builtin_bit_cast(float, u);
}
__device__ __forceinline__ u16x4 f4_to_b4(float4 v) {
    u16x4 o; o.x = f2b(v.x); o.y = f2b(v.y); o.z = f2b(v.z); o.w = f2b(v.w);
    return o;
}

// native transcendentals: single-instruction v_exp_f32 / v_log_f32
__device__ __forceinline__ float fexp2(float x) {
    float r;
    asm("v_exp_f32 %0, %1" : "=v"(r) : "v"(x));
    return r;
}
__device__ __forceinline__ float flog2(float x) {
    float r;
    asm("v_log_f32 %0, %1" : "=v"(r) : "v"(x));
    return r;
}

// DPP add: p += p[lane permuted by CTRL]  (pure VALU, no DS pipe)
template <int CTRL>
__device__ __forceinline__ float dpp_add(float p) {
    int pi = __builtin_bit_cast(int, p);
    int q  = __builtin_amdgcn_update_dpp(pi, pi, CTRL, 0xF, 0xF, false);
    return p + __builtin_bit_cast(float, q);
}
#define DPP_XOR1 0xB1   // quad_perm [1,0,3,2]
#define DPP_XOR2 0x4E   // quad_perm [2,3,0,1]
#define DPP_HMIR 0x141  // row_half_mirror (lane^7)
#define DPP_MIR  0x140  // row_mirror      (lane^15)

// ---------- constants ----------
#define MROWS   2048   // B*L
#define NSEG    16
#define SEGT    64
#define L2E     1.44269504088896340736f
#define LN2     0.69314718055994530942f

#define GLDS(g, l) __builtin_amdgcn_global_load_lds(                      \
    (const __attribute__((address_space(1))) void*)(g),                   \
    (__attribute__((address_space(3))) void*)(l), 16, 0, 0)

// ---------- merged fp32 -> bf16 weight conversion ----------
__global__ __launch_bounds__(256) void cvt_all(const float* __restrict__ W_in,
                                               const float* __restrict__ W_out,
                                               const float* __restrict__ W1,
                                               const float* __restrict__ W2,
                                               const float* __restrict__ W_dt,
                                               u16* __restrict__ Winb,
                                               u16* __restrict__ Woutb,
                                               u16* __restrict__ W1b,
                                               u16* __restrict__ W2b,
                                               u16* __restrict__ Wdtb) {
    const int i = blockIdx.x * 256 + threadIdx.x;
    const float* src; u16* dst; int off;
    if (i < 1048576)      { src = W_in;  dst = Winb;  off = i; }
    else if (i < 1572864) { src = W_out; dst = Woutb; off = i - 1048576; }
    else if (i < 2621440) { src = W1;    dst = W1b;   off = i - 1572864; }
    else if (i < 3670016) { src = W2;    dst = W2b;   off = i - 2621440; }
    else                  { src = W_dt;  dst = Wdtb;  off = i - 3670016; }
    float4 v = ((const float4*)src)[off];
    ((u16x4*)dst)[off] = f4_to_b4(v);
}

// pad W_xproj (96 x 2048) -> bf16 (128 x 2048), rows 96..127 = 0
__global__ __launch_bounds__(256) void pad_xproj_kernel(const float* __restrict__ in,
                                                        u16* __restrict__ out) {
    int i = blockIdx.x * 256 + threadIdx.x;    // over 128*512
    int r = i >> 9, c4 = i & 511;
    float4 v = make_float4(0.f, 0.f, 0.f, 0.f);
    if (r < 96) v = ((const float4*)(in + (size_t)r * 2048))[c4];
    ((u16x4*)(out + (size_t)r * 2048))[c4] = f4_to_b4(v);
}

// ---------- LayerNorm (row = 1024 cols), fp32 in -> bf16 out ----------
__global__ __launch_bounds__(256) void ln_kernel(const float* __restrict__ x,
                                                 const float* __restrict__ w,
                                                 const float* __restrict__ b,
                                                 u16* __restrict__ out) {
    const int row = blockIdx.x;
    const int tid = threadIdx.x;
    const float4 v = ((const float4*)(x + (size_t)row * 1024))[tid];
    float s = v.x + v.y + v.z + v.w;
    float q = v.x * v.x + v.y * v.y + v.z * v.z + v.w * v.w;
#pragma unroll
    for (int off = 1; off < 64; off <<= 1) {
        s += __shfl_xor(s, off, 64);
        q += __shfl_xor(q, off, 64);
    }
    __shared__ float ss[4], qq[4];
    const int wave = tid >> 6;
    if ((tid & 63) == 0) { ss[wave] = s; qq[wave] = q; }
    __syncthreads();
    s = ss[0] + ss[1] + ss[2] + ss[3];
    q = qq[0] + qq[1] + qq[2] + qq[3];
    const float mean = s * (1.f / 1024.f);
    const float var  = q * (1.f / 1024.f) - mean * mean;
    const float rstd = rsqrtf(var + 1e-5f);
    const float4 wv = ((const float4*)w)[tid];
    const float4 bv = ((const float4*)b)[tid];
    float4 o;
    o.x = (v.x - mean) * rstd * wv.x + bv.x;
    o.y = (v.y - mean) * rstd * wv.y + bv.y;
    o.z = (v.z - mean) * rstd * wv.z + bv.z;
    o.w = (v.w - mean) * rstd * wv.w + bv.w;
    ((u16x4*)(out + (size_t)row * 1024))[tid] = f4_to_b4(o);
}

// ---------- depthwise causal conv + bias + silu (bf16 in) -> tiled utl only ----------
__global__ __launch_bounds__(256) void conv_kernel(const u16* __restrict__ xzu,
                                                   const float* __restrict__ cw,
                                                   const float* __restrict__ cb,
                                                   u16* __restrict__ utl) {
    const int idx = blockIdx.x * 256 + threadIdx.x;   // over 2048 rows * 512 d4
    const int row = idx >> 9;
    const int d4  = idx & 511;
    const int d   = d4 * 4;
    const int bb  = row >> 10;
    const int t   = row & 1023;
    float w0[4], w1[4], w2[4], w3[4];
    *(float4*)w0 = ((const float4*)cw)[d + 0];
    *(float4*)w1 = ((const float4*)cw)[d + 1];
    *(float4*)w2 = ((const float4*)cw)[d + 2];
    *(float4*)w3 = ((const float4*)cw)[d + 3];
    float4 a = ((const float4*)cb)[d4];
#pragma unroll
    for (int j = 0; j < 4; ++j) {
        const int tt = t - 3 + j;
        if (tt >= 0) {
            const u16x4 uv = *(const u16x4*)(xzu + ((size_t)(bb * 1024 + tt)) * 2048 + d);
            a.x += b2f(uv.x) * w0[j];
            a.y += b2f(uv.y) * w1[j];
            a.z += b2f(uv.z) * w2[j];
            a.w += b2f(uv.w) * w3[j];
        }
    }
    float4 o;
    o.x = a.x / (1.f + __expf(-a.x));
    o.y = a.y / (1.f + __expf(-a.y));
    o.z = a.z / (1.f + __expf(-a.z));
    o.w = a.w / (1.f + __expf(-a.w));
    *(u16x4*)(utl + (((size_t)(d >> 4)) * 2048 + row) * 16 + (d & 15)) = f4_to_b4(o);
}

// ---------- 3-buffer single-barrier GEMM 128x128, 8 waves, XCD-swizzled ----------
// ring: step k reads buf k%3, refills slot (k+2)%3 (= the slot read at step k-1,
// fully consumed by every wave's MFMAs before barrier k). ONE barrier per step.
// LDS 48 KB -> 3 blocks/CU (24 waves/CU).
// EPI: 3 = relu(c+bias) bf16; 5 = xz split; 10 = split-K partial fp32
template <int EPI>
__global__ __launch_bounds__(512) void gemm_tb(const u16* __restrict__ A,
                                               const u16* __restrict__ Bw,
                                               void* __restrict__ Cptr,
                                               void* __restrict__ Cptr2,
                                               const float* __restrict__ bias,
                                               int M, int N, int K, int KS) {
    const int nbm = gridDim.x, nbn = gridDim.y;
    const int nwg = nbm * nbn;
    const int id  = blockIdx.x + nbm * blockIdx.y;
    const int sw  = (nwg >= 8) ? ((id & 7) * (nwg >> 3) + (id >> 3)) : id;
    const int bm  = sw % nbm, bn = sw / nbm;

    __shared__ u16 Asm[3][128 * 32];
    __shared__ u16 Bsm[3][128 * 32];
    const int tid  = threadIdx.x;
    const int kz   = blockIdx.z;
    const int lane = tid & 63;
    const int wave = tid >> 6;
    const int wm   = wave >> 1, wn = wave & 1;
    const u16* Ag = A  + (size_t)bm * 128 * K;
    const u16* Bg = Bw + (size_t)bn * 128 * K;
    const int r0 = tid >> 2;            // 0..127
    const int sg = (tid & 3) * 8;
    const int k0 = kz * KS;
    const int nk = KS >> 5;
    const int fr = lane & 15, fk = (lane >> 4) * 8;

#define STG(bf, kk)                                                            \
    {                                                                          \
        const int kof = k0 + (kk) * 32;                                        \
        GLDS(Ag + (size_t)r0 * K + kof + sg, &Asm[bf][tid * 8]);               \
        GLDS(Bg + (size_t)r0 * K + kof + sg, &Bsm[bf][tid * 8]);               \
    }

    f32x4 acc[2][4] = {};
    STG(0, 0); STG(1, 1);
    int buf = 0;
    for (int k = 0; k < nk; ++k) {
        // per-wave: 2 loads/stage, 2 stages in flight
        if (k < nk - 1) asm volatile("s_waitcnt vmcnt(2)" ::: "memory");
        else            asm volatile("s_waitcnt vmcnt(0)" ::: "memory");
        __builtin_amdgcn_s_barrier();
        bf16x8 a[2], b[4];
#pragma unroll
        for (int m = 0; m < 2; ++m)
            a[m] = *(const bf16x8*)&Asm[buf][(wm * 32 + m * 16 + fr) * 32 + fk];
#pragma unroll
        for (int n = 0; n < 4; ++n)
            b[n] = *(const bf16x8*)&Bsm[buf][(wn * 64 + n * 16 + fr) * 32 + fk];
        if (k + 2 < nk) {                      // refill slot consumed at step k-1
            const int slot = (buf + 2) % 3;
            STG(slot, k + 2);
        }
#pragma unroll
        for (int m = 0; m < 2; ++m)
#pragma unroll
            for (int n = 0; n < 4; ++n)
                acc[m][n] = __builtin_amdgcn_mfma_f32_16x16x32_bf16(a[m], b[n], acc[m][n], 0, 0, 0);
        buf = (buf == 2) ? 0 : buf + 1;
    }
#undef STG

    const int fq = lane >> 4;
#pragma unroll
    for (int m = 0; m < 2; ++m) {
#pragma unroll
        for (int n = 0; n < 4; ++n) {
            const int row0 = bm * 128 + wm * 32 + m * 16 + fq * 4;
            const int col  = bn * 128 + wn * 64 + n * 16 + fr;
#pragma unroll
            for (int j = 0; j < 4; ++j) {
                float v = acc[m][n][j];
                if constexpr (EPI == 3) {
                    v += bias[col];
                    ((u16*)Cptr)[(size_t)(row0 + j) * N + col] = f2b(fmaxf(v, 0.f));
                } else if constexpr (EPI == 5) {
                    if (col < 2048) {
                        ((u16*)Cptr)[(size_t)(row0 + j) * 2048 + col] = f2b(v);
                    } else {
                        const float sv = v / (1.f + __expf(-v));
                        const int zc = col - 2048;
                        ((u16*)Cptr2)[(((size_t)(zc >> 4)) * 2048 + row0 + j) * 16 + (zc & 15)]
                            = f2b(sv);
                    }
                } else {   // 10: split-K partial
                    ((float*)Cptr)[(size_t)kz * M * N + (size_t)(row0 + j) * N + col] = v;
                }
            }
        }
    }
}

// ---------- xproj GEMM: A from TILED utl; 3-buffer single-barrier; 256 thr ----------
__global__ __launch_bounds__(256) void gemm_xp(const u16* __restrict__ utl,
                                               const u16* __restrict__ Bw,
                                               float* __restrict__ part) {
    const int nwg = 16;
    const int id  = blockIdx.x;
    const int sw  = (id & 7) * (nwg >> 3) + (id >> 3);
    const int bm  = sw;
    __shared__ u16 Asm[3][128 * 32];
    __shared__ u16 Bsm[3][128 * 32];
    const int tid  = threadIdx.x;
    const int kz   = blockIdx.z;
    const int lane = tid & 63;
    const int wave = tid >> 6;
    const int wm   = wave >> 1, wn = wave & 1;
    const u16* Bg = Bw;
    const int r0 = tid >> 2;             // 0..63
    const int pc = tid & 3;              // K-piece 0..3 (8 u16 each)
    const int sg = pc * 8;
    const int k0 = kz * 256;
    const int fr = lane & 15, fk = (lane >> 4) * 8;

#define STGX(bf, kk)                                                                     \
    {                                                                                    \
        const int kof = k0 + (kk) * 32;                                                  \
        const int kc  = kof >> 4;                                                        \
        GLDS(utl + ((size_t)(kc + (pc >> 1)) * 2048 + bm * 128 + r0) * 16 + (pc & 1) * 8,\
             &Asm[bf][tid * 8]);                                                         \
        GLDS(utl + ((size_t)(kc + (pc >> 1)) * 2048 + bm * 128 + r0 + 64) * 16 + (pc & 1) * 8,\
             &Asm[bf][(tid + 256) * 8]);                                                 \
        GLDS(Bg + (size_t)r0 * 2048 + kof + sg, &Bsm[bf][tid * 8]);                      \
        GLDS(Bg + (size_t)(r0 + 64) * 2048 + kof + sg, &Bsm[bf][(tid + 256) * 8]);       \
    }

    f32x4 acc[4][4] = {};
    STGX(0, 0); STGX(1, 1);
    int buf = 0;
    const int nk = 8;
    for (int k = 0; k < nk; ++k) {
        if (k < nk - 1) asm volatile("s_waitcnt vmcnt(4)" ::: "memory");
        else            asm volatile("s_waitcnt vmcnt(0)" ::: "memory");
        __builtin_amdgcn_s_barrier();
        bf16x8 a[4], b[4];
#pragma unroll
        for (int m = 0; m < 4; ++m)
            a[m] = *(const bf16x8*)&Asm[buf][(wm * 64 + m * 16 + fr) * 32 + fk];
#pragma unroll
        for (int n = 0; n < 4; ++n)
            b[n] = *(const bf16x8*)&Bsm[buf][(wn * 64 + n * 16 + fr) * 32 + fk];
        if (k + 2 < nk) {
            const int slot = (buf + 2) % 3;
            STGX(slot, k + 2);
        }
#pragma unroll
        for (int m = 0; m < 4; ++m)
#pragma unroll
            for (int n = 0; n < 4; ++n)
                acc[m][n] = __builtin_amdgcn_mfma_f32_16x16x32_bf16(a[m], b[n], acc[m][n], 0, 0, 0);
        buf = (buf == 2) ? 0 : buf + 1;
    }
#undef STGX

    const int fq = lane >> 4;
    float* Cp = part + (size_t)kz * MROWS * 128;
#pragma unroll
    for (int m = 0; m < 4; ++m) {
#pragma unroll
        for (int n = 0; n < 4; ++n) {
            const int row0 = bm * 128 + wm * 64 + m * 16 + fq * 4;
            const int col  = wn * 64 + n * 16 + fr;
#pragma unroll
            for (int j = 0; j < 4; ++j)
                Cp[(size_t)(row0 + j) * 128 + col] = acc[m][n][j];
        }
    }
}

// combine split-K partials -> xdbr bf16 [2048,64] + bcp fp32 pair-packed +
// bpk (B-only, pass1): bpk[(t>>1)*32 + s*2 + (t&1)]
__global__ __launch_bounds__(256) void xproj_combine(const float* __restrict__ part,
                                                     u16* __restrict__ xdbr,
                                                     float* __restrict__ bcp,
                                                     float* __restrict__ bpk) {
    int i = blockIdx.x * 256 + threadIdx.x;     // over 2048*32
    int row = i >> 5, c4 = i & 31;
    if (c4 >= 24) return;
    float4 s = make_float4(0.f, 0.f, 0.f, 0.f);
#pragma unroll
    for (int p = 0; p < 8; ++p) {
        float4 v = ((const float4*)(part + (size_t)p * MROWS * 128 + (size_t)row * 128))[c4];
        s.x += v.x; s.y += v.y; s.z += v.z; s.w += v.w;
    }
    if (c4 < 16) {
        ((u16x4*)(xdbr + (size_t)row * 64))[c4] = f4_to_b4(s);
    } else {
        const int e0 = (c4 - 16) * 4;          // 0..31 over B(0..15)|C(16..31)
        float sv[4] = {s.x, s.y, s.z, s.w};
#pragma unroll
        for (int j = 0; j < 4; ++j) {
            const int e = e0 + j;
            const int st  = (e < 16) ? e : (e - 16);
            const int isc = (e < 16) ? 0 : 1;
            bcp[(size_t)(row >> 1) * 64 + st * 4 + (row & 1) * 2 + isc] = sv[j];
            if (e < 16)
                bpk[(size_t)(row >> 1) * 32 + st * 2 + (row & 1)] = sv[j];
        }
    }
}

// ---------- selective scan: time-segmented, dt fused via MFMA ----------
__device__ __forceinline__ void compute_dtu_tile(const u16* __restrict__ xdbr,
                                                 const u16* __restrict__ Wdtb,
                                                 const float* __restrict__ b_dt,
                                                 const u16* __restrict__ utile,
                                                 float* __restrict__ du_s,
                                                 size_t t0, int d0, int w, int l) {
    const int fr = l & 15, fk = (l >> 4) * 8;
    const bf16x8 a0 = *(const bf16x8*)(xdbr + (t0 + w * 16 + fr) * 64 + fk);
    const bf16x8 a1 = *(const bf16x8*)(xdbr + (t0 + w * 16 + fr) * 64 + 32 + fk);
    const bf16x8 b0 = *(const bf16x8*)(Wdtb + (size_t)(d0 + fr) * 64 + fk);
    const bf16x8 b1 = *(const bf16x8*)(Wdtb + (size_t)(d0 + fr) * 64 + 32 + fk);
    const float bdt = b_dt[d0 + fr];
    f32x4 acc = {};
    acc = __builtin_amdgcn_mfma_f32_16x16x32_bf16(a0, b0, acc, 0, 0, 0);
    acc = __builtin_amdgcn_mfma_f32_16x16x32_bf16(a1, b1, acc, 0, 0, 0);
#pragma unroll
    for (int j = 0; j < 4; ++j) {
        const int row = w * 16 + (l >> 4) * 4 + j;
        float v = acc[j] + bdt;
        const float sp = flog2(1.f + fexp2(v * L2E)) * LN2;
        v = (v > 20.f) ? v : sp;
        const float uval = b2f(utile[(t0 + row) * 16 + fr]);
        float2 dv; dv.x = v; dv.y = v * uval;
        *(float2*)&du_s[(row >> 1) * 66 + fr * 4 + (row & 1) * 2] = dv;  // b64 write
    }
}

// stage bcp pair rows: 32 rows x 64 floats = 8KB, lane-linear per wave
__device__ __forceinline__ void stage_bc(const float* __restrict__ bcp,
                                         float* __restrict__ bc_s,
                                         size_t p0, int w, int l) {
    const int pr = (w << 3) + (l >> 4);
    const int pc = (l & 15) << 2;
    GLDS(bcp + (p0 + pr) * 64 + pc,     &bc_s[(w << 9)]);
    GLDS(bcp + (p0 + pr + 4) * 64 + pc, &bc_s[(w << 9) + 256]);
}

// grid (128, 2, 16): d-chunk, b, seg.  block 256.
__global__ __launch_bounds__(256) void scan_pass1(const u16* __restrict__ xdbr,
                                                  const u16* __restrict__ Wdtb,
                                                  const float* __restrict__ b_dt,
                                                  const u16* __restrict__ utl,
                                                  const float* __restrict__ bpk,
                                                  const float* __restrict__ A_log,
                                                  float* __restrict__ Qarr,
                                                  float* __restrict__ Sarr) {
    __shared__ __align__(16) float du_s[32 * 66];
    __shared__ __align__(16) float bp_s[32 * 32];   // B-only: [pair-row][s*2 + t&1]

    const int tid = threadIdx.x;
    const int l   = tid & 63;
    const int w   = tid >> 6;
    const int s   = l & 15;
    const int g   = (w << 2) | (l >> 4);
    const int d0  = blockIdx.x << 4;
    const int b   = blockIdx.y;
    const int seg = blockIdx.z;
    const int d   = d0 + g;
    const size_t t0 = (size_t)b * 1024 + (size_t)seg * SEGT;
    const u16* utile = utl + (size_t)(d0 >> 4) * 2048 * 16;

    // B-only staging: 4KB, one GLDS per thread (pair-row tid>>3, col (tid&7)*4)
    GLDS(bpk + ((t0 >> 1) + (tid >> 3)) * 32 + ((tid & 7) << 2), &bp_s[w << 8]);
    compute_dtu_tile(xdbr, Wdtb, b_dt, utile, du_s, t0, d0, w, l);

    const float As2 = -__expf(A_log[d * 16 + s]) * L2E;
    asm volatile("s_waitcnt vmcnt(0) lgkmcnt(0)" ::: "memory");
    __builtin_amdgcn_s_barrier();

    float Q = 0.f, S = 0.f;
#pragma unroll 8
    for (int t2 = 0; t2 < 32; ++t2) {
        const float4 du4 = *(const float4*)&du_s[t2 * 66 + g * 4];
        const float2 Bp  = *(const float2*)&bp_s[t2 * 32 + s * 2];
        S += du4.x;
        Q = fexp2(du4.x * As2) * Q + du4.y * Bp.x;
        S += du4.z;
        Q = fexp2(du4.z * As2) * Q + du4.w * Bp.y;
    }
    Qarr[(((size_t)seg * 2 + b) * 2048 + d) * 16 + s] = Q;
    if (s == 0) Sarr[((size_t)seg * 2 + b) * 2048 + d] = S;
}

// prefix scan over segments: H0[i][b][d][s] = h entering segment i
__global__ __launch_bounds__(256) void scan_prefix(const float* __restrict__ Qarr,
                                                   const float* __restrict__ Sarr,
                                                   const float* __restrict__ A_log,
                                                   float* __restrict__ H0) {
    const int tid = threadIdx.x;
    const int d   = (blockIdx.x << 4) + (tid >> 4);
    const int s   = tid & 15;
    const int b   = blockIdx.y;
    const float As2 = -__expf(A_log[d * 16 + s]) * L2E;
    float h = 0.f;
#pragma unroll
    for (int i = 0; i < NSEG; ++i) {
        const size_t base = ((size_t)i * 2 + b) * 2048 + d;
        H0[base * 16 + s] = h;
        h = fexp2(As2 * Sarr[base]) * h + Qarr[base * 16 + s];
    }
}

__global__ __launch_bounds__(256) void scan_pass2(const u16* __restrict__ xdbr,
                                                  const u16* __restrict__ Wdtb,
                                                  const float* __restrict__ b_dt,
                                                  const u16* __restrict__ utl,
                                                  const float* __restrict__ bcp,
                                                  const u16* __restrict__ zst,
                                                  const float* __restrict__ A_log,
                                                  const float* __restrict__ Dp,
                                                  const float* __restrict__ H0,
                                                  u16* __restrict__ ymul) {
    __shared__ __align__(16) float du_s[32 * 66];   // overlaid by p_s after inner loop
    __shared__ __align__(16) float bc_s[32 * 64];

    const int tid = threadIdx.x;
    const int l   = tid & 63;
    const int w   = tid >> 6;
    const int s   = l & 15;
    const int g   = (w << 2) | (l >> 4);
    const int d0  = blockIdx.x << 4;
    const int b   = blockIdx.y;
    const int seg = blockIdx.z;
    const int d   = d0 + g;
    const size_t t0 = (size_t)b * 1024 + (size_t)seg * SEGT;
    const u16* utile = utl + (size_t)(d0 >> 4) * 2048 * 16;
    const u16* ztile = zst + (size_t)(d0 >> 4) * 2048 * 16;

    stage_bc(bcp, bc_s, t0 >> 1, w, l);
    compute_dtu_tile(xdbr, Wdtb, b_dt, utile, du_s, t0, d0, w, l);

    const float As2 = -__expf(A_log[d * 16 + s]) * L2E;
    float h = H0[(((size_t)seg * 2 + b) * 2048 + d) * 16 + s];

    asm volatile("s_waitcnt vmcnt(0) lgkmcnt(0)" ::: "memory");
    __builtin_amdgcn_s_barrier();

    float pk[4];
#pragma unroll
    for (int c = 0; c < 4; ++c) {
        pk[c] = 0.f;
#pragma unroll
        for (int q = 0; q < 8; ++q) {
            const int t2 = c * 8 + q;
            const float4 du4 = *(const float4*)&du_s[t2 * 66 + g * 4];
            const float4 BC2 = *(const float4*)&bc_s[t2 * 64 + s * 4];
            // even t
            h = fexp2(du4.x * As2) * h + du4.y * BC2.x;
            float p = h * BC2.y;
            p = dpp_add<DPP_XOR1>(p);
            p = dpp_add<DPP_XOR2>(p);
            p = dpp_add<DPP_HMIR>(p);
            p = dpp_add<DPP_MIR>(p);
            {
                const unsigned long long km = 0x0001000100010001ULL << (2 * q);
                asm("v_cndmask_b32 %0, %0, %1, %2" : "+v"(pk[c]) : "v"(p), "s"(km));
            }
            // odd t
            h = fexp2(du4.z * As2) * h + du4.w * BC2.z;
            p = h * BC2.w;
            p = dpp_add<DPP_XOR1>(p);
            p = dpp_add<DPP_XOR2>(p);
            p = dpp_add<DPP_HMIR>(p);
            p = dpp_add<DPP_MIR>(p);
            {
                const unsigned long long km = 0x0001000100010001ULL << (2 * q + 1);
                asm("v_cndmask_b32 %0, %0, %1, %2" : "+v"(pk[c]) : "v"(p), "s"(km));
            }
        }
    }

    __builtin_amdgcn_s_barrier();    // all waves done reading du_s (reuse as p_s)
    float* p_s = du_s;
#pragma unroll
    for (int c = 0; c < 4; ++c) {
        const int row = c * 16 + s;
        p_s[row * 16 + (g ^ (row & 12))] = pk[c];
    }

    asm volatile("s_waitcnt lgkmcnt(0)" ::: "memory");
    __builtin_amdgcn_s_barrier();

    // epilogue: u/z read directly from tiled global (coalesced, cache-warm)
    {
        const int tt = tid >> 2, cc = (tid & 3) << 2;
        const float4 pv = *(const float4*)&p_s[tt * 16 + (cc ^ (tt & 12))];
        const u16x4  uv = *(const u16x4*)(utile + (t0 + tt) * 16 + cc);
        const u16x4  zs = *(const u16x4*)(ztile + (t0 + tt) * 16 + cc);
        const float4 Dv = *(const float4*)(Dp + d0 + cc);
        float4 o;
        o.x = (pv.x + b2f(uv.x) * Dv.x) * b2f(zs.x);
        o.y = (pv.y + b2f(uv.y) * Dv.y) * b2f(zs.y);
        o.z = (pv.z + b2f(uv.z) * Dv.z) * b2f(zs.z);
        o.w = (pv.w + b2f(uv.w) * Dv.w) * b2f(zs.w);
        *(u16x4*)(ymul + (t0 + tt) * 2048 + d0 + cc) = f4_to_b4(o);
    }
}

// out = x2 + b2 + sum of 4 partials   [2048,1024] fp32
__global__ __launch_bounds__(256) void ffn2_combine(const float* __restrict__ part,
                                                    const float* __restrict__ x2,
                                                    const float* __restrict__ b2,
                                                    float* __restrict__ out) {
    int i = blockIdx.x * 256 + threadIdx.x;    // over 2048*256
    float4 s = ((const float4*)x2)[i];
    float4 bv = ((const float4*)b2)[i & 255];
    s.x += bv.x; s.y += bv.y; s.z += bv.z; s.w += bv.w;
#pragma unroll
    for (int p = 0; p < 4; ++p) {
        float4 v = ((const float4*)(part + (size_t)p * MROWS * 1024))[i];
        s.x += v.x; s.y += v.y; s.z += v.z; s.w += v.w;
    }
    ((float4*)out)[i] = s;
}

// x2 = x + part0 + part1; h2 = LN2(x2) bf16.   one block per row.
__global__ __launch_bounds__(256) void outproj_combine_ln2(const float* __restrict__ x,
                                                           const float* __restrict__ part,
                                                           const float* __restrict__ w,
                                                           const float* __restrict__ b,
                                                           float* __restrict__ x2,
                                                           u16* __restrict__ h2) {
    const int row = blockIdx.x;
    const int tid = threadIdx.x;
    float4 v = ((const float4*)(x + (size_t)row * 1024))[tid];
    float4 p0 = ((const float4*)(part + (size_t)row * 1024))[tid];
    float4 p1 = ((const float4*)(part + (size_t)MROWS * 1024 + (size_t)row * 1024))[tid];
    v.x += p0.x + p1.x; v.y += p0.y + p1.y; v.z += p0.z + p1.z; v.w += p0.w + p1.w;
    ((float4*)(x2 + (size_t)row * 1024))[tid] = v;
    float s = v.x + v.y + v.z + v.w;
    float q = v.x * v.x + v.y * v.y + v.z * v.z + v.w * v.w;
#pragma unroll
    for (int off = 1; off < 64; off <<= 1) {
        s += __shfl_xor(s, off, 64);
        q += __shfl_xor(q, off, 64);
    }
    __shared__ float ss[4], qq[4];
    const int wave = tid >> 6;
    if ((tid & 63) == 0) { ss[wave] = s; qq[wave] = q; }
    __syncthreads();
    s = ss[0] + ss[1] + ss[2] + ss[3];
    q = qq[0] + qq[1] + qq[2] + qq[3];
    const float mean = s * (1.f / 1024.f);
    const float var  = q * (1.f / 1024.f) - mean * mean;
    const float rstd = rsqrtf(var + 1e-5f);
    const float4 wv = ((const float4*)w)[tid];
    const float4 bv = ((const float4*)b)[tid];
    float4 o;
    o.x = (v.x - mean) * rstd * wv.x + bv.x;
    o.y = (v.y - mean) * rstd * wv.y + bv.y;
    o.z = (v.z - mean) * rstd * wv.z + bv.z;
    o.w = (v.w - mean) * rstd * wv.w + bv.w;
    ((u16x4*)(h2 + (size_t)row * 1024))[tid] = f4_to_b4(o);
}

// ---------- host launcher ----------
extern "C" void kernel_launch(void* const* d_in, const int* in_sizes, int n_in,
                              void* d_out, int out_size, void* d_ws, size_t ws_size,
                              hipStream_t stream) {
    const float* x      = (const float*)d_in[0];
    const float* ln1_w  = (const float*)d_in[1];
    const float* ln1_b  = (const float*)d_in[2];
    const float* W_in   = (const float*)d_in[3];
    const float* conv_w = (const float*)d_in[4];
    const float* conv_b = (const float*)d_in[5];
    const float* W_xproj= (const float*)d_in[6];
    const float* W_dt   = (const float*)d_in[7];
    const float* b_dt   = (const float*)d_in[8];
    const float* A_log  = (const float*)d_in[9];
    const float* Dvec   = (const float*)d_in[10];
    const float* W_out  = (const float*)d_in[11];
    const float* ln2_w  = (const float*)d_in[12];
    const float* ln2_b  = (const float*)d_in[13];
    const float* W1     = (const float*)d_in[14];
    const float* b1     = (const float*)d_in[15];
    const float* W2     = (const float*)d_in[16];
    const float* b2     = (const float*)d_in[17];
    float* out = (float*)d_out;
    char*  ws  = (char*)d_ws;
    const size_t MB = 1024ull * 1024ull;

    u16*   h1b   = (u16*)(ws + 0);              // 4 MB (reused as h2b)
    u16*   xzu   = (u16*)(ws + 4 * MB);         // 8 MB  [2048,2048] bf16 (u pre-conv)
    u16*   zst   = (u16*)(ws + 12 * MB);        // 8 MB  tiled silu(z) [128][2048][16]
    u16*   utl   = (u16*)(ws + 20 * MB);        // 8 MB  tiled u [128][2048][16]
    float* parts = (float*)(ws + 28 * MB);      // 8 MB  [8][2048][128] fp32
    float* bcp   = (float*)(ws + 36 * MB);      // 256 KB [1024 pairs][64]
    u16*   xdbr  = (u16*)(ws + 36 * MB + 256 * 1024);  // 256 KB
    u16*   Wdtb  = (u16*)(ws + 36 * MB + 512 * 1024);  // 256 KB
    float* bpk   = (float*)(ws + 36 * MB + 768 * 1024);// 128 KB [1024 pairs][32] B-only
    u16*   ymul  = (u16*)(ws + 37 * MB);        // 8 MB
    float* Qarr  = (float*)(ws + 45 * MB);      // 4 MB  [16][2][2048][16]
    float* Sarr  = (float*)(ws + 49 * MB);      // 256 KB
    float* H0    = (float*)(ws + 50 * MB);      // 4 MB  [16][2][2048][16]
    float* x2    = (float*)(ws + 54 * MB);      // 8 MB
    u16*   Winb  = (u16*)(ws + 62 * MB);        // 8 MB
    u16*   Woutb = (u16*)(ws + 70 * MB);        // 4 MB
    u16*   W1b   = (u16*)(ws + 74 * MB);        // 8 MB
    u16*   W2b   = (u16*)(ws + 82 * MB);        // 8 MB
    u16*   Wxpb  = (u16*)(ws + 90 * MB);        // 512 KB
    u16*   h2b   = h1b;
    float* opart = (float*)(ws + 4 * MB);       // 16 MB (xzu+zst dead after pass2)
    u16*   f1    = (u16*)(ws + 4 * MB);         // 16 MB (opart dead after combine_ln2)
    float* fpart = (float*)(ws + 20 * MB);      // 32 MB (utl..H0 dead by FFN2)

    // weight conversions: 1 merged kernel + pad
    cvt_all<<<14464, 256, 0, stream>>>(W_in, W_out, W1, W2, W_dt,
                                       Winb, Woutb, W1b, W2b, Wdtb);
    pad_xproj_kernel<<<256, 256, 0, stream>>>(W_xproj, Wxpb);

    // LN1 -> h1 (bf16)
    ln_kernel<<<2048, 256, 0, stream>>>(x, ln1_w, ln1_b, h1b);
    // xz = h1 @ W_in^T : u-half -> bf16 xzu row-major, z-half -> silu -> TILED zst
    gemm_tb<5><<<dim3(16, 32, 1), 512, 0, stream>>>(h1b, Winb, xzu, zst, nullptr,
                                                    MROWS, 4096, 1024, 1024);
    // depthwise conv + silu -> tiled utl only
    conv_kernel<<<4096, 256, 0, stream>>>(xzu, conv_w, conv_b, utl);
    // xproj split-K (8 x K=256), A from tiled utl -> partials -> combine
    gemm_xp<<<dim3(16, 1, 8), 256, 0, stream>>>(utl, Wxpb, parts);
    xproj_combine<<<256, 256, 0, stream>>>(parts, xdbr, bcp, bpk);
    // selective scan: per-segment states -> prefix -> in-segment scan
    scan_pass1<<<dim3(128, 2, NSEG), 256, 0, stream>>>(xdbr, Wdtb, b_dt, utl, bpk, A_log,
                                                       Qarr, Sarr);
    scan_prefix<<<dim3(128, 2), 256, 0, stream>>>(Qarr, Sarr, A_log, H0);
    scan_pass2<<<dim3(128, 2, NSEG), 256, 0, stream>>>(xdbr, Wdtb, b_dt, utl, bcp, zst,
                                                       A_log, Dvec, H0, ymul);
    // out-proj split-K (2 x K=1024) -> partials; combine + residual + LN2 fused
    gemm_tb<10><<<dim3(16, 8, 2), 512, 0, stream>>>(ymul, Woutb, opart, nullptr, nullptr,
                                                    MROWS, 1024, 2048, 1024);
    outproj_combine_ln2<<<2048, 256, 0, stream>>>(x, opart, ln2_w, ln2_b, x2, h2b);
    // f1 = relu(h2 @ W1^T + b1)  bf16 [2048,4096]
    gemm_tb<3><<<dim3(16, 32, 1), 512, 0, stream>>>(h2b, W1b, f1, nullptr, b1,
                                                    MROWS, 4096, 1024, 1024);
    // FFN2 split-K (4 x K=1024) -> partials; combine + bias + residual
    gemm_tb<10><<<dim3(16, 8, 4), 512, 0, stream>>>(f1, W2b, fpart, nullptr, nullptr,
                                                    MROWS, 1024, 4096, 1024);
    ffn2_combine<<<2048, 256, 0, stream>>>(fpart, x2, b2, out);
}

// Round 18
// 214.312 us; speedup vs baseline: 1.1333x; 1.0087x over previous
//
#include <hip/hip_runtime.h>

typedef unsigned short u16;
typedef unsigned int   u32;
typedef short   bf16x8 __attribute__((ext_vector_type(8)));
typedef float   f32x4  __attribute__((ext_vector_type(4)));
typedef u16     u16x4  __attribute__((ext_vector_type(4)));
typedef u16     u16x8  __attribute__((ext_vector_type(8)));

// ---------- bf16 helpers (RNE) ----------
__device__ __forceinline__ u16 f2b(float f) {
    u32 u = __builtin_bit_cast(u32, f);
    u32 r = u + 0x7FFFu + ((u >> 16) & 1u);
    return (u16)(r >> 16);
}
__device__ __forceinline__ float b2f(u16 h) {
    u32 u = ((u32)h) << 16;
    return __builtin_bit_cast(float, u);
}
__device__ __forceinline__ u16x4 f4_to_b4(float4 v) {
    u16x4 o; o.x = f2b(v.x); o.y = f2b(v.y); o.z = f2b(v.z); o.w = f2b(v.w);
    return o;
}

// native transcendentals: single-instruction v_exp_f32 / v_log_f32
__device__ __forceinline__ float fexp2(float x) {
    float r;
    asm("v_exp_f32 %0, %1" : "=v"(r) : "v"(x));
    return r;
}
__device__ __forceinline__ float flog2(float x) {
    float r;
    asm("v_log_f32 %0, %1" : "=v"(r) : "v"(x));
    return r;
}

// DPP add: p += p[lane permuted by CTRL]  (pure VALU, no DS pipe)
template <int CTRL>
__device__ __forceinline__ float dpp_add(float p) {
    int pi = __builtin_bit_cast(int, p);
    int q  = __builtin_amdgcn_update_dpp(pi, pi, CTRL, 0xF, 0xF, false);
    return p + __builtin_bit_cast(float, q);
}
#define DPP_XOR1 0xB1   // quad_perm [1,0,3,2]
#define DPP_XOR2 0x4E   // quad_perm [2,3,0,1]
#define DPP_HMIR 0x141  // row_half_mirror (lane^7)
#define DPP_MIR  0x140  // row_mirror      (lane^15)

// ---------- constants ----------
#define MROWS   2048   // B*L
#define NSEG    16
#define SEGT    64
#define L2E     1.44269504088896340736f
#define LN2     0.69314718055994530942f

#define GLDS(g, l) __builtin_amdgcn_global_load_lds(                      \
    (const __attribute__((address_space(1))) void*)(g),                   \
    (__attribute__((address_space(3))) void*)(l), 16, 0, 0)

// ---------- merged prep: weight cvt (14464 blk) + xproj pad (256) + LN1 (2048) ----------
__global__ __launch_bounds__(256) void prep_kernel(const float* __restrict__ W_in,
                                                   const float* __restrict__ W_out,
                                                   const float* __restrict__ W1,
                                                   const float* __restrict__ W2,
                                                   const float* __restrict__ W_dt,
                                                   const float* __restrict__ W_xproj,
                                                   const float* __restrict__ x,
                                                   const float* __restrict__ ln1_w,
                                                   const float* __restrict__ ln1_b,
                                                   u16* __restrict__ Winb,
                                                   u16* __restrict__ Woutb,
                                                   u16* __restrict__ W1b,
                                                   u16* __restrict__ W2b,
                                                   u16* __restrict__ Wdtb,
                                                   u16* __restrict__ Wxpb,
                                                   u16* __restrict__ h1b) {
    const int blk = blockIdx.x;
    const int tid = threadIdx.x;
    if (blk < 14464) {
        const int i = blk * 256 + tid;
        const float* src; u16* dst; int off;
        if (i < 1048576)      { src = W_in;  dst = Winb;  off = i; }
        else if (i < 1572864) { src = W_out; dst = Woutb; off = i - 1048576; }
        else if (i < 2621440) { src = W1;    dst = W1b;   off = i - 1572864; }
        else if (i < 3670016) { src = W2;    dst = W2b;   off = i - 2621440; }
        else                  { src = W_dt;  dst = Wdtb;  off = i - 3670016; }
        float4 v = ((const float4*)src)[off];
        ((u16x4*)dst)[off] = f4_to_b4(v);
    } else if (blk < 14464 + 256) {
        const int i = (blk - 14464) * 256 + tid;   // over 128*512
        const int r = i >> 9, c4 = i & 511;
        float4 v = make_float4(0.f, 0.f, 0.f, 0.f);
        if (r < 96) v = ((const float4*)(W_xproj + (size_t)r * 2048))[c4];
        ((u16x4*)(Wxpb + (size_t)r * 2048))[c4] = f4_to_b4(v);
    } else {
        const int row = blk - 14720;
        const float4 v = ((const float4*)(x + (size_t)row * 1024))[tid];
        float s = v.x + v.y + v.z + v.w;
        float q = v.x * v.x + v.y * v.y + v.z * v.z + v.w * v.w;
#pragma unroll
        for (int off = 1; off < 64; off <<= 1) {
            s += __shfl_xor(s, off, 64);
            q += __shfl_xor(q, off, 64);
        }
        __shared__ float ss[4], qq[4];
        const int wave = tid >> 6;
        if ((tid & 63) == 0) { ss[wave] = s; qq[wave] = q; }
        __syncthreads();
        s = ss[0] + ss[1] + ss[2] + ss[3];
        q = qq[0] + qq[1] + qq[2] + qq[3];
        const float mean = s * (1.f / 1024.f);
        const float var  = q * (1.f / 1024.f) - mean * mean;
        const float rstd = rsqrtf(var + 1e-5f);
        const float4 wv = ((const float4*)ln1_w)[tid];
        const float4 bv = ((const float4*)ln1_b)[tid];
        float4 o;
        o.x = (v.x - mean) * rstd * wv.x + bv.x;
        o.y = (v.y - mean) * rstd * wv.y + bv.y;
        o.z = (v.z - mean) * rstd * wv.z + bv.z;
        o.w = (v.w - mean) * rstd * wv.w + bv.w;
        ((u16x4*)(h1b + (size_t)row * 1024))[tid] = f4_to_b4(o);
    }
}

// ---------- LayerNorm (row = 1024 cols), fp32 in -> bf16 out ----------
__global__ __launch_bounds__(256) void ln_kernel(const float* __restrict__ x,
                                                 const float* __restrict__ w,
                                                 const float* __restrict__ b,
                                                 u16* __restrict__ out) {
    const int row = blockIdx.x;
    const int tid = threadIdx.x;
    const float4 v = ((const float4*)(x + (size_t)row * 1024))[tid];
    float s = v.x + v.y + v.z + v.w;
    float q = v.x * v.x + v.y * v.y + v.z * v.z + v.w * v.w;
#pragma unroll
    for (int off = 1; off < 64; off <<= 1) {
        s += __shfl_xor(s, off, 64);
        q += __shfl_xor(q, off, 64);
    }
    __shared__ float ss[4], qq[4];
    const int wave = tid >> 6;
    if ((tid & 63) == 0) { ss[wave] = s; qq[wave] = q; }
    __syncthreads();
    s = ss[0] + ss[1] + ss[2] + ss[3];
    q = qq[0] + qq[1] + qq[2] + qq[3];
    const float mean = s * (1.f / 1024.f);
    const float var  = q * (1.f / 1024.f) - mean * mean;
    const float rstd = rsqrtf(var + 1e-5f);
    const float4 wv = ((const float4*)w)[tid];
    const float4 bv = ((const float4*)b)[tid];
    float4 o;
    o.x = (v.x - mean) * rstd * wv.x + bv.x;
    o.y = (v.y - mean) * rstd * wv.y + bv.y;
    o.z = (v.z - mean) * rstd * wv.z + bv.z;
    o.w = (v.w - mean) * rstd * wv.w + bv.w;
    ((u16x4*)(out + (size_t)row * 1024))[tid] = f4_to_b4(o);
}

// ---------- depthwise causal conv + bias + silu (bf16 in) -> tiled utl only ----------
__global__ __launch_bounds__(256) void conv_kernel(const u16* __restrict__ xzu,
                                                   const float* __restrict__ cw,
                                                   const float* __restrict__ cb,
                                                   u16* __restrict__ utl) {
    const int idx = blockIdx.x * 256 + threadIdx.x;   // over 2048 rows * 512 d4
    const int row = idx >> 9;
    const int d4  = idx & 511;
    const int d   = d4 * 4;
    const int bb  = row >> 10;
    const int t   = row & 1023;
    float w0[4], w1[4], w2[4], w3[4];
    *(float4*)w0 = ((const float4*)cw)[d + 0];
    *(float4*)w1 = ((const float4*)cw)[d + 1];
    *(float4*)w2 = ((const float4*)cw)[d + 2];
    *(float4*)w3 = ((const float4*)cw)[d + 3];
    float4 a = ((const float4*)cb)[d4];
#pragma unroll
    for (int j = 0; j < 4; ++j) {
        const int tt = t - 3 + j;
        if (tt >= 0) {
            const u16x4 uv = *(const u16x4*)(xzu + ((size_t)(bb * 1024 + tt)) * 2048 + d);
            a.x += b2f(uv.x) * w0[j];
            a.y += b2f(uv.y) * w1[j];
            a.z += b2f(uv.z) * w2[j];
            a.w += b2f(uv.w) * w3[j];
        }
    }
    float4 o;
    o.x = a.x / (1.f + __expf(-a.x));
    o.y = a.y / (1.f + __expf(-a.y));
    o.z = a.z / (1.f + __expf(-a.z));
    o.w = a.w / (1.f + __expf(-a.w));
    *(u16x4*)(utl + (((size_t)(d >> 4)) * 2048 + row) * 16 + (d & 15)) = f4_to_b4(o);
}

// ---------- 3-buffer single-barrier GEMM 128x128, 8 waves, XCD-swizzled ----------
// bf16 epilogues (EPI 3/5) repack through wave-private LDS -> coalesced 16B stores.
// EPI: 3 = relu(c+bias) bf16; 5 = xz split; 10 = split-K partial fp32
template <int EPI>
__global__ __launch_bounds__(512) void gemm_tb(const u16* __restrict__ A,
                                               const u16* __restrict__ Bw,
                                               void* __restrict__ Cptr,
                                               void* __restrict__ Cptr2,
                                               const float* __restrict__ bias,
                                               int M, int N, int K, int KS) {
    const int nbm = gridDim.x, nbn = gridDim.y;
    const int nwg = nbm * nbn;
    const int id  = blockIdx.x + nbm * blockIdx.y;
    const int sw  = (nwg >= 8) ? ((id & 7) * (nwg >> 3) + (id >> 3)) : id;
    const int bm  = sw % nbm, bn = sw / nbm;

    __shared__ u16 SMEM[3 * 2 * 128 * 32];      // 48 KB pool (A: first half, B: second)
    u16* Asm = SMEM;
    u16* Bsm = SMEM + 3 * 128 * 32;
    const int tid  = threadIdx.x;
    const int kz   = blockIdx.z;
    const int lane = tid & 63;
    const int wave = tid >> 6;
    const int wm   = wave >> 1, wn = wave & 1;
    const u16* Ag = A  + (size_t)bm * 128 * K;
    const u16* Bg = Bw + (size_t)bn * 128 * K;
    const int r0 = tid >> 2;            // 0..127
    const int sg = (tid & 3) * 8;
    const int k0 = kz * KS;
    const int nk = KS >> 5;
    const int fr = lane & 15, fk = (lane >> 4) * 8;

#define STG(bf, kk)                                                            \
    {                                                                          \
        const int kof = k0 + (kk) * 32;                                        \
        GLDS(Ag + (size_t)r0 * K + kof + sg, Asm + (bf) * 4096 + tid * 8);     \
        GLDS(Bg + (size_t)r0 * K + kof + sg, Bsm + (bf) * 4096 + tid * 8);     \
    }

    f32x4 acc[2][4] = {};
    STG(0, 0); STG(1, 1);
    int buf = 0;
    for (int k = 0; k < nk; ++k) {
        if (k < nk - 1) asm volatile("s_waitcnt vmcnt(2)" ::: "memory");
        else            asm volatile("s_waitcnt vmcnt(0)" ::: "memory");
        __builtin_amdgcn_s_barrier();
        bf16x8 a[2], b[4];
#pragma unroll
        for (int m = 0; m < 2; ++m)
            a[m] = *(const bf16x8*)&Asm[buf * 4096 + (wm * 32 + m * 16 + fr) * 32 + fk];
#pragma unroll
        for (int n = 0; n < 4; ++n)
            b[n] = *(const bf16x8*)&Bsm[buf * 4096 + (wn * 64 + n * 16 + fr) * 32 + fk];
        if (k + 2 < nk) {
            const int slot = (buf + 2) % 3;
            STG(slot, k + 2);
        }
#pragma unroll
        for (int m = 0; m < 2; ++m)
#pragma unroll
            for (int n = 0; n < 4; ++n)
                acc[m][n] = __builtin_amdgcn_mfma_f32_16x16x32_bf16(a[m], b[n], acc[m][n], 0, 0, 0);
        buf = (buf == 2) ? 0 : buf + 1;
    }
#undef STG

    const int fq = lane >> 4;
    if constexpr (EPI == 10) {
#pragma unroll
        for (int m = 0; m < 2; ++m)
#pragma unroll
            for (int n = 0; n < 4; ++n) {
                const int row0 = bm * 128 + wm * 32 + m * 16 + fq * 4;
                const int col  = bn * 128 + wn * 64 + n * 16 + fr;
#pragma unroll
                for (int j = 0; j < 4; ++j)
                    ((float*)Cptr)[(size_t)kz * M * N + (size_t)(row0 + j) * N + col]
                        = acc[m][n][j];
            }
    } else {
        // bf16 output: wave-private LDS repack (32x64 u16 = 4 KB), then 16B stores.
        // Protocol: drain own ds_reads, then BARRIER (all waves done with staging),
        // then repack. Fixed indexing: 64 cols = 8 chunks of 8 u16 per row.
        asm volatile("s_waitcnt lgkmcnt(0)" ::: "memory");
        __builtin_amdgcn_s_barrier();
        u16* wbuf = SMEM + wave * 2048;
#pragma unroll
        for (int m = 0; m < 2; ++m)
#pragma unroll
            for (int n = 0; n < 4; ++n)
#pragma unroll
                for (int j = 0; j < 4; ++j) {
                    float v = acc[m][n][j];
                    if constexpr (EPI == 3) {
                        const int col = bn * 128 + wn * 64 + n * 16 + fr;
                        v += bias[col];
                        v = fmaxf(v, 0.f);
                    } else {
                        if (bn >= 16) v = v / (1.f + __expf(-v));   // z-half: silu
                    }
                    wbuf[(m * 16 + fq * 4 + j) * 64 + n * 16 + fr] = f2b(v);
                }
        asm volatile("s_waitcnt lgkmcnt(0)" ::: "memory");   // writes visible to own reads
#pragma unroll
        for (int i = 0; i < 4; ++i) {
            const int c   = lane + 64 * i;        // 0..255 chunks of 8 u16
            const int row = c >> 3;               // 0..31 (8 chunks per 64-col row)
            const int off = (c & 7) * 8;          // u16 offset 0..56
            const u16x8 val = *(const u16x8*)&wbuf[row * 64 + off];
            const int row_g = bm * 128 + wm * 32 + row;
            const int col_g = bn * 128 + wn * 64 + off;
            if constexpr (EPI == 3) {
                *(u16x8*)((u16*)Cptr + (size_t)row_g * N + col_g) = val;
            } else {
                if (bn < 16) {   // u-half: row-major [2048][2048]
                    *(u16x8*)((u16*)Cptr + (size_t)row_g * 2048 + col_g) = val;
                } else {         // z-half: tiled zst [128][2048][16]
                    const int zc = col_g - 2048;
                    *(u16x8*)((u16*)Cptr2 + ((size_t)(zc >> 4) * 2048 + row_g) * 16 + (zc & 15)) = val;
                }
            }
        }
    }
}

// ---------- xproj GEMM: A from TILED utl; 3-buffer single-barrier; 256 thr ----------
__global__ __launch_bounds__(256) void gemm_xp(const u16* __restrict__ utl,
                                               const u16* __restrict__ Bw,
                                               float* __restrict__ part) {
    const int nwg = 16;
    const int id  = blockIdx.x;
    const int sw  = (id & 7) * (nwg >> 3) + (id >> 3);
    const int bm  = sw;
    __shared__ u16 Asm[3][128 * 32];
    __shared__ u16 Bsm[3][128 * 32];
    const int tid  = threadIdx.x;
    const int kz   = blockIdx.z;
    const int lane = tid & 63;
    const int wave = tid >> 6;
    const int wm   = wave >> 1, wn = wave & 1;
    const u16* Bg = Bw;
    const int r0 = tid >> 2;             // 0..63
    const int pc = tid & 3;              // K-piece 0..3 (8 u16 each)
    const int sg = pc * 8;
    const int k0 = kz * 256;
    const int fr = lane & 15, fk = (lane >> 4) * 8;

#define STGX(bf, kk)                                                                     \
    {                                                                                    \
        const int kof = k0 + (kk) * 32;                                                  \
        const int kc  = kof >> 4;                                                        \
        GLDS(utl + ((size_t)(kc + (pc >> 1)) * 2048 + bm * 128 + r0) * 16 + (pc & 1) * 8,\
             &Asm[bf][tid * 8]);                                                         \
        GLDS(utl + ((size_t)(kc + (pc >> 1)) * 2048 + bm * 128 + r0 + 64) * 16 + (pc & 1) * 8,\
             &Asm[bf][(tid + 256) * 8]);                                                 \
        GLDS(Bg + (size_t)r0 * 2048 + kof + sg, &Bsm[bf][tid * 8]);                      \
        GLDS(Bg + (size_t)(r0 + 64) * 2048 + kof + sg, &Bsm[bf][(tid + 256) * 8]);       \
    }

    f32x4 acc[4][4] = {};
    STGX(0, 0); STGX(1, 1);
    int buf = 0;
    const int nk = 8;
    for (int k = 0; k < nk; ++k) {
        if (k < nk - 1) asm volatile("s_waitcnt vmcnt(4)" ::: "memory");
        else            asm volatile("s_waitcnt vmcnt(0)" ::: "memory");
        __builtin_amdgcn_s_barrier();
        bf16x8 a[4], b[4];
#pragma unroll
        for (int m = 0; m < 4; ++m)
            a[m] = *(const bf16x8*)&Asm[buf][(wm * 64 + m * 16 + fr) * 32 + fk];
#pragma unroll
        for (int n = 0; n < 4; ++n)
            b[n] = *(const bf16x8*)&Bsm[buf][(wn * 64 + n * 16 + fr) * 32 + fk];
        if (k + 2 < nk) {
            const int slot = (buf + 2) % 3;
            STGX(slot, k + 2);
        }
#pragma unroll
        for (int m = 0; m < 4; ++m)
#pragma unroll
            for (int n = 0; n < 4; ++n)
                acc[m][n] = __builtin_amdgcn_mfma_f32_16x16x32_bf16(a[m], b[n], acc[m][n], 0, 0, 0);
        buf = (buf == 2) ? 0 : buf + 1;
    }
#undef STGX

    const int fq = lane >> 4;
    float* Cp = part + (size_t)kz * MROWS * 128;
#pragma unroll
    for (int m = 0; m < 4; ++m) {
#pragma unroll
        for (int n = 0; n < 4; ++n) {
            const int row0 = bm * 128 + wm * 64 + m * 16 + fq * 4;
            const int col  = wn * 64 + n * 16 + fr;
#pragma unroll
            for (int j = 0; j < 4; ++j)
                Cp[(size_t)(row0 + j) * 128 + col] = acc[m][n][j];
        }
    }
}

// combine split-K partials -> xdbr bf16 [2048,64] + bcp fp32 pair-packed +
// bpk (B-only, pass1): bpk[(t>>1)*32 + s*2 + (t&1)]
__global__ __launch_bounds__(256) void xproj_combine(const float* __restrict__ part,
                                                     u16* __restrict__ xdbr,
                                                     float* __restrict__ bcp,
                                                     float* __restrict__ bpk) {
    int i = blockIdx.x * 256 + threadIdx.x;     // over 2048*32
    int row = i >> 5, c4 = i & 31;
    if (c4 >= 24) return;
    float4 s = make_float4(0.f, 0.f, 0.f, 0.f);
#pragma unroll
    for (int p = 0; p < 8; ++p) {
        float4 v = ((const float4*)(part + (size_t)p * MROWS * 128 + (size_t)row * 128))[c4];
        s.x += v.x; s.y += v.y; s.z += v.z; s.w += v.w;
    }
    if (c4 < 16) {
        ((u16x4*)(xdbr + (size_t)row * 64))[c4] = f4_to_b4(s);
    } else {
        const int e0 = (c4 - 16) * 4;          // 0..31 over B(0..15)|C(16..31)
        float sv[4] = {s.x, s.y, s.z, s.w};
#pragma unroll
        for (int j = 0; j < 4; ++j) {
            const int e = e0 + j;
            const int st  = (e < 16) ? e : (e - 16);
            const int isc = (e < 16) ? 0 : 1;
            bcp[(size_t)(row >> 1) * 64 + st * 4 + (row & 1) * 2 + isc] = sv[j];
            if (e < 16)
                bpk[(size_t)(row >> 1) * 32 + st * 2 + (row & 1)] = sv[j];
        }
    }
}

// ---------- selective scan: time-segmented, dt fused via MFMA ----------
__device__ __forceinline__ void compute_dtu_tile(const u16* __restrict__ xdbr,
                                                 const u16* __restrict__ Wdtb,
                                                 const float* __restrict__ b_dt,
                                                 const u16* __restrict__ utile,
                                                 float* __restrict__ du_s,
                                                 size_t t0, int d0, int w, int l) {
    const int fr = l & 15, fk = (l >> 4) * 8;
    const bf16x8 a0 = *(const bf16x8*)(xdbr + (t0 + w * 16 + fr) * 64 + fk);
    const bf16x8 a1 = *(const bf16x8*)(xdbr + (t0 + w * 16 + fr) * 64 + 32 + fk);
    const bf16x8 b0 = *(const bf16x8*)(Wdtb + (size_t)(d0 + fr) * 64 + fk);
    const bf16x8 b1 = *(const bf16x8*)(Wdtb + (size_t)(d0 + fr) * 64 + 32 + fk);
    const float bdt = b_dt[d0 + fr];
    f32x4 acc = {};
    acc = __builtin_amdgcn_mfma_f32_16x16x32_bf16(a0, b0, acc, 0, 0, 0);
    acc = __builtin_amdgcn_mfma_f32_16x16x32_bf16(a1, b1, acc, 0, 0, 0);
#pragma unroll
    for (int j = 0; j < 4; ++j) {
        const int row = w * 16 + (l >> 4) * 4 + j;
        float v = acc[j] + bdt;
        const float sp = flog2(1.f + fexp2(v * L2E)) * LN2;
        v = (v > 20.f) ? v : sp;
        const float uval = b2f(utile[(t0 + row) * 16 + fr]);
        float2 dv; dv.x = v; dv.y = v * uval;
        *(float2*)&du_s[(row >> 1) * 66 + fr * 4 + (row & 1) * 2] = dv;  // b64 write
    }
}

// stage bcp pair rows: 32 rows x 64 floats = 8KB, lane-linear per wave
__device__ __forceinline__ void stage_bc(const float* __restrict__ bcp,
                                         float* __restrict__ bc_s,
                                         size_t p0, int w, int l) {
    const int pr = (w << 3) + (l >> 4);
    const int pc = (l & 15) << 2;
    GLDS(bcp + (p0 + pr) * 64 + pc,     &bc_s[(w << 9)]);
    GLDS(bcp + (p0 + pr + 4) * 64 + pc, &bc_s[(w << 9) + 256]);
}

// grid (128, 2, 16): d-chunk, b, seg.  block 256.
__global__ __launch_bounds__(256) void scan_pass1(const u16* __restrict__ xdbr,
                                                  const u16* __restrict__ Wdtb,
                                                  const float* __restrict__ b_dt,
                                                  const u16* __restrict__ utl,
                                                  const float* __restrict__ bpk,
                                                  const float* __restrict__ A_log,
                                                  float* __restrict__ Qarr,
                                                  float* __restrict__ Sarr) {
    __shared__ __align__(16) float du_s[32 * 66];
    __shared__ __align__(16) float bp_s[32 * 32];   // B-only: [pair-row][s*2 + t&1]

    const int tid = threadIdx.x;
    const int l   = tid & 63;
    const int w   = tid >> 6;
    const int s   = l & 15;
    const int g   = (w << 2) | (l >> 4);
    const int d0  = blockIdx.x << 4;
    const int b   = blockIdx.y;
    const int seg = blockIdx.z;
    const int d   = d0 + g;
    const size_t t0 = (size_t)b * 1024 + (size_t)seg * SEGT;
    const u16* utile = utl + (size_t)(d0 >> 4) * 2048 * 16;

    GLDS(bpk + ((t0 >> 1) + (tid >> 3)) * 32 + ((tid & 7) << 2), &bp_s[w << 8]);
    compute_dtu_tile(xdbr, Wdtb, b_dt, utile, du_s, t0, d0, w, l);

    const float As2 = -__expf(A_log[d * 16 + s]) * L2E;
    asm volatile("s_waitcnt vmcnt(0) lgkmcnt(0)" ::: "memory");
    __builtin_amdgcn_s_barrier();

    float Q = 0.f, S = 0.f;
#pragma unroll 8
    for (int t2 = 0; t2 < 32; ++t2) {
        const float4 du4 = *(const float4*)&du_s[t2 * 66 + g * 4];
        const float2 Bp  = *(const float2*)&bp_s[t2 * 32 + s * 2];
        S += du4.x;
        Q = fexp2(du4.x * As2) * Q + du4.y * Bp.x;
        S += du4.z;
        Q = fexp2(du4.z * As2) * Q + du4.w * Bp.y;
    }
    Qarr[(((size_t)seg * 2 + b) * 2048 + d) * 16 + s] = Q;
    if (s == 0) Sarr[((size_t)seg * 2 + b) * 2048 + d] = S;
}

// prefix scan over segments: H0[i][b][d][s] = h entering segment i
__global__ __launch_bounds__(256) void scan_prefix(const float* __restrict__ Qarr,
                                                   const float* __restrict__ Sarr,
                                                   const float* __restrict__ A_log,
                                                   float* __restrict__ H0) {
    const int tid = threadIdx.x;
    const int d   = (blockIdx.x << 4) + (tid >> 4);
    const int s   = tid & 15;
    const int b   = blockIdx.y;
    const float As2 = -__expf(A_log[d * 16 + s]) * L2E;
    float h = 0.f;
#pragma unroll
    for (int i = 0; i < NSEG; ++i) {
        const size_t base = ((size_t)i * 2 + b) * 2048 + d;
        H0[base * 16 + s] = h;
        h = fexp2(As2 * Sarr[base]) * h + Qarr[base * 16 + s];
    }
}

__global__ __launch_bounds__(256) void scan_pass2(const u16* __restrict__ xdbr,
                                                  const u16* __restrict__ Wdtb,
                                                  const float* __restrict__ b_dt,
                                                  const u16* __restrict__ utl,
                                                  const float* __restrict__ bcp,
                                                  const u16* __restrict__ zst,
                                                  const float* __restrict__ A_log,
                                                  const float* __restrict__ Dp,
                                                  const float* __restrict__ H0,
                                                  u16* __restrict__ ymul) {
    __shared__ __align__(16) float du_s[32 * 66];   // overlaid by p_s after inner loop
    __shared__ __align__(16) float bc_s[32 * 64];

    const int tid = threadIdx.x;
    const int l   = tid & 63;
    const int w   = tid >> 6;
    const int s   = l & 15;
    const int g   = (w << 2) | (l >> 4);
    const int d0  = blockIdx.x << 4;
    const int b   = blockIdx.y;
    const int seg = blockIdx.z;
    const int d   = d0 + g;
    const size_t t0 = (size_t)b * 1024 + (size_t)seg * SEGT;
    const u16* utile = utl + (size_t)(d0 >> 4) * 2048 * 16;
    const u16* ztile = zst + (size_t)(d0 >> 4) * 2048 * 16;

    stage_bc(bcp, bc_s, t0 >> 1, w, l);
    compute_dtu_tile(xdbr, Wdtb, b_dt, utile, du_s, t0, d0, w, l);

    const float As2 = -__expf(A_log[d * 16 + s]) * L2E;
    float h = H0[(((size_t)seg * 2 + b) * 2048 + d) * 16 + s];

    asm volatile("s_waitcnt vmcnt(0) lgkmcnt(0)" ::: "memory");
    __builtin_amdgcn_s_barrier();

    float pk[4];
#pragma unroll
    for (int c = 0; c < 4; ++c) {
        pk[c] = 0.f;
#pragma unroll
        for (int q = 0; q < 8; ++q) {
            const int t2 = c * 8 + q;
            const float4 du4 = *(const float4*)&du_s[t2 * 66 + g * 4];
            const float4 BC2 = *(const float4*)&bc_s[t2 * 64 + s * 4];
            // even t
            h = fexp2(du4.x * As2) * h + du4.y * BC2.x;
            float p = h * BC2.y;
            p = dpp_add<DPP_XOR1>(p);
            p = dpp_add<DPP_XOR2>(p);
            p = dpp_add<DPP_HMIR>(p);
            p = dpp_add<DPP_MIR>(p);
            {
                const unsigned long long km = 0x0001000100010001ULL << (2 * q);
                asm("v_cndmask_b32 %0, %0, %1, %2" : "+v"(pk[c]) : "v"(p), "s"(km));
            }
            // odd t
            h = fexp2(du4.z * As2) * h + du4.w * BC2.z;
            p = h * BC2.w;
            p = dpp_add<DPP_XOR1>(p);
            p = dpp_add<DPP_XOR2>(p);
            p = dpp_add<DPP_HMIR>(p);
            p = dpp_add<DPP_MIR>(p);
            {
                const unsigned long long km = 0x0001000100010001ULL << (2 * q + 1);
                asm("v_cndmask_b32 %0, %0, %1, %2" : "+v"(pk[c]) : "v"(p), "s"(km));
            }
        }
    }

    __builtin_amdgcn_s_barrier();    // all waves done reading du_s (reuse as p_s)
    float* p_s = du_s;
#pragma unroll
    for (int c = 0; c < 4; ++c) {
        const int row = c * 16 + s;
        p_s[row * 16 + (g ^ (row & 12))] = pk[c];
    }

    asm volatile("s_waitcnt lgkmcnt(0)" ::: "memory");
    __builtin_amdgcn_s_barrier();

    // epilogue: u/z read directly from tiled global (coalesced, cache-warm)
    {
        const int tt = tid >> 2, cc = (tid & 3) << 2;
        const float4 pv = *(const float4*)&p_s[tt * 16 + (cc ^ (tt & 12))];
        const u16x4  uv = *(const u16x4*)(utile + (t0 + tt) * 16 + cc);
        const u16x4  zs = *(const u16x4*)(ztile + (t0 + tt) * 16 + cc);
        const float4 Dv = *(const float4*)(Dp + d0 + cc);
        float4 o;
        o.x = (pv.x + b2f(uv.x) * Dv.x) * b2f(zs.x);
        o.y = (pv.y + b2f(uv.y) * Dv.y) * b2f(zs.y);
        o.z = (pv.z + b2f(uv.z) * Dv.z) * b2f(zs.z);
        o.w = (pv.w + b2f(uv.w) * Dv.w) * b2f(zs.w);
        *(u16x4*)(ymul + (t0 + tt) * 2048 + d0 + cc) = f4_to_b4(o);
    }
}

// out = x2 + b2 + sum of 4 partials   [2048,1024] fp32
__global__ __launch_bounds__(256) void ffn2_combine(const float* __restrict__ part,
                                                    const float* __restrict__ x2,
                                                    const float* __restrict__ b2,
                                                    float* __restrict__ out) {
    int i = blockIdx.x * 256 + threadIdx.x;    // over 2048*256
    float4 s = ((const float4*)x2)[i];
    float4 bv = ((const float4*)b2)[i & 255];
    s.x += bv.x; s.y += bv.y; s.z += bv.z; s.w += bv.w;
#pragma unroll
    for (int p = 0; p < 4; ++p) {
        float4 v = ((const float4*)(part + (size_t)p * MROWS * 1024))[i];
        s.x += v.x; s.y += v.y; s.z += v.z; s.w += v.w;
    }
    ((float4*)out)[i] = s;
}

// x2 = x + sum of 4 partials; h2 = LN2(x2) bf16.   one block per row.
__global__ __launch_bounds__(256) void outproj_combine_ln2(const float* __restrict__ x,
                                                           const float* __restrict__ part,
                                                           const float* __restrict__ w,
                                                           const float* __restrict__ b,
                                                           float* __restrict__ x2,
                                                           u16* __restrict__ h2) {
    const int row = blockIdx.x;
    const int tid = threadIdx.x;
    float4 v = ((const float4*)(x + (size_t)row * 1024))[tid];
#pragma unroll
    for (int p = 0; p < 4; ++p) {
        float4 pv = ((const float4*)(part + (size_t)p * MROWS * 1024 + (size_t)row * 1024))[tid];
        v.x += pv.x; v.y += pv.y; v.z += pv.z; v.w += pv.w;
    }
    ((float4*)(x2 + (size_t)row * 1024))[tid] = v;
    float s = v.x + v.y + v.z + v.w;
    float q = v.x * v.x + v.y * v.y + v.z * v.z + v.w * v.w;
#pragma unroll
    for (int off = 1; off < 64; off <<= 1) {
        s += __shfl_xor(s, off, 64);
        q += __shfl_xor(q, off, 64);
    }
    __shared__ float ss[4], qq[4];
    const int wave = tid >> 6;
    if ((tid & 63) == 0) { ss[wave] = s; qq[wave] = q; }
    __syncthreads();
    s = ss[0] + ss[1] + ss[2] + ss[3];
    q = qq[0] + qq[1] + qq[2] + qq[3];
    const float mean = s * (1.f / 1024.f);
    const float var  = q * (1.f / 1024.f) - mean * mean;
    const float rstd = rsqrtf(var + 1e-5f);
    const float4 wv = ((const float4*)w)[tid];
    const float4 bv = ((const float4*)b)[tid];
    float4 o;
    o.x = (v.x - mean) * rstd * wv.x + bv.x;
    o.y = (v.y - mean) * rstd * wv.y + bv.y;
    o.z = (v.z - mean) * rstd * wv.z + bv.z;
    o.w = (v.w - mean) * rstd * wv.w + bv.w;
    ((u16x4*)(h2 + (size_t)row * 1024))[tid] = f4_to_b4(o);
}

// ---------- host launcher ----------
extern "C" void kernel_launch(void* const* d_in, const int* in_sizes, int n_in,
                              void* d_out, int out_size, void* d_ws, size_t ws_size,
                              hipStream_t stream) {
    const float* x      = (const float*)d_in[0];
    const float* ln1_w  = (const float*)d_in[1];
    const float* ln1_b  = (const float*)d_in[2];
    const float* W_in   = (const float*)d_in[3];
    const float* conv_w = (const float*)d_in[4];
    const float* conv_b = (const float*)d_in[5];
    const float* W_xproj= (const float*)d_in[6];
    const float* W_dt   = (const float*)d_in[7];
    const float* b_dt   = (const float*)d_in[8];
    const float* A_log  = (const float*)d_in[9];
    const float* Dvec   = (const float*)d_in[10];
    const float* W_out  = (const float*)d_in[11];
    const float* ln2_w  = (const float*)d_in[12];
    const float* ln2_b  = (const float*)d_in[13];
    const float* W1     = (const float*)d_in[14];
    const float* b1     = (const float*)d_in[15];
    const float* W2     = (const float*)d_in[16];
    const float* b2     = (const float*)d_in[17];
    float* out = (float*)d_out;
    char*  ws  = (char*)d_ws;
    const size_t MB = 1024ull * 1024ull;

    u16*   h1b   = (u16*)(ws + 0);              // 4 MB (reused as h2b)
    u16*   xzu   = (u16*)(ws + 4 * MB);         // 8 MB  [2048,2048] bf16 (u pre-conv)
    u16*   zst   = (u16*)(ws + 12 * MB);        // 8 MB  tiled silu(z) [128][2048][16]
    u16*   utl   = (u16*)(ws + 20 * MB);        // 8 MB  tiled u [128][2048][16]
    float* parts = (float*)(ws + 28 * MB);      // 8 MB  [8][2048][128] fp32
    float* bcp   = (float*)(ws + 36 * MB);      // 256 KB [1024 pairs][64]
    u16*   xdbr  = (u16*)(ws + 36 * MB + 256 * 1024);  // 256 KB
    u16*   Wdtb  = (u16*)(ws + 36 * MB + 512 * 1024);  // 256 KB
    float* bpk   = (float*)(ws + 36 * MB + 768 * 1024);// 128 KB [1024 pairs][32] B-only
    u16*   ymul  = (u16*)(ws + 37 * MB);        // 8 MB
    float* Qarr  = (float*)(ws + 45 * MB);      // 4 MB  [16][2][2048][16]
    float* Sarr  = (float*)(ws + 49 * MB);      // 256 KB
    float* H0    = (float*)(ws + 50 * MB);      // 4 MB  [16][2][2048][16]
    float* x2    = (float*)(ws + 54 * MB);      // 8 MB
    u16*   Winb  = (u16*)(ws + 62 * MB);        // 8 MB
    u16*   Woutb = (u16*)(ws + 70 * MB);        // 4 MB
    u16*   W1b   = (u16*)(ws + 74 * MB);        // 8 MB
    u16*   W2b   = (u16*)(ws + 82 * MB);        // 8 MB
    u16*   Wxpb  = (u16*)(ws + 90 * MB);        // 512 KB
    u16*   h2b   = h1b;
    float* opart = (float*)(ws + 4 * MB);       // 32 MB (xzu,zst,utl,parts dead after pass2)
    u16*   f1    = (u16*)(ws + 4 * MB);         // 16 MB (opart dead after combine_ln2)
    float* fpart = (float*)(ws + 20 * MB);      // 32 MB (utl..H0 dead by FFN2)

    // prep: weight conversions + xproj pad + LN1 (single kernel)
    prep_kernel<<<16768, 256, 0, stream>>>(W_in, W_out, W1, W2, W_dt, W_xproj,
                                           x, ln1_w, ln1_b,
                                           Winb, Woutb, W1b, W2b, Wdtb, Wxpb, h1b);

    // xz = h1 @ W_in^T : u-half -> bf16 xzu row-major, z-half -> silu -> TILED zst
    gemm_tb<5><<<dim3(16, 32, 1), 512, 0, stream>>>(h1b, Winb, xzu, zst, nullptr,
                                                    MROWS, 4096, 1024, 1024);
    // depthwise conv + silu -> tiled utl only
    conv_kernel<<<4096, 256, 0, stream>>>(xzu, conv_w, conv_b, utl);
    // xproj split-K (8 x K=256), A from tiled utl -> partials -> combine
    gemm_xp<<<dim3(16, 1, 8), 256, 0, stream>>>(utl, Wxpb, parts);
    xproj_combine<<<256, 256, 0, stream>>>(parts, xdbr, bcp, bpk);
    // selective scan: per-segment states -> prefix -> in-segment scan
    scan_pass1<<<dim3(128, 2, NSEG), 256, 0, stream>>>(xdbr, Wdtb, b_dt, utl, bpk, A_log,
                                                       Qarr, Sarr);
    scan_prefix<<<dim3(128, 2), 256, 0, stream>>>(Qarr, Sarr, A_log, H0);
    scan_pass2<<<dim3(128, 2, NSEG), 256, 0, stream>>>(xdbr, Wdtb, b_dt, utl, bcp, zst,
                                                       A_log, Dvec, H0, ymul);
    // out-proj split-K (4 x K=512) -> partials; combine + residual + LN2 fused
    gemm_tb<10><<<dim3(16, 8, 4), 512, 0, stream>>>(ymul, Woutb, opart, nullptr, nullptr,
                                                    MROWS, 1024, 2048, 512);
    outproj_combine_ln2<<<2048, 256, 0, stream>>>(x, opart, ln2_w, ln2_b, x2, h2b);
    // f1 = relu(h2 @ W1^T + b1)  bf16 [2048,4096]
    gemm_tb<3><<<dim3(16, 32, 1), 512, 0, stream>>>(h2b, W1b, f1, nullptr, b1,
                                                    MROWS, 4096, 1024, 1024);
    // FFN2 split-K (4 x K=1024) -> partials; combine + bias + residual
    gemm_tb<10><<<dim3(16, 8, 4), 512, 0, stream>>>(f1, W2b, fpart, nullptr, nullptr,
                                                    MROWS, 1024, 4096, 1024);
    ffn2_combine<<<2048, 256, 0, stream>>>(fpart, x2, b2, out);
}